// Round 10
// baseline (740.555 us; speedup 1.0000x reference)
//
#include <hip/hip_runtime.h>

#define B_ 2
#define S_ 4096
#define D_ 768
#define H_ 12
#define DH_ 64
#define W_ 256
#define G_ 64
#define FF_ 3072
#define L_ 2
#define M_ (B_*S_)
#define NEGV -1e9f
#define NSPLIT 16

typedef short bf16x8 __attribute__((ext_vector_type(8)));
typedef float f32x4 __attribute__((ext_vector_type(4)));
typedef unsigned short u16;
typedef unsigned short u16x4 __attribute__((ext_vector_type(4)));

__device__ __forceinline__ u16 f2bf(float f) {
  union { float f; unsigned u; } a; a.f = f;
  unsigned r = a.u + 0x7FFFu + ((a.u >> 16) & 1u);
  return (u16)(r >> 16);
}
__device__ __forceinline__ float b2f(u16 u) {
  union { unsigned u; float f; } a; a.u = ((unsigned)u) << 16;
  return a.f;
}

__device__ __forceinline__ f32x4 mfma16(bf16x8 a, bf16x8 b, f32x4 c) {
  return __builtin_amdgcn_mfma_f32_16x16x32_bf16(a, b, c, 0, 0, 0);
}

__device__ __forceinline__ void gload16(const u16* g, u16* l) {
  __builtin_amdgcn_global_load_lds((const __attribute__((address_space(1))) void*)g,
                                   (__attribute__((address_space(3))) void*)l, 16, 0, 0);
}

__device__ __forceinline__ int xcd_swz(int bid, int nwg) {
  if ((nwg & 7) == 0) {
    int cpx = nwg >> 3;
    bid = (bid & 7) * cpx + (bid >> 3);
  }
  return bid;
}

// ---------------- batched weight transpose (7 DxD slabs) ---------
struct Ptr7 { const float* p[7]; };
__global__ __launch_bounds__(256) void wtrans7(Ptr7 in, u16* __restrict__ out) {
  __shared__ float tile[32][33];
  int z = blockIdx.z;
  int slab = z >> 1, l = z & 1;
  const float* src = in.p[slab] + (size_t)l * D_ * D_;
  u16* dst = out + (size_t)z * D_ * D_;
  int k0 = blockIdx.y * 32, n0 = blockIdx.x * 32;
  int tx = threadIdx.x, ty = threadIdx.y;
#pragma unroll
  for (int i = 0; i < 4; i++)
    tile[ty + i*8][tx] = src[(size_t)(k0 + ty + i*8) * D_ + n0 + tx];
  __syncthreads();
#pragma unroll
  for (int i = 0; i < 4; i++)
    dst[(size_t)(n0 + ty + i*8) * D_ + k0 + tx] = f2bf(tile[tx][ty + i*8]);
}

__global__ __launch_bounds__(256) void wtrans(const float* __restrict__ in,
                                              u16* __restrict__ out, int K, int N) {
  __shared__ float tile[32][33];
  size_t base = (size_t)blockIdx.z * K * N;
  int k0 = blockIdx.y * 32, n0 = blockIdx.x * 32;
  int tx = threadIdx.x, ty = threadIdx.y;
#pragma unroll
  for (int i = 0; i < 4; i++)
    tile[ty + i*8][tx] = in[base + (size_t)(k0 + ty + i*8) * N + n0 + tx];
  __syncthreads();
#pragma unroll
  for (int i = 0; i < 4; i++)
    out[base + (size_t)(n0 + ty + i*8) * K + k0 + tx] = f2bf(tile[tx][ty + i*8]);
}

// ---------------- f32 -> bf16 convert ----------------------------
__global__ __launch_bounds__(256) void conv_b(const float* __restrict__ in,
                                              u16* __restrict__ outb, int n4) {
  int i = blockIdx.x * 256 + threadIdx.x;
  if (i >= n4) return;
  float4 v = ((const float4*)in)[i];
  u16x4 o;
  o[0] = f2bf(v.x); o[1] = f2bf(v.y); o[2] = f2bf(v.z); o[3] = f2bf(v.w);
  ((u16x4*)outb)[i] = o;
}

template <int MODE>
__device__ __forceinline__ float epi_post(float v) {
  if (MODE == 2) return v * 0.125f;
  if (MODE == 3) {
    float y = 0.79788456f * (v + 0.044715f * v * v * v);
    float e = __expf(fminf(2.f * y, 20.f));
    return v * e / (e + 1.f);
  }
  return v;
}

struct Bias5 { const float* p[5]; };

// ============ 256x256 8-PHASE GEMM + LDS-bounce epilogue ==========
#define VMC4() asm volatile("s_waitcnt vmcnt(4)" ::: "memory")
#define VMC0() asm volatile("s_waitcnt vmcnt(0)" ::: "memory")
#define GPH_PRE() do { __builtin_amdgcn_s_barrier(); \
  asm volatile("s_waitcnt lgkmcnt(0)" ::: "memory"); \
  __builtin_amdgcn_sched_barrier(0); } while (0)
#define GPH_PRE_NOLDS() do { __builtin_amdgcn_s_barrier(); \
  __builtin_amdgcn_sched_barrier(0); } while (0)
#define GPH_POST() do { __builtin_amdgcn_sched_barrier(0); \
  __builtin_amdgcn_s_barrier(); } while (0)
#define GPH_MFMA(AF, BF, QM, QN) do { \
  __builtin_amdgcn_s_setprio(1); \
  _Pragma("unroll") for (int mi = 0; mi < 4; mi++) \
  _Pragma("unroll") for (int nj = 0; nj < 2; nj++) \
  _Pragma("unroll") for (int ks = 0; ks < 2; ks++) \
    acc[(QM)*4+mi][(QN)*2+nj] = mfma16(AF[mi][ks], BF[nj][ks], acc[(QM)*4+mi][(QN)*2+nj]); \
  __builtin_amdgcn_s_setprio(0); } while (0)

template <int MODE, int NW>
__global__ __launch_bounds__(512, 2) void gemm256p(const u16* __restrict__ A,
                                                   const u16* __restrict__ Wbase,
                                                   Bias5 bp,
                                                   u16* __restrict__ OutBase,
                                                   int Kdim, int Nstride, int l) {
  __shared__ u16 sh[65536];   // 128 KiB: dbuf A/B during K-loop, C bounce after
  int gx = gridDim.x;
  int bid = blockIdx.x + blockIdx.y * gx;
  bid = xcd_swz(bid, gx * gridDim.y);
  int bxx = bid % gx, by = bid / gx;
  int bm = by * 256;
  int widx, bn;
  const u16* Bt; u16* Cb; const float* bias;
  if (NW == 5) {
    widx = bxx / 3;
    bn = (bxx % 3) * 256;
    int slab = widx + (widx >= 3 ? 1 : 0);
    Bt = Wbase + ((size_t)slab * L_ + l) * (size_t)D_ * D_;
    Cb = OutBase + (size_t)slab * M_ * D_;
    bias = bp.p[widx];
  } else {
    widx = 0;
    bn = bxx * 256;
    Bt = Wbase; Cb = OutBase; bias = bp.p[0];
  }
  int tid = threadIdx.x;
  int lane = tid & 63, wid = tid >> 6;
  int wr = wid >> 2, wc = wid & 3;
  int lr = lane & 15, lg = lane >> 4;

  int rr0 = tid >> 3, slot0 = tid & 7;
  int c80 = slot0 ^ (rr0 & 7);
  const u16* pA = A + (size_t)(bm + rr0) * Kdim + c80 * 8;
  const u16* pB = Bt + (size_t)(bn + rr0) * Kdim + c80 * 8;

  auto stA = [&](int buf, int h, int kt) {
    u16* base = sh + buf * 16384;
    gload16(pA + (size_t)(h * 128) * Kdim + kt * 64, &base[(h * 1024 + tid) * 8]);
    gload16(pA + (size_t)(h * 128 + 64) * Kdim + kt * 64, &base[(h * 1024 + 512 + tid) * 8]);
  };
  auto stB = [&](int buf, int h, int kt) {
    u16* base = sh + 32768 + buf * 16384;
    gload16(pB + (size_t)(h * 128) * Kdim + kt * 64, &base[(h * 1024 + tid) * 8]);
    gload16(pB + (size_t)(h * 128 + 64) * Kdim + kt * 64, &base[(h * 1024 + 512 + tid) * 8]);
  };
  auto ldA = [&](bf16x8 (&af)[4][2], int c, int qm) {
    const u16* base = sh + c * 16384;
#pragma unroll
    for (int mi = 0; mi < 4; mi++)
#pragma unroll
      for (int ks = 0; ks < 2; ks++) {
        int row = wr * 128 + qm * 64 + mi * 16 + lr;
        int c8 = ks * 4 + lg;
        af[mi][ks] = *(const bf16x8*)&base[(row * 8 + (c8 ^ (row & 7))) * 8];
      }
  };
  auto ldB = [&](bf16x8 (&bf)[2][2], int c, int qn) {
    const u16* base = sh + 32768 + c * 16384;
#pragma unroll
    for (int nj = 0; nj < 2; nj++)
#pragma unroll
      for (int ks = 0; ks < 2; ks++) {
        int row = wc * 64 + qn * 32 + nj * 16 + lr;
        int c8 = ks * 4 + lg;
        bf[nj][ks] = *(const bf16x8*)&base[(row * 8 + (c8 ^ (row & 7))) * 8];
      }
  };

  f32x4 acc[8][4] = {};
  int nt = Kdim >> 6;

  stA(0, 0, 0); stA(0, 1, 0);
  stB(0, 0, 0); stB(0, 1, 0);
  stB(1, 0, 1); stB(1, 1, 1);
  VMC4();
  __builtin_amdgcn_s_barrier();

  bf16x8 af[4][2], b0[2][2], b1[2][2];
  for (int kt = 0; kt < nt; kt += 2) {
    bool notlast = (kt + 2 < nt);
    ldA(af, 0, 0); ldB(b0, 0, 0);
    stA(1, 0, kt + 1);
    GPH_PRE(); GPH_MFMA(af, b0, 0, 0); GPH_POST();
    ldB(b1, 0, 1);
    stA(1, 1, kt + 1);
    GPH_PRE(); GPH_MFMA(af, b1, 0, 1); GPH_POST();
    ldA(af, 0, 1);
    if (notlast) stB(0, 0, kt + 2);
    GPH_PRE(); GPH_MFMA(af, b0, 1, 0); GPH_POST();
    if (notlast) { stB(0, 1, kt + 2); VMC4(); } else { VMC0(); }
    GPH_PRE_NOLDS(); GPH_MFMA(af, b1, 1, 1); GPH_POST();
    ldA(af, 1, 0); ldB(b0, 1, 0);
    if (notlast) stA(0, 0, kt + 2);
    GPH_PRE(); GPH_MFMA(af, b0, 0, 0); GPH_POST();
    ldB(b1, 1, 1);
    if (notlast) stA(0, 1, kt + 2);
    GPH_PRE(); GPH_MFMA(af, b1, 0, 1); GPH_POST();
    ldA(af, 1, 1);
    if (notlast) stB(1, 0, kt + 3);
    GPH_PRE(); GPH_MFMA(af, b0, 1, 0); GPH_POST();
    if (notlast) { stB(1, 1, kt + 3); VMC4(); } else { VMC0(); }
    GPH_PRE_NOLDS(); GPH_MFMA(af, b1, 1, 1); GPH_POST();
  }

  // ------- epilogue: bounce C through LDS, vectorized stores -------
  // element (row,col) of the 256x256 tile -> sh[row*256 + (chunk^ (row&31))*8 + (col&7)]
  int cr = (lane >> 4) * 4, cc = lane & 15;
  float scale = (NW == 5 && widx == 0) ? 0.125f : 1.0f;
#pragma unroll
  for (int nj = 0; nj < 4; nj++) {
    int col = wc * 64 + nj * 16 + cc;
    float bv = bias[bn + col];
#pragma unroll
    for (int mi = 0; mi < 8; mi++)
#pragma unroll
      for (int r = 0; r < 4; r++) {
        int row = wr * 128 + mi * 16 + cr + r;
        int chunk = (col >> 3) ^ (row & 31);
        sh[row * 256 + chunk * 8 + (col & 7)] =
            f2bf(epi_post<MODE>((acc[mi][nj][r] + bv) * scale));
      }
  }
  __syncthreads();
  {
    int row = tid >> 1, half = tid & 1;
    u16* gro = Cb + (size_t)(bm + row) * Nstride + bn + half * 128;
#pragma unroll
    for (int c = 0; c < 16; c++) {
      int lc = half * 16 + c;
      int pc = lc ^ (row & 31);
      bf16x8 v = *(const bf16x8*)&sh[row * 256 + pc * 8];
      *(bf16x8*)(gro + c * 8) = v;
    }
  }
}

// ============ 128x128 GEMM: 3-deep pipeline + LDS-bounce epilogue =
template <int MODE>
__global__ __launch_bounds__(256) void gemm_pipe(const u16* __restrict__ A,
                                                 const u16* __restrict__ Bt,
                                                 const float* __restrict__ bias,
                                                 u16* __restrict__ Cb,
                                                 int Ndim, int Kdim, int rowTileStride) {
  __shared__ u16 sh[24576];   // 48 KiB: 3x(A8K+B8K) ring; C bounce (32KB) after
  int gx = gridDim.x;
  int bid = blockIdx.x + blockIdx.y * gx;
  bid = xcd_swz(bid, gx * gridDim.y);
  int bm = (bid / gx) * rowTileStride * 128;
  int bn = (bid % gx) * 128;
  int tid = threadIdx.x;
  int lane = tid & 63, w = tid >> 6;
  int r0w = (w >> 1) * 64, c0w = (w & 1) * 64;
  int lr = lane & 15, lg = lane >> 4;

  int f0 = tid, l0 = f0 >> 3, s0 = (f0 & 7) ^ (l0 & 7);
  int row0 = (l0 << 1) | (s0 >> 2), c0s = (s0 & 3) * 8;
  int f1 = tid + 256, l1 = f1 >> 3, s1 = (f1 & 7) ^ (l1 & 7);
  int row1 = (l1 << 1) | (s1 >> 2), c1s = (s1 & 3) * 8;
  const u16* A0 = A + (size_t)(bm + row0) * Kdim + c0s;
  const u16* A1 = A + (size_t)(bm + row1) * Kdim + c1s;
  const u16* B0 = Bt + (size_t)(bn + row0) * Kdim + c0s;
  const u16* B1 = Bt + (size_t)(bn + row1) * Kdim + c1s;

  int offa[4], offb[4];
#pragma unroll
  for (int i = 0; i < 4; i++) {
    int ra = r0w + i * 16 + lr;
    int la = ra >> 1, sa = ((ra & 1) << 2) | lg;
    offa[i] = la * 64 + (sa ^ (la & 7)) * 8;
    int rb = c0w + i * 16 + lr;
    int lb = rb >> 1, sb = ((rb & 1) << 2) | lg;
    offb[i] = lb * 64 + (sb ^ (lb & 7)) * 8;
  }

  auto stage = [&](int kt, int buf) {
    int k1 = kt << 5;
    u16* ab = sh + buf * 4096;
    u16* bb = sh + 12288 + buf * 4096;
    gload16(A0 + k1, &ab[tid * 8]);
    gload16(A1 + k1, &ab[tid * 8 + 2048]);
    gload16(B0 + k1, &bb[tid * 8]);
    gload16(B1 + k1, &bb[tid * 8 + 2048]);
  };

  int nt = Kdim >> 5;
  f32x4 acc[4][4] = {};

  stage(0, 0);
  if (nt > 1) stage(1, 1);

  for (int t = 0; t < nt; t++) {
    int cb = t % 3;
    if (t + 2 < nt) {
      stage(t + 2, (t + 2) % 3);
      asm volatile("s_waitcnt vmcnt(8)" ::: "memory");
    } else if (t + 1 < nt) {
      asm volatile("s_waitcnt vmcnt(4)" ::: "memory");
    } else {
      asm volatile("s_waitcnt vmcnt(0)" ::: "memory");
    }
    __builtin_amdgcn_s_barrier();
    __builtin_amdgcn_sched_barrier(0);
    const u16* ab = sh + cb * 4096;
    const u16* bb = sh + 12288 + cb * 4096;
    bf16x8 a[4], b[4];
#pragma unroll
    for (int i = 0; i < 4; i++) a[i] = *(const bf16x8*)&ab[offa[i]];
#pragma unroll
    for (int j = 0; j < 4; j++) b[j] = *(const bf16x8*)&bb[offb[j]];
#pragma unroll
    for (int i = 0; i < 4; i++)
#pragma unroll
      for (int j = 0; j < 4; j++)
        acc[i][j] = mfma16(a[i], b[j], acc[i][j]);
    __builtin_amdgcn_sched_barrier(0);
    __builtin_amdgcn_s_barrier();
    __builtin_amdgcn_sched_barrier(0);
  }

  // ------- epilogue: bounce C (128x128) through LDS ----------------
  int cr = (lane >> 4) * 4, cc = lane & 15;
#pragma unroll
  for (int j = 0; j < 4; j++) {
    int col = c0w + j * 16 + cc;
    float bv = bias[bn + col];
#pragma unroll
    for (int i = 0; i < 4; i++)
#pragma unroll
      for (int r = 0; r < 4; r++) {
        int row = r0w + i * 16 + cr + r;
        int chunk = (col >> 3) ^ (row & 15);
        sh[row * 128 + chunk * 8 + (col & 7)] =
            f2bf(epi_post<MODE>(acc[i][j][r] + bv));
      }
  }
  __syncthreads();
  {
    int row = tid >> 1, half = tid & 1;
    u16* gro = Cb + (size_t)(bm + row) * Ndim + bn + half * 64;
#pragma unroll
    for (int c = 0; c < 8; c++) {
      int lc = half * 8 + c;
      int pc = lc ^ (row & 15);
      bf16x8 v = *(const bf16x8*)&sh[row * 128 + pc * 8];
      *(bf16x8*)(gro + c * 8) = v;
    }
  }
}

// ---------------- local windowed + global-key attention ----------
__global__ __launch_bounds__(128) void attn_local(const u16* __restrict__ qb,
                                                  const u16* __restrict__ kb_,
                                                  const u16* __restrict__ vb,
                                                  const float* __restrict__ mask,
                                                  u16* __restrict__ ao) {
  int bid = blockIdx.x + blockIdx.y * gridDim.x;
  bid = xcd_swz(bid, 1536);
  int cx = bid & 63, bh = bid >> 6;
  int c = cx >> 2, sub = cx & 3;
  int b = bh / H_, h = bh % H_;
  int tid = threadIdx.x;
  int w = tid >> 6, lane = tid & 63;
  int lr = lane & 15, lg = lane >> 4;

  __shared__ u16 vtT[64][72];
  __shared__ u16 plds[2][32][72];
  __shared__ unsigned char vflag[576];

  int base_off = sub * 64;
  int kwin0 = c * W_ - W_;
  for (int i = tid; i < 576; i += 128) {
    int kp = kwin0 + base_off + i;
    vflag[i] = (kp >= 0 && kp < S_ && mask[b * S_ + kp] == 0.0f) ? 1 : 0;
  }

  size_t hoff = (size_t)b * S_ * D_ + h * DH_;
  int qrow0 = c * W_ + base_off + w * 32;
  bf16x8 aq[2][2];
#pragma unroll
  for (int fi = 0; fi < 2; fi++)
#pragma unroll
    for (int ks = 0; ks < 2; ks++)
      aq[fi][ks] = *(const bf16x8*)(qb + hoff + (size_t)(qrow0 + fi * 16 + lr) * D_ + ks * 32 + lg * 8);

  float ls[2][4];
  f32x4 o[2][4] = {};
#pragma unroll
  for (int fi = 0; fi < 2; fi++)
#pragma unroll
    for (int r = 0; r < 4; r++) ls[fi][r] = 0.f;

  int stg_k4 = tid >> 3, stg_j = tid & 7;
  int stg_dh0 = stg_j * 8;

  for (int kb = 0; kb <= 9; kb++) {
    int kstart = 0;
    if (kb > 0) {
      kstart = kwin0 + base_off + (kb - 1) * 64;
      if (kstart + 64 <= 0 || kstart >= S_) continue;
    }
    __syncthreads();
    {
#pragma unroll
      for (int p = 0; p < 4; p++) {
        int key = p * 16 + stg_k4;
        int kp = (kb ? kstart : 0) + key;
        bf16x8 row = *(const bf16x8*)(vb + hoff + (size_t)kp * D_ + stg_dh0);
        u16* basep = &vtT[stg_dh0][key ^ (stg_j << 3)];
#pragma unroll
        for (int e = 0; e < 8; e++) basep[e * 72] = (u16)row[e];
      }
    }
    __syncthreads();

    bf16x8 bk0[4], bk1[4];
#pragma unroll
    for (int nj = 0; nj < 4; nj++) {
      int kp = (kb ? kstart : 0) + nj * 16 + lr;
      const u16* ks8 = kb_ + hoff + (size_t)kp * D_ + lg * 8;
      bk0[nj] = *(const bf16x8*)(ks8);
      bk1[nj] = *(const bf16x8*)(ks8 + 32);
    }
    f32x4 sc[2][4];
#pragma unroll
    for (int fi = 0; fi < 2; fi++)
#pragma unroll
      for (int nj = 0; nj < 4; nj++) {
        f32x4 t = {};
        t = mfma16(aq[fi][0], bk0[nj], t);
        t = mfma16(aq[fi][1], bk1[nj], t);
        sc[fi][nj] = t;
      }

    if (kb >= 2 && kb <= 8) {
#pragma unroll
      for (int nj = 0; nj < 4; nj++) {
        bool kv = vflag[(kb - 1) * 64 + nj * 16 + lr] != 0;
#pragma unroll
        for (int fi = 0; fi < 2; fi++)
#pragma unroll
          for (int r = 0; r < 4; r++)
            sc[fi][nj][r] = kv ? sc[fi][nj][r] : NEGV;
      }
    } else if (kb > 0) {
#pragma unroll
      for (int nj = 0; nj < 4; nj++) {
        int fidx = (kb - 1) * 64 + nj * 16 + lr;
        int koff = base_off + fidx;
        bool kv = vflag[fidx] != 0;
#pragma unroll
        for (int fi = 0; fi < 2; fi++)
#pragma unroll
          for (int r = 0; r < 4; r++) {
            int wq = base_off + w * 32 + fi * 16 + lg * 4 + r;
            if (!(kv && koff >= wq && koff <= wq + 2 * W_)) sc[fi][nj][r] = NEGV;
          }
      }
    }

#pragma unroll
    for (int fi = 0; fi < 2; fi++)
#pragma unroll
      for (int r = 0; r < 4; r++) {
        float ps = 0.f;
#pragma unroll
        for (int nj = 0; nj < 4; nj++) {
          float p = __expf(sc[fi][nj][r]);
          sc[fi][nj][r] = p;
          ps += p;
        }
#pragma unroll
        for (int d = 1; d < 16; d <<= 1) ps += __shfl_xor(ps, d);
        ls[fi][r] += ps;
      }

#pragma unroll
    for (int fi = 0; fi < 2; fi++)
#pragma unroll
      for (int nj = 0; nj < 4; nj++)
#pragma unroll
        for (int r = 0; r < 4; r++)
          plds[w][fi * 16 + lg * 4 + r][nj * 16 + lr] = f2bf(sc[fi][nj][r]);
    asm volatile("s_waitcnt lgkmcnt(0)" ::: "memory");
    __builtin_amdgcn_sched_barrier(0);

    bf16x8 ap[2][2];
#pragma unroll
    for (int fi = 0; fi < 2; fi++)
#pragma unroll
      for (int ks = 0; ks < 2; ks++)
        ap[fi][ks] = *(const bf16x8*)&plds[w][fi * 16 + lr][ks * 32 + lg * 8];
#pragma unroll
    for (int dj = 0; dj < 4; dj++) {
      int xr = ((dj * 16 + lr) >> 3) & 7;
#pragma unroll
      for (int ks = 0; ks < 2; ks++) {
        bf16x8 bv = *(const bf16x8*)&vtT[dj * 16 + lr][(ks * 32 + lg * 8) ^ (xr << 3)];
        o[0][dj] = mfma16(ap[0][ks], bv, o[0][dj]);
        o[1][dj] = mfma16(ap[1][ks], bv, o[1][dj]);
      }
    }
  }

#pragma unroll
  for (int fi = 0; fi < 2; fi++)
#pragma unroll
    for (int dj = 0; dj < 4; dj++)
#pragma unroll
      for (int r = 0; r < 4; r++) {
        int row = qrow0 + fi * 16 + lg * 4 + r;
        float v = o[fi][dj][r] / ls[fi][r];
        ao[hoff + (size_t)row * D_ + dj * 16 + lr] = f2bf(v);
      }
}

// ---------------- global attention, split-K partials -------------
__global__ __launch_bounds__(128) void attn_gsplit(const u16* __restrict__ qg,
                                                   const u16* __restrict__ kg,
                                                   const u16* __restrict__ vg,
                                                   float* __restrict__ opart,
                                                   float* __restrict__ lpart) {
  int sp = blockIdx.x, bh = blockIdx.y;
  int b = bh / H_, h = bh % H_;
  int tid = threadIdx.x, w = tid >> 6, lane = tid & 63;
  int lr = lane & 15, lg = lane >> 4;
  __shared__ u16 vtT[64][72];
  __shared__ u16 plds[2][32][72];
  size_t hoff = (size_t)b * S_ * D_ + h * DH_;
  int qrow0 = w * 32;
  bf16x8 aq[2][2];
#pragma unroll
  for (int fi = 0; fi < 2; fi++)
#pragma unroll
    for (int ks = 0; ks < 2; ks++)
      aq[fi][ks] = *(const bf16x8*)(qg + hoff + (size_t)(qrow0 + fi * 16 + lr) * D_ + ks * 32 + lg * 8);
  float ls[2][4];
  f32x4 o[2][4] = {};
#pragma unroll
  for (int fi = 0; fi < 2; fi++)
#pragma unroll
    for (int r = 0; r < 4; r++) ls[fi][r] = 0.f;

  int stg_k4 = tid >> 3, stg_j = tid & 7;
  int stg_dh0 = stg_j * 8;

  for (int kb = 0; kb < 4; kb++) {
    int kstart = sp * 256 + kb * 64;
    __syncthreads();
#pragma unroll
    for (int p = 0; p < 4; p++) {
      int key = p * 16 + stg_k4;
      bf16x8 row = *(const bf16x8*)(vg + hoff + (size_t)(kstart + key) * D_ + stg_dh0);
      u16* basep = &vtT[stg_dh0][key ^ (stg_j << 3)];
#pragma unroll
      for (int e = 0; e < 8; e++) basep[e * 72] = (u16)row[e];
    }
    __syncthreads();

    bf16x8 bk0[4], bk1[4];
#pragma unroll
    for (int nj = 0; nj < 4; nj++) {
      const u16* ks8 = kg + hoff + (size_t)(kstart + nj * 16 + lr) * D_ + lg * 8;
      bk0[nj] = *(const bf16x8*)(ks8);
      bk1[nj] = *(const bf16x8*)(ks8 + 32);
    }
    f32x4 sc[2][4];
#pragma unroll
    for (int fi = 0; fi < 2; fi++)
#pragma unroll
      for (int nj = 0; nj < 4; nj++) {
        f32x4 t = {};
        t = mfma16(aq[fi][0], bk0[nj], t);
        t = mfma16(aq[fi][1], bk1[nj], t);
        sc[fi][nj] = t;
      }
#pragma unroll
    for (int fi = 0; fi < 2; fi++)
#pragma unroll
      for (int r = 0; r < 4; r++) {
        float ps = 0.f;
#pragma unroll
        for (int nj = 0; nj < 4; nj++) {
          float p = __expf(sc[fi][nj][r]);
          sc[fi][nj][r] = p;
          ps += p;
        }
#pragma unroll
        for (int d = 1; d < 16; d <<= 1) ps += __shfl_xor(ps, d);
        ls[fi][r] += ps;
      }
#pragma unroll
    for (int fi = 0; fi < 2; fi++)
#pragma unroll
      for (int nj = 0; nj < 4; nj++)
#pragma unroll
        for (int r = 0; r < 4; r++)
          plds[w][fi * 16 + lg * 4 + r][nj * 16 + lr] = f2bf(sc[fi][nj][r]);
    asm volatile("s_waitcnt lgkmcnt(0)" ::: "memory");
    __builtin_amdgcn_sched_barrier(0);
    bf16x8 ap[2][2];
#pragma unroll
    for (int fi = 0; fi < 2; fi++)
#pragma unroll
      for (int ks = 0; ks < 2; ks++)
        ap[fi][ks] = *(const bf16x8*)&plds[w][fi * 16 + lr][ks * 32 + lg * 8];
#pragma unroll
    for (int dj = 0; dj < 4; dj++) {
      int xr = ((dj * 16 + lr) >> 3) & 7;
#pragma unroll
      for (int ks = 0; ks < 2; ks++) {
        bf16x8 bv = *(const bf16x8*)&vtT[dj * 16 + lr][(ks * 32 + lg * 8) ^ (xr << 3)];
        o[0][dj] = mfma16(ap[0][ks], bv, o[0][dj]);
        o[1][dj] = mfma16(ap[1][ks], bv, o[1][dj]);
      }
    }
  }

  size_t pbase = (size_t)(bh * NSPLIT + sp) * 64;
#pragma unroll
  for (int fi = 0; fi < 2; fi++)
#pragma unroll
    for (int r = 0; r < 4; r++) {
      int row = qrow0 + fi * 16 + lg * 4 + r;
      if (lr == 0) lpart[pbase + row] = ls[fi][r];
#pragma unroll
      for (int dj = 0; dj < 4; dj++)
        opart[(pbase + row) * 64 + dj * 16 + lr] = o[fi][dj][r];
    }
}

// ---------------- combine split-K partials (plain sums) ----------
__global__ __launch_bounds__(256) void attn_gcombine(const float* __restrict__ opart,
                                                     const float* __restrict__ lpart,
                                                     u16* __restrict__ ao) {
  int bh = blockIdx.x;
  int b = bh / H_, h = bh % H_;
  int t = threadIdx.x;
  __shared__ float lt[64];
  if (t < 64) {
    float lsum = 0.f;
#pragma unroll
    for (int sp = 0; sp < NSPLIT; sp++)
      lsum += lpart[(size_t)(bh * NSPLIT + sp) * 64 + t];
    lt[t] = lsum;
  }
  __syncthreads();
  int row = t >> 2, c0 = (t & 3) * 16;
  float acc[16] = {};
  for (int sp = 0; sp < NSPLIT; sp++) {
    const float* op = opart + ((size_t)(bh * NSPLIT + sp) * 64 + row) * 64 + c0;
#pragma unroll
    for (int j = 0; j < 16; j++) acc[j] += op[j];
  }
  float inv = 1.f / lt[row];
  size_t hoff = (size_t)b * S_ * D_ + h * DH_;
#pragma unroll
  for (int j = 0; j < 16; j++)
    ao[hoff + (size_t)row * D_ + c0 + j] = f2bf(acc[j] * inv);
}

// ---------------- residual + LayerNorm (bf16 in/out) -------------
__global__ __launch_bounds__(192) void ln_b(const u16* __restrict__ x,
                                            const u16* __restrict__ res,
                                            const float* __restrict__ gg,
                                            const float* __restrict__ bb,
                                            u16* __restrict__ outb,
                                            float* __restrict__ outf) {
  int row = blockIdx.x, t = threadIdx.x;
  const u16* xr = x + (size_t)row * D_;
  const u16* rr = res + (size_t)row * D_;
  u16x4 xv = *(const u16x4*)&xr[t * 4];
  u16x4 rv = *(const u16x4*)&rr[t * 4];
  float v[4];
#pragma unroll
  for (int e = 0; e < 4; e++) v[e] = b2f(xv[e]) + b2f(rv[e]);
  __shared__ float sha[3], shb[3];
  float s = v[0] + v[1] + v[2] + v[3];
#pragma unroll
  for (int d = 1; d < 64; d <<= 1) s += __shfl_xor(s, d);
  if ((t & 63) == 0) sha[t >> 6] = s;
  __syncthreads();
  float mu = (sha[0] + sha[1] + sha[2]) * (1.f / 768.f);
  float dd[4], s2 = 0.f;
#pragma unroll
  for (int e = 0; e < 4; e++) { dd[e] = v[e] - mu; s2 += dd[e] * dd[e]; }
#pragma unroll
  for (int d = 1; d < 64; d <<= 1) s2 += __shfl_xor(s2, d);
  if ((t & 63) == 0) shb[t >> 6] = s2;
  __syncthreads();
  float var = (shb[0] + shb[1] + shb[2]) * (1.f / 768.f);
  float rs = rsqrtf(var + 1e-5f);
  float4 gv = *(const float4*)&gg[t * 4];
  float4 bv = *(const float4*)&bb[t * 4];
  float y0 = dd[0] * rs * gv.x + bv.x;
  float y1 = dd[1] * rs * gv.y + bv.y;
  float y2 = dd[2] * rs * gv.z + bv.z;
  float y3 = dd[3] * rs * gv.w + bv.w;
  u16x4 ov;
  ov[0] = f2bf(y0); ov[1] = f2bf(y1); ov[2] = f2bf(y2); ov[3] = f2bf(y3);
  *(u16x4*)&outb[(size_t)row * D_ + t * 4] = ov;
  if (outf) {
    float4 of = {y0, y1, y2, y3};
    *(float4*)&outf[(size_t)row * D_ + t * 4] = of;
  }
}

// =================================================================
extern "C" void kernel_launch(void* const* d_in, const int* in_sizes, int n_in,
                              void* d_out, int out_size, void* d_ws, size_t ws_size,
                              hipStream_t stream) {
  (void)in_sizes; (void)n_in; (void)out_size; (void)ws_size;
  const float* hidden = (const float*)d_in[0];
  const float* mask   = (const float*)d_in[1];
  const float* Wq  = (const float*)d_in[4];   const float* bq  = (const float*)d_in[5];
  const float* Wk  = (const float*)d_in[6];   const float* bk  = (const float*)d_in[7];
  const float* Wv  = (const float*)d_in[8];   const float* bv  = (const float*)d_in[9];
  const float* Wqg = (const float*)d_in[10];  const float* bqg = (const float*)d_in[11];
  const float* Wkg = (const float*)d_in[12];  const float* bkg = (const float*)d_in[13];
  const float* Wvg = (const float*)d_in[14];  const float* bvg = (const float*)d_in[15];
  const float* Wo  = (const float*)d_in[16];  const float* bo  = (const float*)d_in[17];
  const float* Wi  = (const float*)d_in[18];  const float* bi  = (const float*)d_in[19];
  const float* Wo2 = (const float*)d_in[20];  const float* bo2 = (const float*)d_in[21];
  const float* ln1g = (const float*)d_in[22]; const float* ln1b = (const float*)d_in[23];
  const float* ln2g = (const float*)d_in[24]; const float* ln2b = (const float*)d_in[25];

  char* ws = (char*)d_ws;
  size_t off = 0;
  auto alloc = [&](size_t bytes) -> void* {
    void* p = ws + off;
    off += (bytes + 255) & ~(size_t)255;
    return p;
  };
  const size_t DD = (size_t)D_ * D_;
  const size_t DF = (size_t)D_ * FF_;
  u16* Wt = (u16*)alloc((7 * L_ * DD + 2 * L_ * DF) * 2);
  u16* wqg_t = Wt + 3 * L_ * DD;
  u16* wo_t  = Wt + 6 * L_ * DD;
  u16* wi_t  = Wt + 7 * L_ * DD;
  u16* wo2_t = Wt + 7 * L_ * DD + L_ * DF;

  u16* X0 = (u16*)alloc((size_t)M_ * D_ * 2);
  u16* X1 = (u16*)alloc((size_t)M_ * D_ * 2);
  u16* tb = (u16*)alloc((size_t)M_ * D_ * 2);
  u16* B_bf = (u16*)alloc((size_t)M_ * FF_ * 2);
  u16* qbf  = (u16*)alloc((size_t)M_ * D_ * 2);
  u16* kbf  = (u16*)alloc((size_t)M_ * D_ * 2);
  u16* vbf  = (u16*)alloc((size_t)M_ * D_ * 2);
  u16* qgbf = (u16*)alloc((size_t)M_ * D_ * 2);
  u16* kgbf = (u16*)alloc((size_t)M_ * D_ * 2);
  u16* vgbf = (u16*)alloc((size_t)M_ * D_ * 2);
  u16* aobf = (u16*)alloc((size_t)M_ * D_ * 2);
  float* opart = (float*)alloc((size_t)B_ * H_ * NSPLIT * 64 * 64 * 4);
  float* lpart = (float*)alloc((size_t)B_ * H_ * NSPLIT * 64 * 4);

  dim3 tb32(32, 8);
  Ptr7 wp;
  wp.p[0] = Wq; wp.p[1] = Wk; wp.p[2] = Wv; wp.p[3] = Wqg;
  wp.p[4] = Wkg; wp.p[5] = Wvg; wp.p[6] = Wo;
  wtrans7<<<dim3(24, 24, 14), tb32, 0, stream>>>(wp, Wt);
  wtrans<<<dim3(96, 24, 2), tb32, 0, stream>>>(Wi,  wi_t,  D_, FF_);
  wtrans<<<dim3(24, 96, 2), tb32, 0, stream>>>(Wo2, wo2_t, FF_, D_);

  conv_b<<<(M_ * D_ / 4 + 255) / 256, 256, 0, stream>>>(hidden, X0, M_ * D_ / 4);

  for (int l = 0; l < L_; l++) {
    size_t wdd = (size_t)l * DD;
    size_t wdf = (size_t)l * DF;
    dim3 g64(6, 64), g2(6, 2);

    Bias5 bp;
    bp.p[0] = bq  + l * D_;
    bp.p[1] = bk  + l * D_;
    bp.p[2] = bv  + l * D_;
    bp.p[3] = bkg + l * D_;
    bp.p[4] = bvg + l * D_;
    gemm256p<1, 5><<<dim3(15, 32), 512, 0, stream>>>(X0, Wt, bp, qbf, D_, D_, l);
    gemm_pipe<2><<<g2, 256, 0, stream>>>(X0, wqg_t + wdd, bqg + l * D_, qgbf, D_, D_, 32);

    attn_local<<<dim3((S_ / W_) * 4, B_ * H_), 128, 0, stream>>>(qbf, kbf, vbf, mask, aobf);
    attn_gsplit<<<dim3(NSPLIT, B_ * H_), 128, 0, stream>>>(qgbf, kgbf, vgbf, opart, lpart);
    attn_gcombine<<<B_ * H_, 256, 0, stream>>>(opart, lpart, aobf);

    gemm_pipe<1><<<g64, 256, 0, stream>>>(aobf, wo_t + wdd, bo + l * D_, tb, D_, D_, 1);
    ln_b<<<M_, 192, 0, stream>>>(tb, X0, ln1g + l * D_, ln1b + l * D_, X1, nullptr);

    Bias5 bpi; bpi.p[0] = bi + l * FF_;
    gemm256p<3, 1><<<dim3(12, 32), 512, 0, stream>>>(X1, wi_t + wdf, bpi, B_bf, D_, FF_, 0);
    gemm_pipe<1><<<g64, 256, 0, stream>>>(B_bf, wo2_t + wdf, bo2 + l * D_, tb, D_, FF_, 1);

    ln_b<<<M_, 192, 0, stream>>>(tb, X1, ln2g + l * D_, ln2b + l * D_, X0,
                                 (l == L_ - 1) ? (float*)d_out : nullptr);
  }
}

// Round 11
// 704.176 us; speedup vs baseline: 1.0517x; 1.0517x over previous
//
#include <hip/hip_runtime.h>

#define B_ 2
#define S_ 4096
#define D_ 768
#define H_ 12
#define DH_ 64
#define W_ 256
#define G_ 64
#define FF_ 3072
#define L_ 2
#define M_ (B_*S_)
#define NEGV -1e9f
#define NSPLIT 16

typedef short bf16x8 __attribute__((ext_vector_type(8)));
typedef float f32x4 __attribute__((ext_vector_type(4)));
typedef unsigned short u16;
typedef unsigned short u16x4 __attribute__((ext_vector_type(4)));

__device__ __forceinline__ u16 f2bf(float f) {
  union { float f; unsigned u; } a; a.f = f;
  unsigned r = a.u + 0x7FFFu + ((a.u >> 16) & 1u);
  return (u16)(r >> 16);
}
__device__ __forceinline__ float b2f(u16 u) {
  union { unsigned u; float f; } a; a.u = ((unsigned)u) << 16;
  return a.f;
}

__device__ __forceinline__ f32x4 mfma16(bf16x8 a, bf16x8 b, f32x4 c) {
  return __builtin_amdgcn_mfma_f32_16x16x32_bf16(a, b, c, 0, 0, 0);
}

__device__ __forceinline__ void gload16(const u16* g, u16* l) {
  __builtin_amdgcn_global_load_lds((const __attribute__((address_space(1))) void*)g,
                                   (__attribute__((address_space(3))) void*)l, 16, 0, 0);
}

__device__ __forceinline__ int xcd_swz(int bid, int nwg) {
  if ((nwg & 7) == 0) {
    int cpx = nwg >> 3;
    bid = (bid & 7) * cpx + (bid >> 3);
  }
  return bid;
}

// ---------------- batched weight transpose (7 DxD slabs) ---------
struct Ptr7 { const float* p[7]; };
__global__ __launch_bounds__(256) void wtrans7(Ptr7 in, u16* __restrict__ out) {
  __shared__ float tile[32][33];
  int z = blockIdx.z;
  int slab = z >> 1, l = z & 1;
  const float* src = in.p[slab] + (size_t)l * D_ * D_;
  u16* dst = out + (size_t)z * D_ * D_;
  int k0 = blockIdx.y * 32, n0 = blockIdx.x * 32;
  int tx = threadIdx.x, ty = threadIdx.y;
#pragma unroll
  for (int i = 0; i < 4; i++)
    tile[ty + i*8][tx] = src[(size_t)(k0 + ty + i*8) * D_ + n0 + tx];
  __syncthreads();
#pragma unroll
  for (int i = 0; i < 4; i++)
    dst[(size_t)(n0 + ty + i*8) * D_ + k0 + tx] = f2bf(tile[tx][ty + i*8]);
}

__global__ __launch_bounds__(256) void wtrans(const float* __restrict__ in,
                                              u16* __restrict__ out, int K, int N) {
  __shared__ float tile[32][33];
  size_t base = (size_t)blockIdx.z * K * N;
  int k0 = blockIdx.y * 32, n0 = blockIdx.x * 32;
  int tx = threadIdx.x, ty = threadIdx.y;
#pragma unroll
  for (int i = 0; i < 4; i++)
    tile[ty + i*8][tx] = in[base + (size_t)(k0 + ty + i*8) * N + n0 + tx];
  __syncthreads();
#pragma unroll
  for (int i = 0; i < 4; i++)
    out[base + (size_t)(n0 + ty + i*8) * K + k0 + tx] = f2bf(tile[tx][ty + i*8]);
}

// ---------------- f32 -> bf16 convert ----------------------------
__global__ __launch_bounds__(256) void conv_b(const float* __restrict__ in,
                                              u16* __restrict__ outb, int n4) {
  int i = blockIdx.x * 256 + threadIdx.x;
  if (i >= n4) return;
  float4 v = ((const float4*)in)[i];
  u16x4 o;
  o[0] = f2bf(v.x); o[1] = f2bf(v.y); o[2] = f2bf(v.z); o[3] = f2bf(v.w);
  ((u16x4*)outb)[i] = o;
}

template <int MODE>
__device__ __forceinline__ float epi_post(float v) {
  if (MODE == 2) return v * 0.125f;
  if (MODE == 3) {
    float y = 0.79788456f * (v + 0.044715f * v * v * v);
    float e = __expf(fminf(2.f * y, 20.f));
    return v * e / (e + 1.f);
  }
  return v;
}

struct Bias5 { const float* p[5]; };

// ============ 256x256 8-PHASE GEMM (direct-store epilogue) ========
#define VMC4() asm volatile("s_waitcnt vmcnt(4)" ::: "memory")
#define VMC0() asm volatile("s_waitcnt vmcnt(0)" ::: "memory")
#define GPH_PRE() do { __builtin_amdgcn_s_barrier(); \
  asm volatile("s_waitcnt lgkmcnt(0)" ::: "memory"); \
  __builtin_amdgcn_sched_barrier(0); } while (0)
#define GPH_PRE_NOLDS() do { __builtin_amdgcn_s_barrier(); \
  __builtin_amdgcn_sched_barrier(0); } while (0)
#define GPH_POST() do { __builtin_amdgcn_sched_barrier(0); \
  __builtin_amdgcn_s_barrier(); } while (0)
#define GPH_MFMA(AF, BF, QM, QN) do { \
  __builtin_amdgcn_s_setprio(1); \
  _Pragma("unroll") for (int mi = 0; mi < 4; mi++) \
  _Pragma("unroll") for (int nj = 0; nj < 2; nj++) \
  _Pragma("unroll") for (int ks = 0; ks < 2; ks++) \
    acc[(QM)*4+mi][(QN)*2+nj] = mfma16(AF[mi][ks], BF[nj][ks], acc[(QM)*4+mi][(QN)*2+nj]); \
  __builtin_amdgcn_s_setprio(0); } while (0)

template <int MODE, int NW>
__global__ __launch_bounds__(512, 2) void gemm256p(const u16* __restrict__ A,
                                                   const u16* __restrict__ Wbase,
                                                   Bias5 bp,
                                                   u16* __restrict__ OutBase,
                                                   int Kdim, int Nstride, int l) {
  __shared__ u16 sh[65536];
  int gx = gridDim.x;
  int bid = blockIdx.x + blockIdx.y * gx;
  bid = xcd_swz(bid, gx * gridDim.y);
  int bxx = bid % gx, by = bid / gx;
  int bm = by * 256;
  int widx, bn;
  const u16* Bt; u16* Cb; const float* bias;
  if (NW == 5) {
    widx = bxx / 3;
    bn = (bxx % 3) * 256;
    int slab = widx + (widx >= 3 ? 1 : 0);
    Bt = Wbase + ((size_t)slab * L_ + l) * (size_t)D_ * D_;
    Cb = OutBase + (size_t)slab * M_ * D_;
    bias = bp.p[widx];
  } else {
    widx = 0;
    bn = bxx * 256;
    Bt = Wbase; Cb = OutBase; bias = bp.p[0];
  }
  int tid = threadIdx.x;
  int lane = tid & 63, wid = tid >> 6;
  int wr = wid >> 2, wc = wid & 3;
  int lr = lane & 15, lg = lane >> 4;

  int rr0 = tid >> 3, slot0 = tid & 7;
  int c80 = slot0 ^ (rr0 & 7);
  const u16* pA = A + (size_t)(bm + rr0) * Kdim + c80 * 8;
  const u16* pB = Bt + (size_t)(bn + rr0) * Kdim + c80 * 8;

  auto stA = [&](int buf, int h, int kt) {
    u16* base = sh + buf * 16384;
    gload16(pA + (size_t)(h * 128) * Kdim + kt * 64, &base[(h * 1024 + tid) * 8]);
    gload16(pA + (size_t)(h * 128 + 64) * Kdim + kt * 64, &base[(h * 1024 + 512 + tid) * 8]);
  };
  auto stB = [&](int buf, int h, int kt) {
    u16* base = sh + 32768 + buf * 16384;
    gload16(pB + (size_t)(h * 128) * Kdim + kt * 64, &base[(h * 1024 + tid) * 8]);
    gload16(pB + (size_t)(h * 128 + 64) * Kdim + kt * 64, &base[(h * 1024 + 512 + tid) * 8]);
  };
  auto ldA = [&](bf16x8 (&af)[4][2], int c, int qm) {
    const u16* base = sh + c * 16384;
#pragma unroll
    for (int mi = 0; mi < 4; mi++)
#pragma unroll
      for (int ks = 0; ks < 2; ks++) {
        int row = wr * 128 + qm * 64 + mi * 16 + lr;
        int c8 = ks * 4 + lg;
        af[mi][ks] = *(const bf16x8*)&base[(row * 8 + (c8 ^ (row & 7))) * 8];
      }
  };
  auto ldB = [&](bf16x8 (&bf)[2][2], int c, int qn) {
    const u16* base = sh + 32768 + c * 16384;
#pragma unroll
    for (int nj = 0; nj < 2; nj++)
#pragma unroll
      for (int ks = 0; ks < 2; ks++) {
        int row = wc * 64 + qn * 32 + nj * 16 + lr;
        int c8 = ks * 4 + lg;
        bf[nj][ks] = *(const bf16x8*)&base[(row * 8 + (c8 ^ (row & 7))) * 8];
      }
  };

  f32x4 acc[8][4] = {};
  int nt = Kdim >> 6;

  stA(0, 0, 0); stA(0, 1, 0);
  stB(0, 0, 0); stB(0, 1, 0);
  stB(1, 0, 1); stB(1, 1, 1);
  VMC4();
  __builtin_amdgcn_s_barrier();

  bf16x8 af[4][2], b0[2][2], b1[2][2];
  for (int kt = 0; kt < nt; kt += 2) {
    bool notlast = (kt + 2 < nt);
    ldA(af, 0, 0); ldB(b0, 0, 0);
    stA(1, 0, kt + 1);
    GPH_PRE(); GPH_MFMA(af, b0, 0, 0); GPH_POST();
    ldB(b1, 0, 1);
    stA(1, 1, kt + 1);
    GPH_PRE(); GPH_MFMA(af, b1, 0, 1); GPH_POST();
    ldA(af, 0, 1);
    if (notlast) stB(0, 0, kt + 2);
    GPH_PRE(); GPH_MFMA(af, b0, 1, 0); GPH_POST();
    if (notlast) { stB(0, 1, kt + 2); VMC4(); } else { VMC0(); }
    GPH_PRE_NOLDS(); GPH_MFMA(af, b1, 1, 1); GPH_POST();
    ldA(af, 1, 0); ldB(b0, 1, 0);
    if (notlast) stA(0, 0, kt + 2);
    GPH_PRE(); GPH_MFMA(af, b0, 0, 0); GPH_POST();
    ldB(b1, 1, 1);
    if (notlast) stA(0, 1, kt + 2);
    GPH_PRE(); GPH_MFMA(af, b1, 0, 1); GPH_POST();
    ldA(af, 1, 1);
    if (notlast) stB(1, 0, kt + 3);
    GPH_PRE(); GPH_MFMA(af, b0, 1, 0); GPH_POST();
    if (notlast) { stB(1, 1, kt + 3); VMC4(); } else { VMC0(); }
    GPH_PRE_NOLDS(); GPH_MFMA(af, b1, 1, 1); GPH_POST();
  }

  int r0 = bm + wr * 128, c0 = bn + wc * 64;
  int cr = (lane >> 4) * 4, cc = lane & 15;
  float sc = (NW == 5 && widx == 0) ? 0.125f : 1.0f;
#pragma unroll
  for (int nj = 0; nj < 4; nj++) {
    int col = c0 + nj * 16 + cc;
    float bv = bias[col];
#pragma unroll
    for (int mi = 0; mi < 8; mi++)
#pragma unroll
      for (int r = 0; r < 4; r++) {
        size_t off = (size_t)(r0 + mi * 16 + cr + r) * Nstride + col;
        Cb[off] = f2bf(epi_post<MODE>((acc[mi][nj][r] + bv) * sc));
      }
  }
}

// ============ 128x128 GEMM: 3-deep pipeline + LDS-bounce epilogue =
template <int MODE>
__global__ __launch_bounds__(256) void gemm_pipe(const u16* __restrict__ A,
                                                 const u16* __restrict__ Bt,
                                                 const float* __restrict__ bias,
                                                 u16* __restrict__ Cb,
                                                 int Ndim, int Kdim, int rowTileStride) {
  __shared__ u16 sh[24576];
  int gx = gridDim.x;
  int bid = blockIdx.x + blockIdx.y * gx;
  bid = xcd_swz(bid, gx * gridDim.y);
  int bm = (bid / gx) * rowTileStride * 128;
  int bn = (bid % gx) * 128;
  int tid = threadIdx.x;
  int lane = tid & 63, w = tid >> 6;
  int r0w = (w >> 1) * 64, c0w = (w & 1) * 64;
  int lr = lane & 15, lg = lane >> 4;

  int f0 = tid, l0 = f0 >> 3, s0 = (f0 & 7) ^ (l0 & 7);
  int row0 = (l0 << 1) | (s0 >> 2), c0s = (s0 & 3) * 8;
  int f1 = tid + 256, l1 = f1 >> 3, s1 = (f1 & 7) ^ (l1 & 7);
  int row1 = (l1 << 1) | (s1 >> 2), c1s = (s1 & 3) * 8;
  const u16* A0 = A + (size_t)(bm + row0) * Kdim + c0s;
  const u16* A1 = A + (size_t)(bm + row1) * Kdim + c1s;
  const u16* B0 = Bt + (size_t)(bn + row0) * Kdim + c0s;
  const u16* B1 = Bt + (size_t)(bn + row1) * Kdim + c1s;

  int offa[4], offb[4];
#pragma unroll
  for (int i = 0; i < 4; i++) {
    int ra = r0w + i * 16 + lr;
    int la = ra >> 1, sa = ((ra & 1) << 2) | lg;
    offa[i] = la * 64 + (sa ^ (la & 7)) * 8;
    int rb = c0w + i * 16 + lr;
    int lb = rb >> 1, sb = ((rb & 1) << 2) | lg;
    offb[i] = lb * 64 + (sb ^ (lb & 7)) * 8;
  }

  auto stage = [&](int kt, int buf) {
    int k1 = kt << 5;
    u16* ab = sh + buf * 4096;
    u16* bb = sh + 12288 + buf * 4096;
    gload16(A0 + k1, &ab[tid * 8]);
    gload16(A1 + k1, &ab[tid * 8 + 2048]);
    gload16(B0 + k1, &bb[tid * 8]);
    gload16(B1 + k1, &bb[tid * 8 + 2048]);
  };

  int nt = Kdim >> 5;
  f32x4 acc[4][4] = {};

  stage(0, 0);
  if (nt > 1) stage(1, 1);

  for (int t = 0; t < nt; t++) {
    int cb = t % 3;
    if (t + 2 < nt) {
      stage(t + 2, (t + 2) % 3);
      asm volatile("s_waitcnt vmcnt(8)" ::: "memory");
    } else if (t + 1 < nt) {
      asm volatile("s_waitcnt vmcnt(4)" ::: "memory");
    } else {
      asm volatile("s_waitcnt vmcnt(0)" ::: "memory");
    }
    __builtin_amdgcn_s_barrier();
    __builtin_amdgcn_sched_barrier(0);
    const u16* ab = sh + cb * 4096;
    const u16* bb = sh + 12288 + cb * 4096;
    bf16x8 a[4], b[4];
#pragma unroll
    for (int i = 0; i < 4; i++) a[i] = *(const bf16x8*)&ab[offa[i]];
#pragma unroll
    for (int j = 0; j < 4; j++) b[j] = *(const bf16x8*)&bb[offb[j]];
#pragma unroll
    for (int i = 0; i < 4; i++)
#pragma unroll
      for (int j = 0; j < 4; j++)
        acc[i][j] = mfma16(a[i], b[j], acc[i][j]);
    __builtin_amdgcn_sched_barrier(0);
    __builtin_amdgcn_s_barrier();
    __builtin_amdgcn_sched_barrier(0);
  }

  int cr = (lane >> 4) * 4, cc = lane & 15;
#pragma unroll
  for (int j = 0; j < 4; j++) {
    int col = c0w + j * 16 + cc;
    float bv = bias[bn + col];
#pragma unroll
    for (int i = 0; i < 4; i++)
#pragma unroll
      for (int r = 0; r < 4; r++) {
        int row = r0w + i * 16 + cr + r;
        int chunk = (col >> 3) ^ (row & 15);
        sh[row * 128 + chunk * 8 + (col & 7)] =
            f2bf(epi_post<MODE>(acc[i][j][r] + bv));
      }
  }
  __syncthreads();
  {
    int row = tid >> 1, half = tid & 1;
    u16* gro = Cb + (size_t)(bm + row) * Ndim + bn + half * 64;
#pragma unroll
    for (int c = 0; c < 8; c++) {
      int lc = half * 8 + c;
      int pc = lc ^ (row & 15);
      bf16x8 v = *(const bf16x8*)&sh[row * 128 + pc * 8];
      *(bf16x8*)(gro + c * 8) = v;
    }
  }
}

// ---------------- local windowed + global-key attention ----------
// grid (NC*2, B*H), block 256 (4 waves, 128 q-rows per block).
// 128-row sub-block needs window koff in [sub*128, sub*128+640) -> 10 blocks + global.
__global__ __launch_bounds__(256) void attn_local(const u16* __restrict__ qb,
                                                  const u16* __restrict__ kb_,
                                                  const u16* __restrict__ vb,
                                                  const float* __restrict__ mask,
                                                  u16* __restrict__ ao) {
  int bid = blockIdx.x + blockIdx.y * gridDim.x;
  bid = xcd_swz(bid, 768);
  int cx = bid & 31, bh = bid >> 5;
  int c = cx >> 1, sub = cx & 1;
  int b = bh / H_, h = bh % H_;
  int tid = threadIdx.x;
  int w = tid >> 6, lane = tid & 63;
  int lr = lane & 15, lg = lane >> 4;

  __shared__ u16 vtT[64][72];
  __shared__ u16 plds[4][32][72];
  __shared__ unsigned char vflag[640];

  int base_off = sub * 128;
  int kwin0 = c * W_ - W_;
  for (int i = tid; i < 640; i += 256) {
    int kp = kwin0 + base_off + i;
    vflag[i] = (kp >= 0 && kp < S_ && mask[b * S_ + kp] == 0.0f) ? 1 : 0;
  }

  size_t hoff = (size_t)b * S_ * D_ + h * DH_;
  int qrow0 = c * W_ + base_off + w * 32;
  bf16x8 aq[2][2];
#pragma unroll
  for (int fi = 0; fi < 2; fi++)
#pragma unroll
    for (int ks = 0; ks < 2; ks++)
      aq[fi][ks] = *(const bf16x8*)(qb + hoff + (size_t)(qrow0 + fi * 16 + lr) * D_ + ks * 32 + lg * 8);

  float ls[2][4];
  f32x4 o[2][4] = {};
#pragma unroll
  for (int fi = 0; fi < 2; fi++)
#pragma unroll
    for (int r = 0; r < 4; r++) ls[fi][r] = 0.f;

  int stg_k = tid >> 3, stg_j = tid & 7;
  int stg_dh0 = stg_j * 8;

  for (int kb = 0; kb <= 10; kb++) {
    int kstart = 0;
    if (kb > 0) {
      kstart = kwin0 + base_off + (kb - 1) * 64;
      if (kstart + 64 <= 0 || kstart >= S_) continue;
    }
    __syncthreads();
    {
#pragma unroll
      for (int p = 0; p < 2; p++) {
        int key = p * 32 + stg_k;
        int kp = (kb ? kstart : 0) + key;
        bf16x8 row = *(const bf16x8*)(vb + hoff + (size_t)kp * D_ + stg_dh0);
        u16* basep = &vtT[stg_dh0][key ^ (stg_j << 3)];
#pragma unroll
        for (int e = 0; e < 8; e++) basep[e * 72] = (u16)row[e];
      }
    }
    __syncthreads();

    bf16x8 bk0[4], bk1[4];
#pragma unroll
    for (int nj = 0; nj < 4; nj++) {
      int kp = (kb ? kstart : 0) + nj * 16 + lr;
      const u16* ks8 = kb_ + hoff + (size_t)kp * D_ + lg * 8;
      bk0[nj] = *(const bf16x8*)(ks8);
      bk1[nj] = *(const bf16x8*)(ks8 + 32);
    }
    f32x4 sc[2][4];
#pragma unroll
    for (int fi = 0; fi < 2; fi++)
#pragma unroll
      for (int nj = 0; nj < 4; nj++) {
        f32x4 t = {};
        t = mfma16(aq[fi][0], bk0[nj], t);
        t = mfma16(aq[fi][1], bk1[nj], t);
        sc[fi][nj] = t;
      }

    if (kb >= 3 && kb <= 8) {
      // band provably satisfied (fidx >= 128 > max rq, fidx <= 511 <= min rq+512)
#pragma unroll
      for (int nj = 0; nj < 4; nj++) {
        bool kv = vflag[(kb - 1) * 64 + nj * 16 + lr] != 0;
#pragma unroll
        for (int fi = 0; fi < 2; fi++)
#pragma unroll
          for (int r = 0; r < 4; r++)
            sc[fi][nj][r] = kv ? sc[fi][nj][r] : NEGV;
      }
    } else if (kb > 0) {
#pragma unroll
      for (int nj = 0; nj < 4; nj++) {
        int fidx = (kb - 1) * 64 + nj * 16 + lr;
        bool kv = vflag[fidx] != 0;
#pragma unroll
        for (int fi = 0; fi < 2; fi++)
#pragma unroll
          for (int r = 0; r < 4; r++) {
            int rq = w * 32 + fi * 16 + lg * 4 + r;
            if (!(kv && fidx >= rq && fidx <= rq + 2 * W_)) sc[fi][nj][r] = NEGV;
          }
      }
    }

#pragma unroll
    for (int fi = 0; fi < 2; fi++)
#pragma unroll
      for (int r = 0; r < 4; r++) {
        float ps = 0.f;
#pragma unroll
        for (int nj = 0; nj < 4; nj++) {
          float p = __expf(sc[fi][nj][r]);
          sc[fi][nj][r] = p;
          ps += p;
        }
#pragma unroll
        for (int d = 1; d < 16; d <<= 1) ps += __shfl_xor(ps, d);
        ls[fi][r] += ps;
      }

#pragma unroll
    for (int fi = 0; fi < 2; fi++)
#pragma unroll
      for (int nj = 0; nj < 4; nj++)
#pragma unroll
        for (int r = 0; r < 4; r++)
          plds[w][fi * 16 + lg * 4 + r][nj * 16 + lr] = f2bf(sc[fi][nj][r]);
    asm volatile("s_waitcnt lgkmcnt(0)" ::: "memory");
    __builtin_amdgcn_sched_barrier(0);

    bf16x8 ap[2][2];
#pragma unroll
    for (int fi = 0; fi < 2; fi++)
#pragma unroll
      for (int ks = 0; ks < 2; ks++)
        ap[fi][ks] = *(const bf16x8*)&plds[w][fi * 16 + lr][ks * 32 + lg * 8];
#pragma unroll
    for (int dj = 0; dj < 4; dj++) {
      int xr = ((dj * 16 + lr) >> 3) & 7;
#pragma unroll
      for (int ks = 0; ks < 2; ks++) {
        bf16x8 bv = *(const bf16x8*)&vtT[dj * 16 + lr][(ks * 32 + lg * 8) ^ (xr << 3)];
        o[0][dj] = mfma16(ap[0][ks], bv, o[0][dj]);
        o[1][dj] = mfma16(ap[1][ks], bv, o[1][dj]);
      }
    }
  }

#pragma unroll
  for (int fi = 0; fi < 2; fi++)
#pragma unroll
    for (int dj = 0; dj < 4; dj++)
#pragma unroll
      for (int r = 0; r < 4; r++) {
        int row = qrow0 + fi * 16 + lg * 4 + r;
        float v = o[fi][dj][r] / ls[fi][r];
        ao[hoff + (size_t)row * D_ + dj * 16 + lr] = f2bf(v);
      }
}

// ---------------- global attention, split-K partials -------------
__global__ __launch_bounds__(128) void attn_gsplit(const u16* __restrict__ qg,
                                                   const u16* __restrict__ kg,
                                                   const u16* __restrict__ vg,
                                                   float* __restrict__ opart,
                                                   float* __restrict__ lpart) {
  int sp = blockIdx.x, bh = blockIdx.y;
  int b = bh / H_, h = bh % H_;
  int tid = threadIdx.x, w = tid >> 6, lane = tid & 63;
  int lr = lane & 15, lg = lane >> 4;
  __shared__ u16 vtT[64][72];
  __shared__ u16 plds[2][32][72];
  size_t hoff = (size_t)b * S_ * D_ + h * DH_;
  int qrow0 = w * 32;
  bf16x8 aq[2][2];
#pragma unroll
  for (int fi = 0; fi < 2; fi++)
#pragma unroll
    for (int ks = 0; ks < 2; ks++)
      aq[fi][ks] = *(const bf16x8*)(qg + hoff + (size_t)(qrow0 + fi * 16 + lr) * D_ + ks * 32 + lg * 8);
  float ls[2][4];
  f32x4 o[2][4] = {};
#pragma unroll
  for (int fi = 0; fi < 2; fi++)
#pragma unroll
    for (int r = 0; r < 4; r++) ls[fi][r] = 0.f;

  int stg_k4 = tid >> 3, stg_j = tid & 7;
  int stg_dh0 = stg_j * 8;

  for (int kb = 0; kb < 4; kb++) {
    int kstart = sp * 256 + kb * 64;
    __syncthreads();
#pragma unroll
    for (int p = 0; p < 4; p++) {
      int key = p * 16 + stg_k4;
      bf16x8 row = *(const bf16x8*)(vg + hoff + (size_t)(kstart + key) * D_ + stg_dh0);
      u16* basep = &vtT[stg_dh0][key ^ (stg_j << 3)];
#pragma unroll
      for (int e = 0; e < 8; e++) basep[e * 72] = (u16)row[e];
    }
    __syncthreads();

    bf16x8 bk0[4], bk1[4];
#pragma unroll
    for (int nj = 0; nj < 4; nj++) {
      const u16* ks8 = kg + hoff + (size_t)(kstart + nj * 16 + lr) * D_ + lg * 8;
      bk0[nj] = *(const bf16x8*)(ks8);
      bk1[nj] = *(const bf16x8*)(ks8 + 32);
    }
    f32x4 sc[2][4];
#pragma unroll
    for (int fi = 0; fi < 2; fi++)
#pragma unroll
      for (int nj = 0; nj < 4; nj++) {
        f32x4 t = {};
        t = mfma16(aq[fi][0], bk0[nj], t);
        t = mfma16(aq[fi][1], bk1[nj], t);
        sc[fi][nj] = t;
      }
#pragma unroll
    for (int fi = 0; fi < 2; fi++)
#pragma unroll
      for (int r = 0; r < 4; r++) {
        float ps = 0.f;
#pragma unroll
        for (int nj = 0; nj < 4; nj++) {
          float p = __expf(sc[fi][nj][r]);
          sc[fi][nj][r] = p;
          ps += p;
        }
#pragma unroll
        for (int d = 1; d < 16; d <<= 1) ps += __shfl_xor(ps, d);
        ls[fi][r] += ps;
      }
#pragma unroll
    for (int fi = 0; fi < 2; fi++)
#pragma unroll
      for (int nj = 0; nj < 4; nj++)
#pragma unroll
        for (int r = 0; r < 4; r++)
          plds[w][fi * 16 + lg * 4 + r][nj * 16 + lr] = f2bf(sc[fi][nj][r]);
    asm volatile("s_waitcnt lgkmcnt(0)" ::: "memory");
    __builtin_amdgcn_sched_barrier(0);
    bf16x8 ap[2][2];
#pragma unroll
    for (int fi = 0; fi < 2; fi++)
#pragma unroll
      for (int ks = 0; ks < 2; ks++)
        ap[fi][ks] = *(const bf16x8*)&plds[w][fi * 16 + lr][ks * 32 + lg * 8];
#pragma unroll
    for (int dj = 0; dj < 4; dj++) {
      int xr = ((dj * 16 + lr) >> 3) & 7;
#pragma unroll
      for (int ks = 0; ks < 2; ks++) {
        bf16x8 bv = *(const bf16x8*)&vtT[dj * 16 + lr][(ks * 32 + lg * 8) ^ (xr << 3)];
        o[0][dj] = mfma16(ap[0][ks], bv, o[0][dj]);
        o[1][dj] = mfma16(ap[1][ks], bv, o[1][dj]);
      }
    }
  }

  size_t pbase = (size_t)(bh * NSPLIT + sp) * 64;
#pragma unroll
  for (int fi = 0; fi < 2; fi++)
#pragma unroll
    for (int r = 0; r < 4; r++) {
      int row = qrow0 + fi * 16 + lg * 4 + r;
      if (lr == 0) lpart[pbase + row] = ls[fi][r];
#pragma unroll
      for (int dj = 0; dj < 4; dj++)
        opart[(pbase + row) * 64 + dj * 16 + lr] = o[fi][dj][r];
    }
}

// ---------------- combine split-K partials (plain sums) ----------
__global__ __launch_bounds__(256) void attn_gcombine(const float* __restrict__ opart,
                                                     const float* __restrict__ lpart,
                                                     u16* __restrict__ ao) {
  int bh = blockIdx.x;
  int b = bh / H_, h = bh % H_;
  int t = threadIdx.x;
  __shared__ float lt[64];
  if (t < 64) {
    float lsum = 0.f;
#pragma unroll
    for (int sp = 0; sp < NSPLIT; sp++)
      lsum += lpart[(size_t)(bh * NSPLIT + sp) * 64 + t];
    lt[t] = lsum;
  }
  __syncthreads();
  int row = t >> 2, c0 = (t & 3) * 16;
  float acc[16] = {};
  for (int sp = 0; sp < NSPLIT; sp++) {
    const float* op = opart + ((size_t)(bh * NSPLIT + sp) * 64 + row) * 64 + c0;
#pragma unroll
    for (int j = 0; j < 16; j++) acc[j] += op[j];
  }
  float inv = 1.f / lt[row];
  size_t hoff = (size_t)b * S_ * D_ + h * DH_;
#pragma unroll
  for (int j = 0; j < 16; j++)
    ao[hoff + (size_t)row * D_ + c0 + j] = f2bf(acc[j] * inv);
}

// ---------------- residual + LayerNorm (bf16 in/out) -------------
__global__ __launch_bounds__(192) void ln_b(const u16* __restrict__ x,
                                            const u16* __restrict__ res,
                                            const float* __restrict__ gg,
                                            const float* __restrict__ bb,
                                            u16* __restrict__ outb,
                                            float* __restrict__ outf) {
  int row = blockIdx.x, t = threadIdx.x;
  const u16* xr = x + (size_t)row * D_;
  const u16* rr = res + (size_t)row * D_;
  u16x4 xv = *(const u16x4*)&xr[t * 4];
  u16x4 rv = *(const u16x4*)&rr[t * 4];
  float v[4];
#pragma unroll
  for (int e = 0; e < 4; e++) v[e] = b2f(xv[e]) + b2f(rv[e]);
  __shared__ float sha[3], shb[3];
  float s = v[0] + v[1] + v[2] + v[3];
#pragma unroll
  for (int d = 1; d < 64; d <<= 1) s += __shfl_xor(s, d);
  if ((t & 63) == 0) sha[t >> 6] = s;
  __syncthreads();
  float mu = (sha[0] + sha[1] + sha[2]) * (1.f / 768.f);
  float dd[4], s2 = 0.f;
#pragma unroll
  for (int e = 0; e < 4; e++) { dd[e] = v[e] - mu; s2 += dd[e] * dd[e]; }
#pragma unroll
  for (int d = 1; d < 64; d <<= 1) s2 += __shfl_xor(s2, d);
  if ((t & 63) == 0) shb[t >> 6] = s2;
  __syncthreads();
  float var = (shb[0] + shb[1] + shb[2]) * (1.f / 768.f);
  float rs = rsqrtf(var + 1e-5f);
  float4 gv = *(const float4*)&gg[t * 4];
  float4 bv = *(const float4*)&bb[t * 4];
  float y0 = dd[0] * rs * gv.x + bv.x;
  float y1 = dd[1] * rs * gv.y + bv.y;
  float y2 = dd[2] * rs * gv.z + bv.z;
  float y3 = dd[3] * rs * gv.w + bv.w;
  u16x4 ov;
  ov[0] = f2bf(y0); ov[1] = f2bf(y1); ov[2] = f2bf(y2); ov[3] = f2bf(y3);
  *(u16x4*)&outb[(size_t)row * D_ + t * 4] = ov;
  if (outf) {
    float4 of = {y0, y1, y2, y3};
    *(float4*)&outf[(size_t)row * D_ + t * 4] = of;
  }
}

// =================================================================
extern "C" void kernel_launch(void* const* d_in, const int* in_sizes, int n_in,
                              void* d_out, int out_size, void* d_ws, size_t ws_size,
                              hipStream_t stream) {
  (void)in_sizes; (void)n_in; (void)out_size; (void)ws_size;
  const float* hidden = (const float*)d_in[0];
  const float* mask   = (const float*)d_in[1];
  const float* Wq  = (const float*)d_in[4];   const float* bq  = (const float*)d_in[5];
  const float* Wk  = (const float*)d_in[6];   const float* bk  = (const float*)d_in[7];
  const float* Wv  = (const float*)d_in[8];   const float* bv  = (const float*)d_in[9];
  const float* Wqg = (const float*)d_in[10];  const float* bqg = (const float*)d_in[11];
  const float* Wkg = (const float*)d_in[12];  const float* bkg = (const float*)d_in[13];
  const float* Wvg = (const float*)d_in[14];  const float* bvg = (const float*)d_in[15];
  const float* Wo  = (const float*)d_in[16];  const float* bo  = (const float*)d_in[17];
  const float* Wi  = (const float*)d_in[18];  const float* bi  = (const float*)d_in[19];
  const float* Wo2 = (const float*)d_in[20];  const float* bo2 = (const float*)d_in[21];
  const float* ln1g = (const float*)d_in[22]; const float* ln1b = (const float*)d_in[23];
  const float* ln2g = (const float*)d_in[24]; const float* ln2b = (const float*)d_in[25];

  char* ws = (char*)d_ws;
  size_t off = 0;
  auto alloc = [&](size_t bytes) -> void* {
    void* p = ws + off;
    off += (bytes + 255) & ~(size_t)255;
    return p;
  };
  const size_t DD = (size_t)D_ * D_;
  const size_t DF = (size_t)D_ * FF_;
  u16* Wt = (u16*)alloc((7 * L_ * DD + 2 * L_ * DF) * 2);
  u16* wqg_t = Wt + 3 * L_ * DD;
  u16* wo_t  = Wt + 6 * L_ * DD;
  u16* wi_t  = Wt + 7 * L_ * DD;
  u16* wo2_t = Wt + 7 * L_ * DD + L_ * DF;

  u16* X0 = (u16*)alloc((size_t)M_ * D_ * 2);
  u16* X1 = (u16*)alloc((size_t)M_ * D_ * 2);
  u16* tb = (u16*)alloc((size_t)M_ * D_ * 2);
  u16* B_bf = (u16*)alloc((size_t)M_ * FF_ * 2);
  u16* qbf  = (u16*)alloc((size_t)M_ * D_ * 2);
  u16* kbf  = (u16*)alloc((size_t)M_ * D_ * 2);
  u16* vbf  = (u16*)alloc((size_t)M_ * D_ * 2);
  u16* qgbf = (u16*)alloc((size_t)M_ * D_ * 2);
  u16* kgbf = (u16*)alloc((size_t)M_ * D_ * 2);
  u16* vgbf = (u16*)alloc((size_t)M_ * D_ * 2);
  u16* aobf = (u16*)alloc((size_t)M_ * D_ * 2);
  float* opart = (float*)alloc((size_t)B_ * H_ * NSPLIT * 64 * 64 * 4);
  float* lpart = (float*)alloc((size_t)B_ * H_ * NSPLIT * 64 * 4);

  dim3 tb32(32, 8);
  Ptr7 wp;
  wp.p[0] = Wq; wp.p[1] = Wk; wp.p[2] = Wv; wp.p[3] = Wqg;
  wp.p[4] = Wkg; wp.p[5] = Wvg; wp.p[6] = Wo;
  wtrans7<<<dim3(24, 24, 14), tb32, 0, stream>>>(wp, Wt);
  wtrans<<<dim3(96, 24, 2), tb32, 0, stream>>>(Wi,  wi_t,  D_, FF_);
  wtrans<<<dim3(24, 96, 2), tb32, 0, stream>>>(Wo2, wo2_t, FF_, D_);

  conv_b<<<(M_ * D_ / 4 + 255) / 256, 256, 0, stream>>>(hidden, X0, M_ * D_ / 4);

  for (int l = 0; l < L_; l++) {
    size_t wdd = (size_t)l * DD;
    size_t wdf = (size_t)l * DF;
    dim3 g64(6, 64), g2(6, 2);

    Bias5 bp;
    bp.p[0] = bq  + l * D_;
    bp.p[1] = bk  + l * D_;
    bp.p[2] = bv  + l * D_;
    bp.p[3] = bkg + l * D_;
    bp.p[4] = bvg + l * D_;
    gemm256p<1, 5><<<dim3(15, 32), 512, 0, stream>>>(X0, Wt, bp, qbf, D_, D_, l);
    gemm_pipe<2><<<g2, 256, 0, stream>>>(X0, wqg_t + wdd, bqg + l * D_, qgbf, D_, D_, 32);

    attn_local<<<dim3((S_ / W_) * 2, B_ * H_), 256, 0, stream>>>(qbf, kbf, vbf, mask, aobf);
    attn_gsplit<<<dim3(NSPLIT, B_ * H_), 128, 0, stream>>>(qgbf, kgbf, vgbf, opart, lpart);
    attn_gcombine<<<B_ * H_, 256, 0, stream>>>(opart, lpart, aobf);

    gemm_pipe<1><<<g64, 256, 0, stream>>>(aobf, wo_t + wdd, bo + l * D_, tb, D_, D_, 1);
    ln_b<<<M_, 192, 0, stream>>>(tb, X0, ln1g + l * D_, ln1b + l * D_, X1, nullptr);

    Bias5 bpi; bpi.p[0] = bi + l * FF_;
    gemm256p<3, 1><<<dim3(12, 32), 512, 0, stream>>>(X1, wi_t + wdf, bpi, B_bf, D_, FF_, 0);
    gemm_pipe<1><<<g64, 256, 0, stream>>>(B_bf, wo2_t + wdf, bo2 + l * D_, tb, D_, FF_, 1);

    ln_b<<<M_, 192, 0, stream>>>(tb, X1, ln2g + l * D_, ln2b + l * D_, X0,
                                 (l == L_ - 1) ? (float*)d_out : nullptr);
  }
}

// Round 12
// 688.671 us; speedup vs baseline: 1.0753x; 1.0225x over previous
//
#include <hip/hip_runtime.h>

#define B_ 2
#define S_ 4096
#define D_ 768
#define H_ 12
#define DH_ 64
#define W_ 256
#define G_ 64
#define FF_ 3072
#define L_ 2
#define M_ (B_*S_)
#define NEGV -1e9f
#define NSPLIT 16

typedef short bf16x8 __attribute__((ext_vector_type(8)));
typedef float f32x4 __attribute__((ext_vector_type(4)));
typedef unsigned short u16;
typedef unsigned short u16x4 __attribute__((ext_vector_type(4)));

__device__ __forceinline__ u16 f2bf(float f) {
  union { float f; unsigned u; } a; a.f = f;
  unsigned r = a.u + 0x7FFFu + ((a.u >> 16) & 1u);
  return (u16)(r >> 16);
}
__device__ __forceinline__ float b2f(u16 u) {
  union { unsigned u; float f; } a; a.u = ((unsigned)u) << 16;
  return a.f;
}

__device__ __forceinline__ f32x4 mfma16(bf16x8 a, bf16x8 b, f32x4 c) {
  return __builtin_amdgcn_mfma_f32_16x16x32_bf16(a, b, c, 0, 0, 0);
}

__device__ __forceinline__ void gload16(const u16* g, u16* l) {
  __builtin_amdgcn_global_load_lds((const __attribute__((address_space(1))) void*)g,
                                   (__attribute__((address_space(3))) void*)l, 16, 0, 0);
}

__device__ __forceinline__ int xcd_swz(int bid, int nwg) {
  if ((nwg & 7) == 0) {
    int cpx = nwg >> 3;
    bid = (bid & 7) * cpx + (bid >> 3);
  }
  return bid;
}

// ---------------- batched weight transpose (7 DxD slabs) ---------
struct Ptr7 { const float* p[7]; };
__global__ __launch_bounds__(256) void wtrans7(Ptr7 in, u16* __restrict__ out) {
  __shared__ float tile[32][33];
  int z = blockIdx.z;
  int slab = z >> 1, l = z & 1;
  const float* src = in.p[slab] + (size_t)l * D_ * D_;
  u16* dst = out + (size_t)z * D_ * D_;
  int k0 = blockIdx.y * 32, n0 = blockIdx.x * 32;
  int tx = threadIdx.x, ty = threadIdx.y;
#pragma unroll
  for (int i = 0; i < 4; i++)
    tile[ty + i*8][tx] = src[(size_t)(k0 + ty + i*8) * D_ + n0 + tx];
  __syncthreads();
#pragma unroll
  for (int i = 0; i < 4; i++)
    dst[(size_t)(n0 + ty + i*8) * D_ + k0 + tx] = f2bf(tile[tx][ty + i*8]);
}

__global__ __launch_bounds__(256) void wtrans(const float* __restrict__ in,
                                              u16* __restrict__ out, int K, int N) {
  __shared__ float tile[32][33];
  size_t base = (size_t)blockIdx.z * K * N;
  int k0 = blockIdx.y * 32, n0 = blockIdx.x * 32;
  int tx = threadIdx.x, ty = threadIdx.y;
#pragma unroll
  for (int i = 0; i < 4; i++)
    tile[ty + i*8][tx] = in[base + (size_t)(k0 + ty + i*8) * N + n0 + tx];
  __syncthreads();
#pragma unroll
  for (int i = 0; i < 4; i++)
    out[base + (size_t)(n0 + ty + i*8) * K + k0 + tx] = f2bf(tile[tx][ty + i*8]);
}

// ---------------- f32 -> bf16 convert ----------------------------
__global__ __launch_bounds__(256) void conv_b(const float* __restrict__ in,
                                              u16* __restrict__ outb, int n4) {
  int i = blockIdx.x * 256 + threadIdx.x;
  if (i >= n4) return;
  float4 v = ((const float4*)in)[i];
  u16x4 o;
  o[0] = f2bf(v.x); o[1] = f2bf(v.y); o[2] = f2bf(v.z); o[3] = f2bf(v.w);
  ((u16x4*)outb)[i] = o;
}

template <int MODE>
__device__ __forceinline__ float epi_post(float v) {
  if (MODE == 2) return v * 0.125f;
  if (MODE == 3) {
    float y = 0.79788456f * (v + 0.044715f * v * v * v);
    float e = __expf(fminf(2.f * y, 20.f));
    return v * e / (e + 1.f);
  }
  return v;
}

struct Bias5 { const float* p[5]; };

// ============ 256x256 8-PHASE GEMM (direct-store epilogue) ========
#define VMC4() asm volatile("s_waitcnt vmcnt(4)" ::: "memory")
#define VMC0() asm volatile("s_waitcnt vmcnt(0)" ::: "memory")
#define GPH_PRE() do { __builtin_amdgcn_s_barrier(); \
  asm volatile("s_waitcnt lgkmcnt(0)" ::: "memory"); \
  __builtin_amdgcn_sched_barrier(0); } while (0)
#define GPH_PRE_NOLDS() do { __builtin_amdgcn_s_barrier(); \
  __builtin_amdgcn_sched_barrier(0); } while (0)
#define GPH_POST() do { __builtin_amdgcn_sched_barrier(0); \
  __builtin_amdgcn_s_barrier(); } while (0)
#define GPH_MFMA(AF, BF, QM, QN) do { \
  __builtin_amdgcn_s_setprio(1); \
  _Pragma("unroll") for (int mi = 0; mi < 4; mi++) \
  _Pragma("unroll") for (int nj = 0; nj < 2; nj++) \
  _Pragma("unroll") for (int ks = 0; ks < 2; ks++) \
    acc[(QM)*4+mi][(QN)*2+nj] = mfma16(AF[mi][ks], BF[nj][ks], acc[(QM)*4+mi][(QN)*2+nj]); \
  __builtin_amdgcn_s_setprio(0); } while (0)

template <int MODE, int NW>
__global__ __launch_bounds__(512, 2) void gemm256p(const u16* __restrict__ A,
                                                   const u16* __restrict__ Wbase,
                                                   Bias5 bp,
                                                   u16* __restrict__ OutBase,
                                                   int Kdim, int Nstride, int l) {
  __shared__ u16 sh[65536];
  int gx = gridDim.x;
  int bid = blockIdx.x + blockIdx.y * gx;
  bid = xcd_swz(bid, gx * gridDim.y);
  int bxx = bid % gx, by = bid / gx;
  int bm = by * 256;
  int widx, bn;
  const u16* Bt; u16* Cb; const float* bias;
  if (NW == 5) {
    widx = bxx / 3;
    bn = (bxx % 3) * 256;
    int slab = widx + (widx >= 3 ? 1 : 0);
    Bt = Wbase + ((size_t)slab * L_ + l) * (size_t)D_ * D_;
    Cb = OutBase + (size_t)slab * M_ * D_;
    bias = bp.p[widx];
  } else {
    widx = 0;
    bn = bxx * 256;
    Bt = Wbase; Cb = OutBase; bias = bp.p[0];
  }
  int tid = threadIdx.x;
  int lane = tid & 63, wid = tid >> 6;
  int wr = wid >> 2, wc = wid & 3;
  int lr = lane & 15, lg = lane >> 4;

  int rr0 = tid >> 3, slot0 = tid & 7;
  int c80 = slot0 ^ (rr0 & 7);
  const u16* pA = A + (size_t)(bm + rr0) * Kdim + c80 * 8;
  const u16* pB = Bt + (size_t)(bn + rr0) * Kdim + c80 * 8;

  auto stA = [&](int buf, int h, int kt) {
    u16* base = sh + buf * 16384;
    gload16(pA + (size_t)(h * 128) * Kdim + kt * 64, &base[(h * 1024 + tid) * 8]);
    gload16(pA + (size_t)(h * 128 + 64) * Kdim + kt * 64, &base[(h * 1024 + 512 + tid) * 8]);
  };
  auto stB = [&](int buf, int h, int kt) {
    u16* base = sh + 32768 + buf * 16384;
    gload16(pB + (size_t)(h * 128) * Kdim + kt * 64, &base[(h * 1024 + tid) * 8]);
    gload16(pB + (size_t)(h * 128 + 64) * Kdim + kt * 64, &base[(h * 1024 + 512 + tid) * 8]);
  };
  auto ldA = [&](bf16x8 (&af)[4][2], int c, int qm) {
    const u16* base = sh + c * 16384;
#pragma unroll
    for (int mi = 0; mi < 4; mi++)
#pragma unroll
      for (int ks = 0; ks < 2; ks++) {
        int row = wr * 128 + qm * 64 + mi * 16 + lr;
        int c8 = ks * 4 + lg;
        af[mi][ks] = *(const bf16x8*)&base[(row * 8 + (c8 ^ (row & 7))) * 8];
      }
  };
  auto ldB = [&](bf16x8 (&bf)[2][2], int c, int qn) {
    const u16* base = sh + 32768 + c * 16384;
#pragma unroll
    for (int nj = 0; nj < 2; nj++)
#pragma unroll
      for (int ks = 0; ks < 2; ks++) {
        int row = wc * 64 + qn * 32 + nj * 16 + lr;
        int c8 = ks * 4 + lg;
        bf[nj][ks] = *(const bf16x8*)&base[(row * 8 + (c8 ^ (row & 7))) * 8];
      }
  };

  f32x4 acc[8][4] = {};
  int nt = Kdim >> 6;

  stA(0, 0, 0); stA(0, 1, 0);
  stB(0, 0, 0); stB(0, 1, 0);
  stB(1, 0, 1); stB(1, 1, 1);
  VMC4();
  __builtin_amdgcn_s_barrier();

  bf16x8 af[4][2], b0[2][2], b1[2][2];
  for (int kt = 0; kt < nt; kt += 2) {
    bool notlast = (kt + 2 < nt);
    ldA(af, 0, 0); ldB(b0, 0, 0);
    stA(1, 0, kt + 1);
    GPH_PRE(); GPH_MFMA(af, b0, 0, 0); GPH_POST();
    ldB(b1, 0, 1);
    stA(1, 1, kt + 1);
    GPH_PRE(); GPH_MFMA(af, b1, 0, 1); GPH_POST();
    ldA(af, 0, 1);
    if (notlast) stB(0, 0, kt + 2);
    GPH_PRE(); GPH_MFMA(af, b0, 1, 0); GPH_POST();
    if (notlast) { stB(0, 1, kt + 2); VMC4(); } else { VMC0(); }
    GPH_PRE_NOLDS(); GPH_MFMA(af, b1, 1, 1); GPH_POST();
    ldA(af, 1, 0); ldB(b0, 1, 0);
    if (notlast) stA(0, 0, kt + 2);
    GPH_PRE(); GPH_MFMA(af, b0, 0, 0); GPH_POST();
    ldB(b1, 1, 1);
    if (notlast) stA(0, 1, kt + 2);
    GPH_PRE(); GPH_MFMA(af, b1, 0, 1); GPH_POST();
    ldA(af, 1, 1);
    if (notlast) stB(1, 0, kt + 3);
    GPH_PRE(); GPH_MFMA(af, b0, 1, 0); GPH_POST();
    if (notlast) { stB(1, 1, kt + 3); VMC4(); } else { VMC0(); }
    GPH_PRE_NOLDS(); GPH_MFMA(af, b1, 1, 1); GPH_POST();
  }

  int r0 = bm + wr * 128, c0 = bn + wc * 64;
  int cr = (lane >> 4) * 4, cc = lane & 15;
  float sc = (NW == 5 && widx == 0) ? 0.125f : 1.0f;
#pragma unroll
  for (int nj = 0; nj < 4; nj++) {
    int col = c0 + nj * 16 + cc;
    float bv = bias[col];
#pragma unroll
    for (int mi = 0; mi < 8; mi++)
#pragma unroll
      for (int r = 0; r < 4; r++) {
        size_t off = (size_t)(r0 + mi * 16 + cr + r) * Nstride + col;
        Cb[off] = f2bf(epi_post<MODE>((acc[mi][nj][r] + bv) * sc));
      }
  }
}

// ============ 128x128 GEMM: 3-deep pipeline + LDS-bounce epilogue =
template <int MODE>
__global__ __launch_bounds__(256) void gemm_pipe(const u16* __restrict__ A,
                                                 const u16* __restrict__ Bt,
                                                 const float* __restrict__ bias,
                                                 u16* __restrict__ Cb,
                                                 int Ndim, int Kdim, int rowTileStride) {
  __shared__ u16 sh[24576];
  int gx = gridDim.x;
  int bid = blockIdx.x + blockIdx.y * gx;
  bid = xcd_swz(bid, gx * gridDim.y);
  int bm = (bid / gx) * rowTileStride * 128;
  int bn = (bid % gx) * 128;
  int tid = threadIdx.x;
  int lane = tid & 63, w = tid >> 6;
  int r0w = (w >> 1) * 64, c0w = (w & 1) * 64;
  int lr = lane & 15, lg = lane >> 4;

  int f0 = tid, l0 = f0 >> 3, s0 = (f0 & 7) ^ (l0 & 7);
  int row0 = (l0 << 1) | (s0 >> 2), c0s = (s0 & 3) * 8;
  int f1 = tid + 256, l1 = f1 >> 3, s1 = (f1 & 7) ^ (l1 & 7);
  int row1 = (l1 << 1) | (s1 >> 2), c1s = (s1 & 3) * 8;
  const u16* A0 = A + (size_t)(bm + row0) * Kdim + c0s;
  const u16* A1 = A + (size_t)(bm + row1) * Kdim + c1s;
  const u16* B0 = Bt + (size_t)(bn + row0) * Kdim + c0s;
  const u16* B1 = Bt + (size_t)(bn + row1) * Kdim + c1s;

  int offa[4], offb[4];
#pragma unroll
  for (int i = 0; i < 4; i++) {
    int ra = r0w + i * 16 + lr;
    int la = ra >> 1, sa = ((ra & 1) << 2) | lg;
    offa[i] = la * 64 + (sa ^ (la & 7)) * 8;
    int rb = c0w + i * 16 + lr;
    int lb = rb >> 1, sb = ((rb & 1) << 2) | lg;
    offb[i] = lb * 64 + (sb ^ (lb & 7)) * 8;
  }

  auto stage = [&](int kt, int buf) {
    int k1 = kt << 5;
    u16* ab = sh + buf * 4096;
    u16* bb = sh + 12288 + buf * 4096;
    gload16(A0 + k1, &ab[tid * 8]);
    gload16(A1 + k1, &ab[tid * 8 + 2048]);
    gload16(B0 + k1, &bb[tid * 8]);
    gload16(B1 + k1, &bb[tid * 8 + 2048]);
  };

  int nt = Kdim >> 5;
  f32x4 acc[4][4] = {};

  stage(0, 0);
  if (nt > 1) stage(1, 1);

  for (int t = 0; t < nt; t++) {
    int cb = t % 3;
    if (t + 2 < nt) {
      stage(t + 2, (t + 2) % 3);
      asm volatile("s_waitcnt vmcnt(8)" ::: "memory");
    } else if (t + 1 < nt) {
      asm volatile("s_waitcnt vmcnt(4)" ::: "memory");
    } else {
      asm volatile("s_waitcnt vmcnt(0)" ::: "memory");
    }
    __builtin_amdgcn_s_barrier();
    __builtin_amdgcn_sched_barrier(0);
    const u16* ab = sh + cb * 4096;
    const u16* bb = sh + 12288 + cb * 4096;
    bf16x8 a[4], b[4];
#pragma unroll
    for (int i = 0; i < 4; i++) a[i] = *(const bf16x8*)&ab[offa[i]];
#pragma unroll
    for (int j = 0; j < 4; j++) b[j] = *(const bf16x8*)&bb[offb[j]];
#pragma unroll
    for (int i = 0; i < 4; i++)
#pragma unroll
      for (int j = 0; j < 4; j++)
        acc[i][j] = mfma16(a[i], b[j], acc[i][j]);
    __builtin_amdgcn_sched_barrier(0);
    __builtin_amdgcn_s_barrier();
    __builtin_amdgcn_sched_barrier(0);
  }

  int cr = (lane >> 4) * 4, cc = lane & 15;
#pragma unroll
  for (int j = 0; j < 4; j++) {
    int col = c0w + j * 16 + cc;
    float bv = bias[bn + col];
#pragma unroll
    for (int i = 0; i < 4; i++)
#pragma unroll
      for (int r = 0; r < 4; r++) {
        int row = r0w + i * 16 + cr + r;
        int chunk = (col >> 3) ^ (row & 15);
        sh[row * 128 + chunk * 8 + (col & 7)] =
            f2bf(epi_post<MODE>(acc[i][j][r] + bv));
      }
  }
  __syncthreads();
  {
    int row = tid >> 1, half = tid & 1;
    u16* gro = Cb + (size_t)(bm + row) * Ndim + bn + half * 64;
#pragma unroll
    for (int c = 0; c < 8; c++) {
      int lc = half * 8 + c;
      int pc = lc ^ (row & 15);
      bf16x8 v = *(const bf16x8*)&sh[row * 128 + pc * 8];
      *(bf16x8*)(gro + c * 8) = v;
    }
  }
}

// ---------------- local windowed + global-key attention ----------
// grid (NC*4, B*H), block 128 (2 waves, 64 q-rows). Register double-buffer
// prefetch of K fragments and V staging rows across k-block iterations;
// raw s_barrier + lgkmcnt-only so the prefetch stays in flight (no vmcnt drain).
__global__ __launch_bounds__(128) void attn_local(const u16* __restrict__ qb,
                                                  const u16* __restrict__ kb_,
                                                  const u16* __restrict__ vb,
                                                  const float* __restrict__ mask,
                                                  u16* __restrict__ ao) {
  int bid = blockIdx.x + blockIdx.y * gridDim.x;
  bid = xcd_swz(bid, 1536);
  int cx = bid & 63, bh = bid >> 6;
  int c = cx >> 2, sub = cx & 3;
  int b = bh / H_, h = bh % H_;
  int tid = threadIdx.x;
  int w = tid >> 6, lane = tid & 63;
  int lr = lane & 15, lg = lane >> 4;

  __shared__ u16 vtT[64][72];
  __shared__ u16 plds[2][32][72];
  __shared__ unsigned char vflag[576];

  int base_off = sub * 64;
  int kwin0 = c * W_ - W_;
  for (int i = tid; i < 576; i += 128) {
    int kp = kwin0 + base_off + i;
    vflag[i] = (kp >= 0 && kp < S_ && mask[b * S_ + kp] == 0.0f) ? 1 : 0;
  }

  size_t hoff = (size_t)b * S_ * D_ + h * DH_;
  int qrow0 = c * W_ + base_off + w * 32;
  bf16x8 aq[2][2];
#pragma unroll
  for (int fi = 0; fi < 2; fi++)
#pragma unroll
    for (int ks = 0; ks < 2; ks++)
      aq[fi][ks] = *(const bf16x8*)(qb + hoff + (size_t)(qrow0 + fi * 16 + lr) * D_ + ks * 32 + lg * 8);

  // valid window k-blocks form a contiguous range [kb_lo, kb_hi]
  int K0 = kwin0 + base_off;
  int kb_lo = (K0 < 0) ? (1 + ((-K0) >> 6)) : 1;
  int kb_hi = 9;
  { int hi = 1 + ((S_ - 64 - K0) >> 6); if (hi < 9) kb_hi = hi; }
  int niter = 1 + (kb_hi - kb_lo + 1);

  int stg_k4 = tid >> 3, stg_j = tid & 7;
  int stg_dh0 = stg_j * 8;

  float ls[2][4];
  f32x4 o[2][4] = {};
#pragma unroll
  for (int fi = 0; fi < 2; fi++)
#pragma unroll
    for (int r = 0; r < 4; r++) ls[fi][r] = 0.f;

  // prologue: load K frags + V rows for iteration 0 (global block, kstart=0)
  bf16x8 ck0[4], ck1[4], nk0[4], nk1[4], cv[4], nv[4];
#pragma unroll
  for (int nj = 0; nj < 4; nj++) {
    const u16* ks8 = kb_ + hoff + (size_t)(nj * 16 + lr) * D_ + lg * 8;
    ck0[nj] = *(const bf16x8*)(ks8);
    ck1[nj] = *(const bf16x8*)(ks8 + 32);
  }
#pragma unroll
  for (int p = 0; p < 4; p++)
    cv[p] = *(const bf16x8*)(vb + hoff + (size_t)(p * 16 + stg_k4) * D_ + stg_dh0);

  for (int it = 0; it < niter; it++) {
    int kb = (it == 0) ? 0 : (kb_lo + it - 1);

    // barrier A: vtT free (prev PV reads complete on all waves)
    __builtin_amdgcn_s_barrier();
    // write current V (from regs) into swizzled transposed tile
#pragma unroll
    for (int p = 0; p < 4; p++) {
      int key = p * 16 + stg_k4;
      u16* basep = &vtT[stg_dh0][key ^ (stg_j << 3)];
#pragma unroll
      for (int e = 0; e < 8; e++) basep[e * 72] = (u16)cv[p][e];
    }
    // issue next iteration's global loads (stay in flight across barrier B)
    if (it + 1 < niter) {
      int kb2 = kb_lo + it;             // kb of iteration it+1
      int ks2 = K0 + (kb2 - 1) * 64;
#pragma unroll
      for (int nj = 0; nj < 4; nj++) {
        const u16* ks8 = kb_ + hoff + (size_t)(ks2 + nj * 16 + lr) * D_ + lg * 8;
        nk0[nj] = *(const bf16x8*)(ks8);
        nk1[nj] = *(const bf16x8*)(ks8 + 32);
      }
#pragma unroll
      for (int p = 0; p < 4; p++)
        nv[p] = *(const bf16x8*)(vb + hoff + (size_t)(ks2 + p * 16 + stg_k4) * D_ + stg_dh0);
    }
    // barrier B: vtT ready — drain LDS writes only, keep vmcnt outstanding
    asm volatile("s_waitcnt lgkmcnt(0)" ::: "memory");
    __builtin_amdgcn_s_barrier();
    __builtin_amdgcn_sched_barrier(0);

    // QK with current K registers
    f32x4 sc[2][4];
#pragma unroll
    for (int fi = 0; fi < 2; fi++)
#pragma unroll
      for (int nj = 0; nj < 4; nj++) {
        f32x4 t = {};
        t = mfma16(aq[fi][0], ck0[nj], t);
        t = mfma16(aq[fi][1], ck1[nj], t);
        sc[fi][nj] = t;
      }

    if (kb >= 2 && kb <= 8) {
#pragma unroll
      for (int nj = 0; nj < 4; nj++) {
        bool kv = vflag[(kb - 1) * 64 + nj * 16 + lr] != 0;
#pragma unroll
        for (int fi = 0; fi < 2; fi++)
#pragma unroll
          for (int r = 0; r < 4; r++)
            sc[fi][nj][r] = kv ? sc[fi][nj][r] : NEGV;
      }
    } else if (kb > 0) {
#pragma unroll
      for (int nj = 0; nj < 4; nj++) {
        int fidx = (kb - 1) * 64 + nj * 16 + lr;
        int koff = base_off + fidx;
        bool kv = vflag[fidx] != 0;
#pragma unroll
        for (int fi = 0; fi < 2; fi++)
#pragma unroll
          for (int r = 0; r < 4; r++) {
            int wq = base_off + w * 32 + fi * 16 + lg * 4 + r;
            if (!(kv && koff >= wq && koff <= wq + 2 * W_)) sc[fi][nj][r] = NEGV;
          }
      }
    }

    // fixed-max softmax accumulation
#pragma unroll
    for (int fi = 0; fi < 2; fi++)
#pragma unroll
      for (int r = 0; r < 4; r++) {
        float ps = 0.f;
#pragma unroll
        for (int nj = 0; nj < 4; nj++) {
          float p = __expf(sc[fi][nj][r]);
          sc[fi][nj][r] = p;
          ps += p;
        }
#pragma unroll
        for (int d = 1; d < 16; d <<= 1) ps += __shfl_xor(ps, d);
        ls[fi][r] += ps;
      }

#pragma unroll
    for (int fi = 0; fi < 2; fi++)
#pragma unroll
      for (int nj = 0; nj < 4; nj++)
#pragma unroll
        for (int r = 0; r < 4; r++)
          plds[w][fi * 16 + lg * 4 + r][nj * 16 + lr] = f2bf(sc[fi][nj][r]);
    asm volatile("s_waitcnt lgkmcnt(0)" ::: "memory");
    __builtin_amdgcn_sched_barrier(0);

    bf16x8 ap[2][2];
#pragma unroll
    for (int fi = 0; fi < 2; fi++)
#pragma unroll
      for (int ks = 0; ks < 2; ks++)
        ap[fi][ks] = *(const bf16x8*)&plds[w][fi * 16 + lr][ks * 32 + lg * 8];
#pragma unroll
    for (int dj = 0; dj < 4; dj++) {
      int xr = ((dj * 16 + lr) >> 3) & 7;
#pragma unroll
      for (int ks = 0; ks < 2; ks++) {
        bf16x8 bv = *(const bf16x8*)&vtT[dj * 16 + lr][(ks * 32 + lg * 8) ^ (xr << 3)];
        o[0][dj] = mfma16(ap[0][ks], bv, o[0][dj]);
        o[1][dj] = mfma16(ap[1][ks], bv, o[1][dj]);
      }
    }

    // rotate prefetch buffers
    if (it + 1 < niter) {
#pragma unroll
      for (int j = 0; j < 4; j++) {
        ck0[j] = nk0[j]; ck1[j] = nk1[j]; cv[j] = nv[j];
      }
    }
  }

#pragma unroll
  for (int fi = 0; fi < 2; fi++)
#pragma unroll
    for (int dj = 0; dj < 4; dj++)
#pragma unroll
      for (int r = 0; r < 4; r++) {
        int row = qrow0 + fi * 16 + lg * 4 + r;
        float v = o[fi][dj][r] / ls[fi][r];
        ao[hoff + (size_t)row * D_ + dj * 16 + lr] = f2bf(v);
      }
}

// ---------------- global attention, split-K partials -------------
__global__ __launch_bounds__(128) void attn_gsplit(const u16* __restrict__ qg,
                                                   const u16* __restrict__ kg,
                                                   const u16* __restrict__ vg,
                                                   float* __restrict__ opart,
                                                   float* __restrict__ lpart) {
  int sp = blockIdx.x, bh = blockIdx.y;
  int b = bh / H_, h = bh % H_;
  int tid = threadIdx.x, w = tid >> 6, lane = tid & 63;
  int lr = lane & 15, lg = lane >> 4;
  __shared__ u16 vtT[64][72];
  __shared__ u16 plds[2][32][72];
  size_t hoff = (size_t)b * S_ * D_ + h * DH_;
  int qrow0 = w * 32;
  bf16x8 aq[2][2];
#pragma unroll
  for (int fi = 0; fi < 2; fi++)
#pragma unroll
    for (int ks = 0; ks < 2; ks++)
      aq[fi][ks] = *(const bf16x8*)(qg + hoff + (size_t)(qrow0 + fi * 16 + lr) * D_ + ks * 32 + lg * 8);
  float ls[2][4];
  f32x4 o[2][4] = {};
#pragma unroll
  for (int fi = 0; fi < 2; fi++)
#pragma unroll
    for (int r = 0; r < 4; r++) ls[fi][r] = 0.f;

  int stg_k4 = tid >> 3, stg_j = tid & 7;
  int stg_dh0 = stg_j * 8;

  for (int kb = 0; kb < 4; kb++) {
    int kstart = sp * 256 + kb * 64;
    __syncthreads();
#pragma unroll
    for (int p = 0; p < 4; p++) {
      int key = p * 16 + stg_k4;
      bf16x8 row = *(const bf16x8*)(vg + hoff + (size_t)(kstart + key) * D_ + stg_dh0);
      u16* basep = &vtT[stg_dh0][key ^ (stg_j << 3)];
#pragma unroll
      for (int e = 0; e < 8; e++) basep[e * 72] = (u16)row[e];
    }
    __syncthreads();

    bf16x8 bk0[4], bk1[4];
#pragma unroll
    for (int nj = 0; nj < 4; nj++) {
      const u16* ks8 = kg + hoff + (size_t)(kstart + nj * 16 + lr) * D_ + lg * 8;
      bk0[nj] = *(const bf16x8*)(ks8);
      bk1[nj] = *(const bf16x8*)(ks8 + 32);
    }
    f32x4 sc[2][4];
#pragma unroll
    for (int fi = 0; fi < 2; fi++)
#pragma unroll
      for (int nj = 0; nj < 4; nj++) {
        f32x4 t = {};
        t = mfma16(aq[fi][0], bk0[nj], t);
        t = mfma16(aq[fi][1], bk1[nj], t);
        sc[fi][nj] = t;
      }
#pragma unroll
    for (int fi = 0; fi < 2; fi++)
#pragma unroll
      for (int r = 0; r < 4; r++) {
        float ps = 0.f;
#pragma unroll
        for (int nj = 0; nj < 4; nj++) {
          float p = __expf(sc[fi][nj][r]);
          sc[fi][nj][r] = p;
          ps += p;
        }
#pragma unroll
        for (int d = 1; d < 16; d <<= 1) ps += __shfl_xor(ps, d);
        ls[fi][r] += ps;
      }
#pragma unroll
    for (int fi = 0; fi < 2; fi++)
#pragma unroll
      for (int nj = 0; nj < 4; nj++)
#pragma unroll
        for (int r = 0; r < 4; r++)
          plds[w][fi * 16 + lg * 4 + r][nj * 16 + lr] = f2bf(sc[fi][nj][r]);
    asm volatile("s_waitcnt lgkmcnt(0)" ::: "memory");
    __builtin_amdgcn_sched_barrier(0);
    bf16x8 ap[2][2];
#pragma unroll
    for (int fi = 0; fi < 2; fi++)
#pragma unroll
      for (int ks = 0; ks < 2; ks++)
        ap[fi][ks] = *(const bf16x8*)&plds[w][fi * 16 + lr][ks * 32 + lg * 8];
#pragma unroll
    for (int dj = 0; dj < 4; dj++) {
      int xr = ((dj * 16 + lr) >> 3) & 7;
#pragma unroll
      for (int ks = 0; ks < 2; ks++) {
        bf16x8 bv = *(const bf16x8*)&vtT[dj * 16 + lr][(ks * 32 + lg * 8) ^ (xr << 3)];
        o[0][dj] = mfma16(ap[0][ks], bv, o[0][dj]);
        o[1][dj] = mfma16(ap[1][ks], bv, o[1][dj]);
      }
    }
  }

  size_t pbase = (size_t)(bh * NSPLIT + sp) * 64;
#pragma unroll
  for (int fi = 0; fi < 2; fi++)
#pragma unroll
    for (int r = 0; r < 4; r++) {
      int row = qrow0 + fi * 16 + lg * 4 + r;
      if (lr == 0) lpart[pbase + row] = ls[fi][r];
#pragma unroll
      for (int dj = 0; dj < 4; dj++)
        opart[(pbase + row) * 64 + dj * 16 + lr] = o[fi][dj][r];
    }
}

// ---------------- combine split-K partials (plain sums) ----------
__global__ __launch_bounds__(256) void attn_gcombine(const float* __restrict__ opart,
                                                     const float* __restrict__ lpart,
                                                     u16* __restrict__ ao) {
  int bh = blockIdx.x;
  int b = bh / H_, h = bh % H_;
  int t = threadIdx.x;
  __shared__ float lt[64];
  if (t < 64) {
    float lsum = 0.f;
#pragma unroll
    for (int sp = 0; sp < NSPLIT; sp++)
      lsum += lpart[(size_t)(bh * NSPLIT + sp) * 64 + t];
    lt[t] = lsum;
  }
  __syncthreads();
  int row = t >> 2, c0 = (t & 3) * 16;
  float acc[16] = {};
  for (int sp = 0; sp < NSPLIT; sp++) {
    const float* op = opart + ((size_t)(bh * NSPLIT + sp) * 64 + row) * 64 + c0;
#pragma unroll
    for (int j = 0; j < 16; j++) acc[j] += op[j];
  }
  float inv = 1.f / lt[row];
  size_t hoff = (size_t)b * S_ * D_ + h * DH_;
#pragma unroll
  for (int j = 0; j < 16; j++)
    ao[hoff + (size_t)row * D_ + c0 + j] = f2bf(acc[j] * inv);
}

// ---------------- residual + LayerNorm (bf16 in/out) -------------
__global__ __launch_bounds__(192) void ln_b(const u16* __restrict__ x,
                                            const u16* __restrict__ res,
                                            const float* __restrict__ gg,
                                            const float* __restrict__ bb,
                                            u16* __restrict__ outb,
                                            float* __restrict__ outf) {
  int row = blockIdx.x, t = threadIdx.x;
  const u16* xr = x + (size_t)row * D_;
  const u16* rr = res + (size_t)row * D_;
  u16x4 xv = *(const u16x4*)&xr[t * 4];
  u16x4 rv = *(const u16x4*)&rr[t * 4];
  float v[4];
#pragma unroll
  for (int e = 0; e < 4; e++) v[e] = b2f(xv[e]) + b2f(rv[e]);
  __shared__ float sha[3], shb[3];
  float s = v[0] + v[1] + v[2] + v[3];
#pragma unroll
  for (int d = 1; d < 64; d <<= 1) s += __shfl_xor(s, d);
  if ((t & 63) == 0) sha[t >> 6] = s;
  __syncthreads();
  float mu = (sha[0] + sha[1] + sha[2]) * (1.f / 768.f);
  float dd[4], s2 = 0.f;
#pragma unroll
  for (int e = 0; e < 4; e++) { dd[e] = v[e] - mu; s2 += dd[e] * dd[e]; }
#pragma unroll
  for (int d = 1; d < 64; d <<= 1) s2 += __shfl_xor(s2, d);
  if ((t & 63) == 0) shb[t >> 6] = s2;
  __syncthreads();
  float var = (shb[0] + shb[1] + shb[2]) * (1.f / 768.f);
  float rs = rsqrtf(var + 1e-5f);
  float4 gv = *(const float4*)&gg[t * 4];
  float4 bv = *(const float4*)&bb[t * 4];
  float y0 = dd[0] * rs * gv.x + bv.x;
  float y1 = dd[1] * rs * gv.y + bv.y;
  float y2 = dd[2] * rs * gv.z + bv.z;
  float y3 = dd[3] * rs * gv.w + bv.w;
  u16x4 ov;
  ov[0] = f2bf(y0); ov[1] = f2bf(y1); ov[2] = f2bf(y2); ov[3] = f2bf(y3);
  *(u16x4*)&outb[(size_t)row * D_ + t * 4] = ov;
  if (outf) {
    float4 of = {y0, y1, y2, y3};
    *(float4*)&outf[(size_t)row * D_ + t * 4] = of;
  }
}

// =================================================================
extern "C" void kernel_launch(void* const* d_in, const int* in_sizes, int n_in,
                              void* d_out, int out_size, void* d_ws, size_t ws_size,
                              hipStream_t stream) {
  (void)in_sizes; (void)n_in; (void)out_size; (void)ws_size;
  const float* hidden = (const float*)d_in[0];
  const float* mask   = (const float*)d_in[1];
  const float* Wq  = (const float*)d_in[4];   const float* bq  = (const float*)d_in[5];
  const float* Wk  = (const float*)d_in[6];   const float* bk  = (const float*)d_in[7];
  const float* Wv  = (const float*)d_in[8];   const float* bv  = (const float*)d_in[9];
  const float* Wqg = (const float*)d_in[10];  const float* bqg = (const float*)d_in[11];
  const float* Wkg = (const float*)d_in[12];  const float* bkg = (const float*)d_in[13];
  const float* Wvg = (const float*)d_in[14];  const float* bvg = (const float*)d_in[15];
  const float* Wo  = (const float*)d_in[16];  const float* bo  = (const float*)d_in[17];
  const float* Wi  = (const float*)d_in[18];  const float* bi  = (const float*)d_in[19];
  const float* Wo2 = (const float*)d_in[20];  const float* bo2 = (const float*)d_in[21];
  const float* ln1g = (const float*)d_in[22]; const float* ln1b = (const float*)d_in[23];
  const float* ln2g = (const float*)d_in[24]; const float* ln2b = (const float*)d_in[25];

  char* ws = (char*)d_ws;
  size_t off = 0;
  auto alloc = [&](size_t bytes) -> void* {
    void* p = ws + off;
    off += (bytes + 255) & ~(size_t)255;
    return p;
  };
  const size_t DD = (size_t)D_ * D_;
  const size_t DF = (size_t)D_ * FF_;
  u16* Wt = (u16*)alloc((7 * L_ * DD + 2 * L_ * DF) * 2);
  u16* wqg_t = Wt + 3 * L_ * DD;
  u16* wo_t  = Wt + 6 * L_ * DD;
  u16* wi_t  = Wt + 7 * L_ * DD;
  u16* wo2_t = Wt + 7 * L_ * DD + L_ * DF;

  u16* X0 = (u16*)alloc((size_t)M_ * D_ * 2);
  u16* X1 = (u16*)alloc((size_t)M_ * D_ * 2);
  u16* tb = (u16*)alloc((size_t)M_ * D_ * 2);
  u16* B_bf = (u16*)alloc((size_t)M_ * FF_ * 2);
  u16* qbf  = (u16*)alloc((size_t)M_ * D_ * 2);
  u16* kbf  = (u16*)alloc((size_t)M_ * D_ * 2);
  u16* vbf  = (u16*)alloc((size_t)M_ * D_ * 2);
  u16* qgbf = (u16*)alloc((size_t)M_ * D_ * 2);
  u16* kgbf = (u16*)alloc((size_t)M_ * D_ * 2);
  u16* vgbf = (u16*)alloc((size_t)M_ * D_ * 2);
  u16* aobf = (u16*)alloc((size_t)M_ * D_ * 2);
  float* opart = (float*)alloc((size_t)B_ * H_ * NSPLIT * 64 * 64 * 4);
  float* lpart = (float*)alloc((size_t)B_ * H_ * NSPLIT * 64 * 4);

  dim3 tb32(32, 8);
  Ptr7 wp;
  wp.p[0] = Wq; wp.p[1] = Wk; wp.p[2] = Wv; wp.p[3] = Wqg;
  wp.p[4] = Wkg; wp.p[5] = Wvg; wp.p[6] = Wo;
  wtrans7<<<dim3(24, 24, 14), tb32, 0, stream>>>(wp, Wt);
  wtrans<<<dim3(96, 24, 2), tb32, 0, stream>>>(Wi,  wi_t,  D_, FF_);
  wtrans<<<dim3(24, 96, 2), tb32, 0, stream>>>(Wo2, wo2_t, FF_, D_);

  conv_b<<<(M_ * D_ / 4 + 255) / 256, 256, 0, stream>>>(hidden, X0, M_ * D_ / 4);

  for (int l = 0; l < L_; l++) {
    size_t wdd = (size_t)l * DD;
    size_t wdf = (size_t)l * DF;
    dim3 g64(6, 64), g2(6, 2);

    Bias5 bp;
    bp.p[0] = bq  + l * D_;
    bp.p[1] = bk  + l * D_;
    bp.p[2] = bv  + l * D_;
    bp.p[3] = bkg + l * D_;
    bp.p[4] = bvg + l * D_;
    gemm256p<1, 5><<<dim3(15, 32), 512, 0, stream>>>(X0, Wt, bp, qbf, D_, D_, l);
    gemm_pipe<2><<<g2, 256, 0, stream>>>(X0, wqg_t + wdd, bqg + l * D_, qgbf, D_, D_, 32);

    attn_local<<<dim3((S_ / W_) * 4, B_ * H_), 128, 0, stream>>>(qbf, kbf, vbf, mask, aobf);
    attn_gsplit<<<dim3(NSPLIT, B_ * H_), 128, 0, stream>>>(qgbf, kgbf, vgbf, opart, lpart);
    attn_gcombine<<<B_ * H_, 256, 0, stream>>>(opart, lpart, aobf);

    gemm_pipe<1><<<g64, 256, 0, stream>>>(aobf, wo_t + wdd, bo + l * D_, tb, D_, D_, 1);
    ln_b<<<M_, 192, 0, stream>>>(tb, X0, ln1g + l * D_, ln1b + l * D_, X1, nullptr);

    Bias5 bpi; bpi.p[0] = bi + l * FF_;
    gemm256p<3, 1><<<dim3(12, 32), 512, 0, stream>>>(X1, wi_t + wdf, bpi, B_bf, D_, FF_, 0);
    gemm_pipe<1><<<g64, 256, 0, stream>>>(B_bf, wo2_t + wdf, bo2 + l * D_, tb, D_, FF_, 1);

    ln_b<<<M_, 192, 0, stream>>>(tb, X1, ln2g + l * D_, ln2b + l * D_, X0,
                                 (l == L_ - 1) ? (float*)d_out : nullptr);
  }
}

// Round 13
// 650.116 us; speedup vs baseline: 1.1391x; 1.0593x over previous
//
#include <hip/hip_runtime.h>

#define B_ 2
#define S_ 4096
#define D_ 768
#define H_ 12
#define DH_ 64
#define W_ 256
#define G_ 64
#define FF_ 3072
#define L_ 2
#define M_ (B_*S_)
#define NEGV -1e9f
#define NSPLIT 16

typedef short bf16x8 __attribute__((ext_vector_type(8)));
typedef float f32x4 __attribute__((ext_vector_type(4)));
typedef unsigned short u16;
typedef unsigned short u16x4 __attribute__((ext_vector_type(4)));

__device__ __forceinline__ u16 f2bf(float f) {
  union { float f; unsigned u; } a; a.f = f;
  unsigned r = a.u + 0x7FFFu + ((a.u >> 16) & 1u);
  return (u16)(r >> 16);
}
__device__ __forceinline__ float b2f(u16 u) {
  union { unsigned u; float f; } a; a.u = ((unsigned)u) << 16;
  return a.f;
}

__device__ __forceinline__ f32x4 mfma16(bf16x8 a, bf16x8 b, f32x4 c) {
  return __builtin_amdgcn_mfma_f32_16x16x32_bf16(a, b, c, 0, 0, 0);
}

__device__ __forceinline__ void gload16(const u16* g, u16* l) {
  __builtin_amdgcn_global_load_lds((const __attribute__((address_space(1))) void*)g,
                                   (__attribute__((address_space(3))) void*)l, 16, 0, 0);
}

__device__ __forceinline__ int xcd_swz(int bid, int nwg) {
  if ((nwg & 7) == 0) {
    int cpx = nwg >> 3;
    bid = (bid & 7) * cpx + (bid >> 3);
  }
  return bid;
}

// ---------------- batched weight transpose (7 DxD slabs) ---------
struct Ptr7 { const float* p[7]; };
__global__ __launch_bounds__(256) void wtrans7(Ptr7 in, u16* __restrict__ out) {
  __shared__ float tile[32][33];
  int z = blockIdx.z;
  int slab = z >> 1, l = z & 1;
  const float* src = in.p[slab] + (size_t)l * D_ * D_;
  u16* dst = out + (size_t)z * D_ * D_;
  int k0 = blockIdx.y * 32, n0 = blockIdx.x * 32;
  int tx = threadIdx.x, ty = threadIdx.y;
#pragma unroll
  for (int i = 0; i < 4; i++)
    tile[ty + i*8][tx] = src[(size_t)(k0 + ty + i*8) * D_ + n0 + tx];
  __syncthreads();
#pragma unroll
  for (int i = 0; i < 4; i++)
    dst[(size_t)(n0 + ty + i*8) * D_ + k0 + tx] = f2bf(tile[tx][ty + i*8]);
}

__global__ __launch_bounds__(256) void wtrans(const float* __restrict__ in,
                                              u16* __restrict__ out, int K, int N) {
  __shared__ float tile[32][33];
  size_t base = (size_t)blockIdx.z * K * N;
  int k0 = blockIdx.y * 32, n0 = blockIdx.x * 32;
  int tx = threadIdx.x, ty = threadIdx.y;
#pragma unroll
  for (int i = 0; i < 4; i++)
    tile[ty + i*8][tx] = in[base + (size_t)(k0 + ty + i*8) * N + n0 + tx];
  __syncthreads();
#pragma unroll
  for (int i = 0; i < 4; i++)
    out[base + (size_t)(n0 + ty + i*8) * K + k0 + tx] = f2bf(tile[tx][ty + i*8]);
}

// ---------------- f32 -> bf16 convert ----------------------------
__global__ __launch_bounds__(256) void conv_b(const float* __restrict__ in,
                                              u16* __restrict__ outb, int n4) {
  int i = blockIdx.x * 256 + threadIdx.x;
  if (i >= n4) return;
  float4 v = ((const float4*)in)[i];
  u16x4 o;
  o[0] = f2bf(v.x); o[1] = f2bf(v.y); o[2] = f2bf(v.z); o[3] = f2bf(v.w);
  ((u16x4*)outb)[i] = o;
}

template <int MODE>
__device__ __forceinline__ float epi_post(float v) {
  if (MODE == 2) return v * 0.125f;
  if (MODE == 3) {
    float y = 0.79788456f * (v + 0.044715f * v * v * v);
    float e = __expf(fminf(2.f * y, 20.f));
    return v * e / (e + 1.f);
  }
  return v;
}

struct Bias6 { const float* p[6]; };

// ============ 128x256 GEMM: 8 waves, BK=32, 3-ring LDS (72 KB) ====
// 2 blocks/CU (16 waves) -- occupancy is the lever vs the 256^2/128KB kernel.
// NW=5: batched qkv/kg/vg + folded qg (widx 5, only by 0/32 live).
// NW=1: single weight (FF1). MODE as epi_post.
template <int MODE, int NW>
__global__ __launch_bounds__(512, 4) void gemm_wide(const u16* __restrict__ A,
                                                    const u16* __restrict__ Wbase,
                                                    Bias6 bp,
                                                    u16* __restrict__ OutBase,
                                                    int Kdim, int Nstride, int l) {
  __shared__ u16 sh[36864];   // 3 x (A 4096 + B 8192) u16 = 72 KB
  int gx = gridDim.x;
  int bid = blockIdx.x + blockIdx.y * gx;
  bid = xcd_swz(bid, gx * gridDim.y);
  int bxx = bid % gx, by = bid / gx;
  int bm = by * 128;
  int widx, bn;
  const u16* Bt; u16* Cb; const float* bias;
  bool qscale = false;
  if (NW == 5) {
    widx = bxx / 3;
    bn = (bxx % 3) * 256;
    int slab;
    if (widx == 5) {                 // folded qg: rows [0,64) and [4096,4160)
      if (by != 0 && by != 32) return;
      slab = 3; qscale = true;
    } else {
      slab = widx + (widx >= 3 ? 1 : 0);
      qscale = (widx == 0);
    }
    Bt = Wbase + ((size_t)slab * L_ + l) * (size_t)D_ * D_;
    Cb = OutBase + (size_t)slab * M_ * D_;
    bias = bp.p[widx];
  } else {
    widx = 0;
    bn = bxx * 256;
    Bt = Wbase; Cb = OutBase; bias = bp.p[0];
  }
  int tid = threadIdx.x;
  int lane = tid & 63, wid = tid >> 6;
  int wr = wid >> 2, wc = wid & 3;          // 2 x 4 waves of 64x64
  int lr = lane & 15, lg = lane >> 4;

  // staging sources (pre-swizzled): chunk f -> line f>>3, slot f&7
  int fA = tid;
  int lA_ = fA >> 3, uA = (fA & 7) ^ (lA_ & 7);
  int rowA = lA_ * 2 + (uA >> 2), c8A = uA & 3;
  const u16* srcA = A + (size_t)(bm + rowA) * Kdim + c8A * 8;
  int fB0 = tid, fB1 = tid + 512;
  int lB0 = fB0 >> 3, uB0 = (fB0 & 7) ^ (lB0 & 7);
  int rB0 = lB0 * 2 + (uB0 >> 2), c8B0 = uB0 & 3;
  int lB1 = fB1 >> 3, uB1 = (fB1 & 7) ^ (lB1 & 7);
  int rB1 = lB1 * 2 + (uB1 >> 2), c8B1 = uB1 & 3;
  const u16* srcB0 = Bt + (size_t)(bn + rB0) * Kdim + c8B0 * 8;
  const u16* srcB1 = Bt + (size_t)(bn + rB1) * Kdim + c8B1 * 8;

  auto stage = [&](int kt, int buf) {
    int k1 = kt << 5;
    gload16(srcA + k1, &sh[buf * 4096 + fA * 8]);
    gload16(srcB0 + k1, &sh[12288 + buf * 8192 + fB0 * 8]);
    gload16(srcB1 + k1, &sh[12288 + buf * 8192 + fB1 * 8]);
  };

  // fragment LDS offsets (u16 units)
  int offa[4], offb[4];
#pragma unroll
  for (int i = 0; i < 4; i++) {
    int ra = wr * 64 + i * 16 + lr;
    int la = ra >> 1, sa = (((ra & 1) << 2) | lg) ^ (la & 7);
    offa[i] = la * 64 + sa * 8;
    int rb = wc * 64 + i * 16 + lr;
    int lb = rb >> 1, sb = (((rb & 1) << 2) | lg) ^ (lb & 7);
    offb[i] = lb * 64 + sb * 8;
  }

  int nt = Kdim >> 5;
  f32x4 acc[4][4] = {};

  stage(0, 0);
  if (nt > 1) stage(1, 1);

  for (int t = 0; t < nt; t++) {
    int cb = t % 3;
    if (t + 2 < nt) {
      stage(t + 2, (t + 2) % 3);
      asm volatile("s_waitcnt vmcnt(6)" ::: "memory");
    } else if (t + 1 < nt) {
      asm volatile("s_waitcnt vmcnt(3)" ::: "memory");
    } else {
      asm volatile("s_waitcnt vmcnt(0)" ::: "memory");
    }
    __builtin_amdgcn_s_barrier();
    __builtin_amdgcn_sched_barrier(0);
    const u16* ab = sh + cb * 4096;
    const u16* bb = sh + 12288 + cb * 8192;
    bf16x8 a[4], b[4];
#pragma unroll
    for (int i = 0; i < 4; i++) a[i] = *(const bf16x8*)&ab[offa[i]];
#pragma unroll
    for (int j = 0; j < 4; j++) b[j] = *(const bf16x8*)&bb[offb[j]];
    __builtin_amdgcn_s_setprio(1);
#pragma unroll
    for (int i = 0; i < 4; i++)
#pragma unroll
      for (int j = 0; j < 4; j++)
        acc[i][j] = mfma16(a[i], b[j], acc[i][j]);
    __builtin_amdgcn_s_setprio(0);
    __builtin_amdgcn_sched_barrier(0);
    __builtin_amdgcn_s_barrier();
    __builtin_amdgcn_sched_barrier(0);
  }

  int r0 = bm + wr * 64, c0 = bn + wc * 64;
  int cr = (lane >> 4) * 4, cc = lane & 15;
  float sc = qscale ? 0.125f : 1.0f;
#pragma unroll
  for (int j = 0; j < 4; j++) {
    int col = c0 + j * 16 + cc;
    float bv = bias[col];
#pragma unroll
    for (int i = 0; i < 4; i++)
#pragma unroll
      for (int r = 0; r < 4; r++) {
        size_t off = (size_t)(r0 + i * 16 + cr + r) * Nstride + col;
        Cb[off] = f2bf(epi_post<MODE>((acc[i][j][r] + bv) * sc));
      }
  }
}

// ============ 128x128 GEMM: 3-deep pipeline + LDS-bounce epilogue =
template <int MODE>
__global__ __launch_bounds__(256) void gemm_pipe(const u16* __restrict__ A,
                                                 const u16* __restrict__ Bt,
                                                 const float* __restrict__ bias,
                                                 u16* __restrict__ Cb,
                                                 int Ndim, int Kdim, int rowTileStride) {
  __shared__ u16 sh[24576];
  int gx = gridDim.x;
  int bid = blockIdx.x + blockIdx.y * gx;
  bid = xcd_swz(bid, gx * gridDim.y);
  int bm = (bid / gx) * rowTileStride * 128;
  int bn = (bid % gx) * 128;
  int tid = threadIdx.x;
  int lane = tid & 63, w = tid >> 6;
  int r0w = (w >> 1) * 64, c0w = (w & 1) * 64;
  int lr = lane & 15, lg = lane >> 4;

  int f0 = tid, l0 = f0 >> 3, s0 = (f0 & 7) ^ (l0 & 7);
  int row0 = (l0 << 1) | (s0 >> 2), c0s = (s0 & 3) * 8;
  int f1 = tid + 256, l1 = f1 >> 3, s1 = (f1 & 7) ^ (l1 & 7);
  int row1 = (l1 << 1) | (s1 >> 2), c1s = (s1 & 3) * 8;
  const u16* A0 = A + (size_t)(bm + row0) * Kdim + c0s;
  const u16* A1 = A + (size_t)(bm + row1) * Kdim + c1s;
  const u16* B0 = Bt + (size_t)(bn + row0) * Kdim + c0s;
  const u16* B1 = Bt + (size_t)(bn + row1) * Kdim + c1s;

  int offa[4], offb[4];
#pragma unroll
  for (int i = 0; i < 4; i++) {
    int ra = r0w + i * 16 + lr;
    int la = ra >> 1, sa = ((ra & 1) << 2) | lg;
    offa[i] = la * 64 + (sa ^ (la & 7)) * 8;
    int rb = c0w + i * 16 + lr;
    int lb = rb >> 1, sb = ((rb & 1) << 2) | lg;
    offb[i] = lb * 64 + (sb ^ (lb & 7)) * 8;
  }

  auto stage = [&](int kt, int buf) {
    int k1 = kt << 5;
    u16* ab = sh + buf * 4096;
    u16* bb = sh + 12288 + buf * 4096;
    gload16(A0 + k1, &ab[tid * 8]);
    gload16(A1 + k1, &ab[tid * 8 + 2048]);
    gload16(B0 + k1, &bb[tid * 8]);
    gload16(B1 + k1, &bb[tid * 8 + 2048]);
  };

  int nt = Kdim >> 5;
  f32x4 acc[4][4] = {};

  stage(0, 0);
  if (nt > 1) stage(1, 1);

  for (int t = 0; t < nt; t++) {
    int cb = t % 3;
    if (t + 2 < nt) {
      stage(t + 2, (t + 2) % 3);
      asm volatile("s_waitcnt vmcnt(8)" ::: "memory");
    } else if (t + 1 < nt) {
      asm volatile("s_waitcnt vmcnt(4)" ::: "memory");
    } else {
      asm volatile("s_waitcnt vmcnt(0)" ::: "memory");
    }
    __builtin_amdgcn_s_barrier();
    __builtin_amdgcn_sched_barrier(0);
    const u16* ab = sh + cb * 4096;
    const u16* bb = sh + 12288 + cb * 4096;
    bf16x8 a[4], b[4];
#pragma unroll
    for (int i = 0; i < 4; i++) a[i] = *(const bf16x8*)&ab[offa[i]];
#pragma unroll
    for (int j = 0; j < 4; j++) b[j] = *(const bf16x8*)&bb[offb[j]];
#pragma unroll
    for (int i = 0; i < 4; i++)
#pragma unroll
      for (int j = 0; j < 4; j++)
        acc[i][j] = mfma16(a[i], b[j], acc[i][j]);
    __builtin_amdgcn_sched_barrier(0);
    __builtin_amdgcn_s_barrier();
    __builtin_amdgcn_sched_barrier(0);
  }

  int cr = (lane >> 4) * 4, cc = lane & 15;
#pragma unroll
  for (int j = 0; j < 4; j++) {
    int col = c0w + j * 16 + cc;
    float bv = bias[bn + col];
#pragma unroll
    for (int i = 0; i < 4; i++)
#pragma unroll
      for (int r = 0; r < 4; r++) {
        int row = r0w + i * 16 + cr + r;
        int chunk = (col >> 3) ^ (row & 15);
        sh[row * 128 + chunk * 8 + (col & 7)] =
            f2bf(epi_post<MODE>(acc[i][j][r] + bv));
      }
  }
  __syncthreads();
  {
    int row = tid >> 1, half = tid & 1;
    u16* gro = Cb + (size_t)(bm + row) * Ndim + bn + half * 64;
#pragma unroll
    for (int c = 0; c < 8; c++) {
      int lc = half * 8 + c;
      int pc = lc ^ (row & 15);
      bf16x8 v = *(const bf16x8*)&sh[row * 128 + pc * 8];
      *(bf16x8*)(gro + c * 8) = v;
    }
  }
}

// ---------------- local windowed + global-key attention ----------
// grid (NC*4, B*H), block 128 (2 waves, 64 q-rows). Register double-buffer
// prefetch of K fragments and V staging rows across k-block iterations.
__global__ __launch_bounds__(128) void attn_local(const u16* __restrict__ qb,
                                                  const u16* __restrict__ kb_,
                                                  const u16* __restrict__ vb,
                                                  const float* __restrict__ mask,
                                                  u16* __restrict__ ao) {
  int bid = blockIdx.x + blockIdx.y * gridDim.x;
  bid = xcd_swz(bid, 1536);
  int cx = bid & 63, bh = bid >> 6;
  int c = cx >> 2, sub = cx & 3;
  int b = bh / H_, h = bh % H_;
  int tid = threadIdx.x;
  int w = tid >> 6, lane = tid & 63;
  int lr = lane & 15, lg = lane >> 4;

  __shared__ u16 vtT[64][72];
  __shared__ u16 plds[2][32][72];
  __shared__ unsigned char vflag[576];

  int base_off = sub * 64;
  int kwin0 = c * W_ - W_;
  for (int i = tid; i < 576; i += 128) {
    int kp = kwin0 + base_off + i;
    vflag[i] = (kp >= 0 && kp < S_ && mask[b * S_ + kp] == 0.0f) ? 1 : 0;
  }

  size_t hoff = (size_t)b * S_ * D_ + h * DH_;
  int qrow0 = c * W_ + base_off + w * 32;
  bf16x8 aq[2][2];
#pragma unroll
  for (int fi = 0; fi < 2; fi++)
#pragma unroll
    for (int ks = 0; ks < 2; ks++)
      aq[fi][ks] = *(const bf16x8*)(qb + hoff + (size_t)(qrow0 + fi * 16 + lr) * D_ + ks * 32 + lg * 8);

  int K0 = kwin0 + base_off;
  int kb_lo = (K0 < 0) ? (1 + ((-K0) >> 6)) : 1;
  int kb_hi = 9;
  { int hi = 1 + ((S_ - 64 - K0) >> 6); if (hi < 9) kb_hi = hi; }
  int niter = 1 + (kb_hi - kb_lo + 1);

  int stg_k4 = tid >> 3, stg_j = tid & 7;
  int stg_dh0 = stg_j * 8;

  float ls[2][4];
  f32x4 o[2][4] = {};
#pragma unroll
  for (int fi = 0; fi < 2; fi++)
#pragma unroll
    for (int r = 0; r < 4; r++) ls[fi][r] = 0.f;

  bf16x8 ck0[4], ck1[4], nk0[4], nk1[4], cv[4], nv[4];
#pragma unroll
  for (int nj = 0; nj < 4; nj++) {
    const u16* ks8 = kb_ + hoff + (size_t)(nj * 16 + lr) * D_ + lg * 8;
    ck0[nj] = *(const bf16x8*)(ks8);
    ck1[nj] = *(const bf16x8*)(ks8 + 32);
  }
#pragma unroll
  for (int p = 0; p < 4; p++)
    cv[p] = *(const bf16x8*)(vb + hoff + (size_t)(p * 16 + stg_k4) * D_ + stg_dh0);

  for (int it = 0; it < niter; it++) {
    int kb = (it == 0) ? 0 : (kb_lo + it - 1);

    __builtin_amdgcn_s_barrier();
#pragma unroll
    for (int p = 0; p < 4; p++) {
      int key = p * 16 + stg_k4;
      u16* basep = &vtT[stg_dh0][key ^ (stg_j << 3)];
#pragma unroll
      for (int e = 0; e < 8; e++) basep[e * 72] = (u16)cv[p][e];
    }
    if (it + 1 < niter) {
      int kb2 = kb_lo + it;
      int ks2 = K0 + (kb2 - 1) * 64;
#pragma unroll
      for (int nj = 0; nj < 4; nj++) {
        const u16* ks8 = kb_ + hoff + (size_t)(ks2 + nj * 16 + lr) * D_ + lg * 8;
        nk0[nj] = *(const bf16x8*)(ks8);
        nk1[nj] = *(const bf16x8*)(ks8 + 32);
      }
#pragma unroll
      for (int p = 0; p < 4; p++)
        nv[p] = *(const bf16x8*)(vb + hoff + (size_t)(ks2 + p * 16 + stg_k4) * D_ + stg_dh0);
    }
    asm volatile("s_waitcnt lgkmcnt(0)" ::: "memory");
    __builtin_amdgcn_s_barrier();
    __builtin_amdgcn_sched_barrier(0);

    f32x4 sc[2][4];
#pragma unroll
    for (int fi = 0; fi < 2; fi++)
#pragma unroll
      for (int nj = 0; nj < 4; nj++) {
        f32x4 t = {};
        t = mfma16(aq[fi][0], ck0[nj], t);
        t = mfma16(aq[fi][1], ck1[nj], t);
        sc[fi][nj] = t;
      }

    if (kb >= 2 && kb <= 8) {
#pragma unroll
      for (int nj = 0; nj < 4; nj++) {
        bool kv = vflag[(kb - 1) * 64 + nj * 16 + lr] != 0;
#pragma unroll
        for (int fi = 0; fi < 2; fi++)
#pragma unroll
          for (int r = 0; r < 4; r++)
            sc[fi][nj][r] = kv ? sc[fi][nj][r] : NEGV;
      }
    } else if (kb > 0) {
#pragma unroll
      for (int nj = 0; nj < 4; nj++) {
        int fidx = (kb - 1) * 64 + nj * 16 + lr;
        int koff = base_off + fidx;
        bool kv = vflag[fidx] != 0;
#pragma unroll
        for (int fi = 0; fi < 2; fi++)
#pragma unroll
          for (int r = 0; r < 4; r++) {
            int wq = base_off + w * 32 + fi * 16 + lg * 4 + r;
            if (!(kv && koff >= wq && koff <= wq + 2 * W_)) sc[fi][nj][r] = NEGV;
          }
      }
    }

#pragma unroll
    for (int fi = 0; fi < 2; fi++)
#pragma unroll
      for (int r = 0; r < 4; r++) {
        float ps = 0.f;
#pragma unroll
        for (int nj = 0; nj < 4; nj++) {
          float p = __expf(sc[fi][nj][r]);
          sc[fi][nj][r] = p;
          ps += p;
        }
#pragma unroll
        for (int d = 1; d < 16; d <<= 1) ps += __shfl_xor(ps, d);
        ls[fi][r] += ps;
      }

#pragma unroll
    for (int fi = 0; fi < 2; fi++)
#pragma unroll
      for (int nj = 0; nj < 4; nj++)
#pragma unroll
        for (int r = 0; r < 4; r++)
          plds[w][fi * 16 + lg * 4 + r][nj * 16 + lr] = f2bf(sc[fi][nj][r]);
    asm volatile("s_waitcnt lgkmcnt(0)" ::: "memory");
    __builtin_amdgcn_sched_barrier(0);

    bf16x8 ap[2][2];
#pragma unroll
    for (int fi = 0; fi < 2; fi++)
#pragma unroll
      for (int ks = 0; ks < 2; ks++)
        ap[fi][ks] = *(const bf16x8*)&plds[w][fi * 16 + lr][ks * 32 + lg * 8];
#pragma unroll
    for (int dj = 0; dj < 4; dj++) {
      int xr = ((dj * 16 + lr) >> 3) & 7;
#pragma unroll
      for (int ks = 0; ks < 2; ks++) {
        bf16x8 bv = *(const bf16x8*)&vtT[dj * 16 + lr][(ks * 32 + lg * 8) ^ (xr << 3)];
        o[0][dj] = mfma16(ap[0][ks], bv, o[0][dj]);
        o[1][dj] = mfma16(ap[1][ks], bv, o[1][dj]);
      }
    }

    if (it + 1 < niter) {
#pragma unroll
      for (int j = 0; j < 4; j++) {
        ck0[j] = nk0[j]; ck1[j] = nk1[j]; cv[j] = nv[j];
      }
    }
  }

#pragma unroll
  for (int fi = 0; fi < 2; fi++)
#pragma unroll
    for (int dj = 0; dj < 4; dj++)
#pragma unroll
      for (int r = 0; r < 4; r++) {
        int row = qrow0 + fi * 16 + lg * 4 + r;
        float v = o[fi][dj][r] / ls[fi][r];
        ao[hoff + (size_t)row * D_ + dj * 16 + lr] = f2bf(v);
      }
}

// ---------------- global attention, split-K partials -------------
__global__ __launch_bounds__(128) void attn_gsplit(const u16* __restrict__ qg,
                                                   const u16* __restrict__ kg,
                                                   const u16* __restrict__ vg,
                                                   float* __restrict__ opart,
                                                   float* __restrict__ lpart) {
  int sp = blockIdx.x, bh = blockIdx.y;
  int b = bh / H_, h = bh % H_;
  int tid = threadIdx.x, w = tid >> 6, lane = tid & 63;
  int lr = lane & 15, lg = lane >> 4;
  __shared__ u16 vtT[64][72];
  __shared__ u16 plds[2][32][72];
  size_t hoff = (size_t)b * S_ * D_ + h * DH_;
  int qrow0 = w * 32;
  bf16x8 aq[2][2];
#pragma unroll
  for (int fi = 0; fi < 2; fi++)
#pragma unroll
    for (int ks = 0; ks < 2; ks++)
      aq[fi][ks] = *(const bf16x8*)(qg + hoff + (size_t)(qrow0 + fi * 16 + lr) * D_ + ks * 32 + lg * 8);
  float ls[2][4];
  f32x4 o[2][4] = {};
#pragma unroll
  for (int fi = 0; fi < 2; fi++)
#pragma unroll
    for (int r = 0; r < 4; r++) ls[fi][r] = 0.f;

  int stg_k4 = tid >> 3, stg_j = tid & 7;
  int stg_dh0 = stg_j * 8;

  for (int kb = 0; kb < 4; kb++) {
    int kstart = sp * 256 + kb * 64;
    __syncthreads();
#pragma unroll
    for (int p = 0; p < 4; p++) {
      int key = p * 16 + stg_k4;
      bf16x8 row = *(const bf16x8*)(vg + hoff + (size_t)(kstart + key) * D_ + stg_dh0);
      u16* basep = &vtT[stg_dh0][key ^ (stg_j << 3)];
#pragma unroll
      for (int e = 0; e < 8; e++) basep[e * 72] = (u16)row[e];
    }
    __syncthreads();

    bf16x8 bk0[4], bk1[4];
#pragma unroll
    for (int nj = 0; nj < 4; nj++) {
      const u16* ks8 = kg + hoff + (size_t)(kstart + nj * 16 + lr) * D_ + lg * 8;
      bk0[nj] = *(const bf16x8*)(ks8);
      bk1[nj] = *(const bf16x8*)(ks8 + 32);
    }
    f32x4 sc[2][4];
#pragma unroll
    for (int fi = 0; fi < 2; fi++)
#pragma unroll
      for (int nj = 0; nj < 4; nj++) {
        f32x4 t = {};
        t = mfma16(aq[fi][0], bk0[nj], t);
        t = mfma16(aq[fi][1], bk1[nj], t);
        sc[fi][nj] = t;
      }
#pragma unroll
    for (int fi = 0; fi < 2; fi++)
#pragma unroll
      for (int r = 0; r < 4; r++) {
        float ps = 0.f;
#pragma unroll
        for (int nj = 0; nj < 4; nj++) {
          float p = __expf(sc[fi][nj][r]);
          sc[fi][nj][r] = p;
          ps += p;
        }
#pragma unroll
        for (int d = 1; d < 16; d <<= 1) ps += __shfl_xor(ps, d);
        ls[fi][r] += ps;
      }
#pragma unroll
    for (int fi = 0; fi < 2; fi++)
#pragma unroll
      for (int nj = 0; nj < 4; nj++)
#pragma unroll
        for (int r = 0; r < 4; r++)
          plds[w][fi * 16 + lg * 4 + r][nj * 16 + lr] = f2bf(sc[fi][nj][r]);
    asm volatile("s_waitcnt lgkmcnt(0)" ::: "memory");
    __builtin_amdgcn_sched_barrier(0);
    bf16x8 ap[2][2];
#pragma unroll
    for (int fi = 0; fi < 2; fi++)
#pragma unroll
      for (int ks = 0; ks < 2; ks++)
        ap[fi][ks] = *(const bf16x8*)&plds[w][fi * 16 + lr][ks * 32 + lg * 8];
#pragma unroll
    for (int dj = 0; dj < 4; dj++) {
      int xr = ((dj * 16 + lr) >> 3) & 7;
#pragma unroll
      for (int ks = 0; ks < 2; ks++) {
        bf16x8 bv = *(const bf16x8*)&vtT[dj * 16 + lr][(ks * 32 + lg * 8) ^ (xr << 3)];
        o[0][dj] = mfma16(ap[0][ks], bv, o[0][dj]);
        o[1][dj] = mfma16(ap[1][ks], bv, o[1][dj]);
      }
    }
  }

  size_t pbase = (size_t)(bh * NSPLIT + sp) * 64;
#pragma unroll
  for (int fi = 0; fi < 2; fi++)
#pragma unroll
    for (int r = 0; r < 4; r++) {
      int row = qrow0 + fi * 16 + lg * 4 + r;
      if (lr == 0) lpart[pbase + row] = ls[fi][r];
#pragma unroll
      for (int dj = 0; dj < 4; dj++)
        opart[(pbase + row) * 64 + dj * 16 + lr] = o[fi][dj][r];
    }
}

// ---------------- combine split-K partials (plain sums) ----------
__global__ __launch_bounds__(256) void attn_gcombine(const float* __restrict__ opart,
                                                     const float* __restrict__ lpart,
                                                     u16* __restrict__ ao) {
  int bh = blockIdx.x;
  int b = bh / H_, h = bh % H_;
  int t = threadIdx.x;
  __shared__ float lt[64];
  if (t < 64) {
    float lsum = 0.f;
#pragma unroll
    for (int sp = 0; sp < NSPLIT; sp++)
      lsum += lpart[(size_t)(bh * NSPLIT + sp) * 64 + t];
    lt[t] = lsum;
  }
  __syncthreads();
  int row = t >> 2, c0 = (t & 3) * 16;
  float acc[16] = {};
  for (int sp = 0; sp < NSPLIT; sp++) {
    const float* op = opart + ((size_t)(bh * NSPLIT + sp) * 64 + row) * 64 + c0;
#pragma unroll
    for (int j = 0; j < 16; j++) acc[j] += op[j];
  }
  float inv = 1.f / lt[row];
  size_t hoff = (size_t)b * S_ * D_ + h * DH_;
#pragma unroll
  for (int j = 0; j < 16; j++)
    ao[hoff + (size_t)row * D_ + c0 + j] = f2bf(acc[j] * inv);
}

// ---------------- residual + LayerNorm (bf16 in/out) -------------
__global__ __launch_bounds__(192) void ln_b(const u16* __restrict__ x,
                                            const u16* __restrict__ res,
                                            const float* __restrict__ gg,
                                            const float* __restrict__ bb,
                                            u16* __restrict__ outb,
                                            float* __restrict__ outf) {
  int row = blockIdx.x, t = threadIdx.x;
  const u16* xr = x + (size_t)row * D_;
  const u16* rr = res + (size_t)row * D_;
  u16x4 xv = *(const u16x4*)&xr[t * 4];
  u16x4 rv = *(const u16x4*)&rr[t * 4];
  float v[4];
#pragma unroll
  for (int e = 0; e < 4; e++) v[e] = b2f(xv[e]) + b2f(rv[e]);
  __shared__ float sha[3], shb[3];
  float s = v[0] + v[1] + v[2] + v[3];
#pragma unroll
  for (int d = 1; d < 64; d <<= 1) s += __shfl_xor(s, d);
  if ((t & 63) == 0) sha[t >> 6] = s;
  __syncthreads();
  float mu = (sha[0] + sha[1] + sha[2]) * (1.f / 768.f);
  float dd[4], s2 = 0.f;
#pragma unroll
  for (int e = 0; e < 4; e++) { dd[e] = v[e] - mu; s2 += dd[e] * dd[e]; }
#pragma unroll
  for (int d = 1; d < 64; d <<= 1) s2 += __shfl_xor(s2, d);
  if ((t & 63) == 0) shb[t >> 6] = s2;
  __syncthreads();
  float var = (shb[0] + shb[1] + shb[2]) * (1.f / 768.f);
  float rs = rsqrtf(var + 1e-5f);
  float4 gv = *(const float4*)&gg[t * 4];
  float4 bv = *(const float4*)&bb[t * 4];
  float y0 = dd[0] * rs * gv.x + bv.x;
  float y1 = dd[1] * rs * gv.y + bv.y;
  float y2 = dd[2] * rs * gv.z + bv.z;
  float y3 = dd[3] * rs * gv.w + bv.w;
  u16x4 ov;
  ov[0] = f2bf(y0); ov[1] = f2bf(y1); ov[2] = f2bf(y2); ov[3] = f2bf(y3);
  *(u16x4*)&outb[(size_t)row * D_ + t * 4] = ov;
  if (outf) {
    float4 of = {y0, y1, y2, y3};
    *(float4*)&outf[(size_t)row * D_ + t * 4] = of;
  }
}

// =================================================================
extern "C" void kernel_launch(void* const* d_in, const int* in_sizes, int n_in,
                              void* d_out, int out_size, void* d_ws, size_t ws_size,
                              hipStream_t stream) {
  (void)in_sizes; (void)n_in; (void)out_size; (void)ws_size;
  const float* hidden = (const float*)d_in[0];
  const float* mask   = (const float*)d_in[1];
  const float* Wq  = (const float*)d_in[4];   const float* bq  = (const float*)d_in[5];
  const float* Wk  = (const float*)d_in[6];   const float* bk  = (const float*)d_in[7];
  const float* Wv  = (const float*)d_in[8];   const float* bv  = (const float*)d_in[9];
  const float* Wqg = (const float*)d_in[10];  const float* bqg = (const float*)d_in[11];
  const float* Wkg = (const float*)d_in[12];  const float* bkg = (const float*)d_in[13];
  const float* Wvg = (const float*)d_in[14];  const float* bvg = (const float*)d_in[15];
  const float* Wo  = (const float*)d_in[16];  const float* bo  = (const float*)d_in[17];
  const float* Wi  = (const float*)d_in[18];  const float* bi  = (const float*)d_in[19];
  const float* Wo2 = (const float*)d_in[20];  const float* bo2 = (const float*)d_in[21];
  const float* ln1g = (const float*)d_in[22]; const float* ln1b = (const float*)d_in[23];
  const float* ln2g = (const float*)d_in[24]; const float* ln2b = (const float*)d_in[25];

  char* ws = (char*)d_ws;
  size_t off = 0;
  auto alloc = [&](size_t bytes) -> void* {
    void* p = ws + off;
    off += (bytes + 255) & ~(size_t)255;
    return p;
  };
  const size_t DD = (size_t)D_ * D_;
  const size_t DF = (size_t)D_ * FF_;
  u16* Wt = (u16*)alloc((7 * L_ * DD + 2 * L_ * DF) * 2);
  u16* wo_t  = Wt + 6 * L_ * DD;
  u16* wi_t  = Wt + 7 * L_ * DD;
  u16* wo2_t = Wt + 7 * L_ * DD + L_ * DF;

  u16* X0 = (u16*)alloc((size_t)M_ * D_ * 2);
  u16* X1 = (u16*)alloc((size_t)M_ * D_ * 2);
  u16* tb = (u16*)alloc((size_t)M_ * D_ * 2);
  u16* B_bf = (u16*)alloc((size_t)M_ * FF_ * 2);
  // q,k,v,qg,kg,vg contiguous: slab index s -> qbf + s*M*D
  u16* qbf  = (u16*)alloc((size_t)M_ * D_ * 2 * 6);
  u16* kbf  = qbf + 1 * (size_t)M_ * D_;
  u16* vbf  = qbf + 2 * (size_t)M_ * D_;
  u16* qgbf = qbf + 3 * (size_t)M_ * D_;
  u16* kgbf = qbf + 4 * (size_t)M_ * D_;
  u16* vgbf = qbf + 5 * (size_t)M_ * D_;
  u16* aobf = (u16*)alloc((size_t)M_ * D_ * 2);
  float* opart = (float*)alloc((size_t)B_ * H_ * NSPLIT * 64 * 64 * 4);
  float* lpart = (float*)alloc((size_t)B_ * H_ * NSPLIT * 64 * 4);

  dim3 tb32(32, 8);
  Ptr7 wp;
  wp.p[0] = Wq; wp.p[1] = Wk; wp.p[2] = Wv; wp.p[3] = Wqg;
  wp.p[4] = Wkg; wp.p[5] = Wvg; wp.p[6] = Wo;
  wtrans7<<<dim3(24, 24, 14), tb32, 0, stream>>>(wp, Wt);
  wtrans<<<dim3(96, 24, 2), tb32, 0, stream>>>(Wi,  wi_t,  D_, FF_);
  wtrans<<<dim3(24, 96, 2), tb32, 0, stream>>>(Wo2, wo2_t, FF_, D_);

  conv_b<<<(M_ * D_ / 4 + 255) / 256, 256, 0, stream>>>(hidden, X0, M_ * D_ / 4);

  for (int l = 0; l < L_; l++) {
    size_t wdd = (size_t)l * DD;
    size_t wdf = (size_t)l * DF;
    dim3 g64(6, 64);

    Bias6 bp;
    bp.p[0] = bq  + l * D_;
    bp.p[1] = bk  + l * D_;
    bp.p[2] = bv  + l * D_;
    bp.p[3] = bkg + l * D_;
    bp.p[4] = bvg + l * D_;
    bp.p[5] = bqg + l * D_;
    gemm_wide<1, 5><<<dim3(18, 64), 512, 0, stream>>>(X0, Wt, bp, qbf, D_, D_, l);

    attn_local<<<dim3((S_ / W_) * 4, B_ * H_), 128, 0, stream>>>(qbf, kbf, vbf, mask, aobf);
    attn_gsplit<<<dim3(NSPLIT, B_ * H_), 128, 0, stream>>>(qgbf, kgbf, vgbf, opart, lpart);
    attn_gcombine<<<B_ * H_, 256, 0, stream>>>(opart, lpart, aobf);

    gemm_pipe<1><<<g64, 256, 0, stream>>>(aobf, wo_t + wdd, bo + l * D_, tb, D_, D_, 1);
    ln_b<<<M_, 192, 0, stream>>>(tb, X0, ln1g + l * D_, ln1b + l * D_, X1, nullptr);

    Bias6 bpi; bpi.p[0] = bi + l * FF_;
    gemm_wide<3, 1><<<dim3(12, 64), 512, 0, stream>>>(X1, wi_t + wdf, bpi, B_bf, D_, FF_, 0);
    gemm_pipe<1><<<g64, 256, 0, stream>>>(B_bf, wo2_t + wdf, bo2 + l * D_, tb, D_, FF_, 1);

    ln_b<<<M_, 192, 0, stream>>>(tb, X1, ln2g + l * D_, ln2b + l * D_, X0,
                                 (l == L_ - 1) ? (float*)d_out : nullptr);
  }
}

// Round 14
// 646.994 us; speedup vs baseline: 1.1446x; 1.0048x over previous
//
#include <hip/hip_runtime.h>

#define B_ 2
#define S_ 4096
#define D_ 768
#define H_ 12
#define DH_ 64
#define W_ 256
#define G_ 64
#define FF_ 3072
#define L_ 2
#define M_ (B_*S_)
#define NEGV -1e9f
#define NSPLIT 16

typedef short bf16x8 __attribute__((ext_vector_type(8)));
typedef float f32x4 __attribute__((ext_vector_type(4)));
typedef unsigned short u16;
typedef unsigned short u16x4 __attribute__((ext_vector_type(4)));

__device__ __forceinline__ u16 f2bf(float f) {
  union { float f; unsigned u; } a; a.f = f;
  unsigned r = a.u + 0x7FFFu + ((a.u >> 16) & 1u);
  return (u16)(r >> 16);
}
__device__ __forceinline__ float b2f(u16 u) {
  union { unsigned u; float f; } a; a.u = ((unsigned)u) << 16;
  return a.f;
}

__device__ __forceinline__ f32x4 mfma16(bf16x8 a, bf16x8 b, f32x4 c) {
  return __builtin_amdgcn_mfma_f32_16x16x32_bf16(a, b, c, 0, 0, 0);
}

__device__ __forceinline__ void gload16(const u16* g, u16* l) {
  __builtin_amdgcn_global_load_lds((const __attribute__((address_space(1))) void*)g,
                                   (__attribute__((address_space(3))) void*)l, 16, 0, 0);
}

__device__ __forceinline__ int xcd_swz(int bid, int nwg) {
  if ((nwg & 7) == 0) {
    int cpx = nwg >> 3;
    bid = (bid & 7) * cpx + (bid >> 3);
  }
  return bid;
}

// ---------------- batched weight transpose (7 DxD slabs) ---------
struct Ptr7 { const float* p[7]; };
__global__ __launch_bounds__(256) void wtrans7(Ptr7 in, u16* __restrict__ out) {
  __shared__ float tile[32][33];
  int z = blockIdx.z;
  int slab = z >> 1, l = z & 1;
  const float* src = in.p[slab] + (size_t)l * D_ * D_;
  u16* dst = out + (size_t)z * D_ * D_;
  int k0 = blockIdx.y * 32, n0 = blockIdx.x * 32;
  int tx = threadIdx.x, ty = threadIdx.y;
#pragma unroll
  for (int i = 0; i < 4; i++)
    tile[ty + i*8][tx] = src[(size_t)(k0 + ty + i*8) * D_ + n0 + tx];
  __syncthreads();
#pragma unroll
  for (int i = 0; i < 4; i++)
    dst[(size_t)(n0 + ty + i*8) * D_ + k0 + tx] = f2bf(tile[tx][ty + i*8]);
}

__global__ __launch_bounds__(256) void wtrans(const float* __restrict__ in,
                                              u16* __restrict__ out, int K, int N) {
  __shared__ float tile[32][33];
  size_t base = (size_t)blockIdx.z * K * N;
  int k0 = blockIdx.y * 32, n0 = blockIdx.x * 32;
  int tx = threadIdx.x, ty = threadIdx.y;
#pragma unroll
  for (int i = 0; i < 4; i++)
    tile[ty + i*8][tx] = in[base + (size_t)(k0 + ty + i*8) * N + n0 + tx];
  __syncthreads();
#pragma unroll
  for (int i = 0; i < 4; i++)
    out[base + (size_t)(n0 + ty + i*8) * K + k0 + tx] = f2bf(tile[tx][ty + i*8]);
}

// ---------------- f32 -> bf16 convert ----------------------------
__global__ __launch_bounds__(256) void conv_b(const float* __restrict__ in,
                                              u16* __restrict__ outb, int n4) {
  int i = blockIdx.x * 256 + threadIdx.x;
  if (i >= n4) return;
  float4 v = ((const float4*)in)[i];
  u16x4 o;
  o[0] = f2bf(v.x); o[1] = f2bf(v.y); o[2] = f2bf(v.z); o[3] = f2bf(v.w);
  ((u16x4*)outb)[i] = o;
}

template <int MODE>
__device__ __forceinline__ float epi_post(float v) {
  if (MODE == 2) return v * 0.125f;
  if (MODE == 3) {
    float y = 0.79788456f * (v + 0.044715f * v * v * v);
    float e = __expf(fminf(2.f * y, 20.f));
    return v * e / (e + 1.f);
  }
  return v;
}

struct Bias6 { const float* p[6]; };

// ============ 128x256 GEMM: 8 waves, BK=32, 3-ring LDS (72 KB) ====
// NW=5: batched q/k/v/kg/vg + folded qg.  v (widx2) and vg (widx4) are
// emitted TRANSPOSED to VtB: element (m=b*4096+s, col=h*64+dh) stored at
// VtB[(b*768+col)*4096 + s]; acc r=0..3 are 4 consecutive s -> one u16x4.
template <int MODE, int NW>
__global__ __launch_bounds__(512, 4) void gemm_wide(const u16* __restrict__ A,
                                                    const u16* __restrict__ Wbase,
                                                    Bias6 bp,
                                                    u16* __restrict__ OutBase,
                                                    u16* __restrict__ VtB,
                                                    int Kdim, int Nstride, int l) {
  __shared__ u16 sh[36864];
  int gx = gridDim.x;
  int bid = blockIdx.x + blockIdx.y * gx;
  bid = xcd_swz(bid, gx * gridDim.y);
  int bxx = bid % gx, by = bid / gx;
  int bm = by * 128;
  int widx, bn;
  const u16* Bt; u16* Cb; const float* bias;
  bool qscale = false;
  if (NW == 5) {
    widx = bxx / 3;
    bn = (bxx % 3) * 256;
    int slab;
    if (widx == 5) {
      if (by != 0 && by != 32) return;
      slab = 3; qscale = true;
    } else {
      slab = widx + (widx >= 3 ? 1 : 0);
      qscale = (widx == 0);
    }
    Bt = Wbase + ((size_t)slab * L_ + l) * (size_t)D_ * D_;
    Cb = OutBase + (size_t)slab * M_ * D_;
    bias = bp.p[widx];
  } else {
    widx = 0;
    bn = bxx * 256;
    Bt = Wbase; Cb = OutBase; bias = bp.p[0];
  }
  int tid = threadIdx.x;
  int lane = tid & 63, wid = tid >> 6;
  int wr = wid >> 2, wc = wid & 3;
  int lr = lane & 15, lg = lane >> 4;

  int fA = tid;
  int lA_ = fA >> 3, uA = (fA & 7) ^ (lA_ & 7);
  int rowA = lA_ * 2 + (uA >> 2), c8A = uA & 3;
  const u16* srcA = A + (size_t)(bm + rowA) * Kdim + c8A * 8;
  int fB0 = tid, fB1 = tid + 512;
  int lB0 = fB0 >> 3, uB0 = (fB0 & 7) ^ (lB0 & 7);
  int rB0 = lB0 * 2 + (uB0 >> 2), c8B0 = uB0 & 3;
  int lB1 = fB1 >> 3, uB1 = (fB1 & 7) ^ (lB1 & 7);
  int rB1 = lB1 * 2 + (uB1 >> 2), c8B1 = uB1 & 3;
  const u16* srcB0 = Bt + (size_t)(bn + rB0) * Kdim + c8B0 * 8;
  const u16* srcB1 = Bt + (size_t)(bn + rB1) * Kdim + c8B1 * 8;

  auto stage = [&](int kt, int buf) {
    int k1 = kt << 5;
    gload16(srcA + k1, &sh[buf * 4096 + fA * 8]);
    gload16(srcB0 + k1, &sh[12288 + buf * 8192 + fB0 * 8]);
    gload16(srcB1 + k1, &sh[12288 + buf * 8192 + fB1 * 8]);
  };

  int offa[4], offb[4];
#pragma unroll
  for (int i = 0; i < 4; i++) {
    int ra = wr * 64 + i * 16 + lr;
    int la = ra >> 1, sa = (((ra & 1) << 2) | lg) ^ (la & 7);
    offa[i] = la * 64 + sa * 8;
    int rb = wc * 64 + i * 16 + lr;
    int lb = rb >> 1, sb = (((rb & 1) << 2) | lg) ^ (lb & 7);
    offb[i] = lb * 64 + sb * 8;
  }

  int nt = Kdim >> 5;
  f32x4 acc[4][4] = {};

  stage(0, 0);
  if (nt > 1) stage(1, 1);

  for (int t = 0; t < nt; t++) {
    int cb = t % 3;
    if (t + 2 < nt) {
      stage(t + 2, (t + 2) % 3);
      asm volatile("s_waitcnt vmcnt(6)" ::: "memory");
    } else if (t + 1 < nt) {
      asm volatile("s_waitcnt vmcnt(3)" ::: "memory");
    } else {
      asm volatile("s_waitcnt vmcnt(0)" ::: "memory");
    }
    __builtin_amdgcn_s_barrier();
    __builtin_amdgcn_sched_barrier(0);
    const u16* ab = sh + cb * 4096;
    const u16* bb = sh + 12288 + cb * 8192;
    bf16x8 a[4], b[4];
#pragma unroll
    for (int i = 0; i < 4; i++) a[i] = *(const bf16x8*)&ab[offa[i]];
#pragma unroll
    for (int j = 0; j < 4; j++) b[j] = *(const bf16x8*)&bb[offb[j]];
    __builtin_amdgcn_s_setprio(1);
#pragma unroll
    for (int i = 0; i < 4; i++)
#pragma unroll
      for (int j = 0; j < 4; j++)
        acc[i][j] = mfma16(a[i], b[j], acc[i][j]);
    __builtin_amdgcn_s_setprio(0);
    __builtin_amdgcn_sched_barrier(0);
    __builtin_amdgcn_s_barrier();
    __builtin_amdgcn_sched_barrier(0);
  }

  int r0 = bm + wr * 64, c0 = bn + wc * 64;
  int cr = (lane >> 4) * 4, cc = lane & 15;

  if (NW == 5 && (widx == 2 || widx == 4)) {
    // transposed V/VG epilogue
    u16* Vt = VtB + (widx == 4 ? (size_t)M_ * D_ : 0);
#pragma unroll
    for (int j = 0; j < 4; j++) {
      int col = c0 + j * 16 + cc;
      float bv = bias[col];
#pragma unroll
      for (int i = 0; i < 4; i++) {
        int srow = r0 + i * 16 + cr;
        int bb2 = srow >> 12, ss = srow & 4095;
        u16x4 ov;
#pragma unroll
        for (int r = 0; r < 4; r++) ov[r] = f2bf(acc[i][j][r] + bv);
        *(u16x4*)&Vt[((size_t)(bb2 * D_ + col) << 12) + ss] = ov;
      }
    }
    return;
  }

  float sc = qscale ? 0.125f : 1.0f;
#pragma unroll
  for (int j = 0; j < 4; j++) {
    int col = c0 + j * 16 + cc;
    float bv = bias[col];
#pragma unroll
    for (int i = 0; i < 4; i++)
#pragma unroll
      for (int r = 0; r < 4; r++) {
        size_t off = (size_t)(r0 + i * 16 + cr + r) * Nstride + col;
        Cb[off] = f2bf(epi_post<MODE>((acc[i][j][r] + bv) * sc));
      }
  }
}

// ============ 128x128 GEMM: 3-deep pipeline + LDS-bounce epilogue =
template <int MODE>
__global__ __launch_bounds__(256) void gemm_pipe(const u16* __restrict__ A,
                                                 const u16* __restrict__ Bt,
                                                 const float* __restrict__ bias,
                                                 u16* __restrict__ Cb,
                                                 int Ndim, int Kdim, int rowTileStride) {
  __shared__ u16 sh[24576];
  int gx = gridDim.x;
  int bid = blockIdx.x + blockIdx.y * gx;
  bid = xcd_swz(bid, gx * gridDim.y);
  int bm = (bid / gx) * rowTileStride * 128;
  int bn = (bid % gx) * 128;
  int tid = threadIdx.x;
  int lane = tid & 63, w = tid >> 6;
  int r0w = (w >> 1) * 64, c0w = (w & 1) * 64;
  int lr = lane & 15, lg = lane >> 4;

  int f0 = tid, l0 = f0 >> 3, s0 = (f0 & 7) ^ (l0 & 7);
  int row0 = (l0 << 1) | (s0 >> 2), c0s = (s0 & 3) * 8;
  int f1 = tid + 256, l1 = f1 >> 3, s1 = (f1 & 7) ^ (l1 & 7);
  int row1 = (l1 << 1) | (s1 >> 2), c1s = (s1 & 3) * 8;
  const u16* A0 = A + (size_t)(bm + row0) * Kdim + c0s;
  const u16* A1 = A + (size_t)(bm + row1) * Kdim + c1s;
  const u16* B0 = Bt + (size_t)(bn + row0) * Kdim + c0s;
  const u16* B1 = Bt + (size_t)(bn + row1) * Kdim + c1s;

  int offa[4], offb[4];
#pragma unroll
  for (int i = 0; i < 4; i++) {
    int ra = r0w + i * 16 + lr;
    int la = ra >> 1, sa = ((ra & 1) << 2) | lg;
    offa[i] = la * 64 + (sa ^ (la & 7)) * 8;
    int rb = c0w + i * 16 + lr;
    int lb = rb >> 1, sb = ((rb & 1) << 2) | lg;
    offb[i] = lb * 64 + (sb ^ (lb & 7)) * 8;
  }

  auto stage = [&](int kt, int buf) {
    int k1 = kt << 5;
    u16* ab = sh + buf * 4096;
    u16* bb = sh + 12288 + buf * 4096;
    gload16(A0 + k1, &ab[tid * 8]);
    gload16(A1 + k1, &ab[tid * 8 + 2048]);
    gload16(B0 + k1, &bb[tid * 8]);
    gload16(B1 + k1, &bb[tid * 8 + 2048]);
  };

  int nt = Kdim >> 5;
  f32x4 acc[4][4] = {};

  stage(0, 0);
  if (nt > 1) stage(1, 1);

  for (int t = 0; t < nt; t++) {
    int cb = t % 3;
    if (t + 2 < nt) {
      stage(t + 2, (t + 2) % 3);
      asm volatile("s_waitcnt vmcnt(8)" ::: "memory");
    } else if (t + 1 < nt) {
      asm volatile("s_waitcnt vmcnt(4)" ::: "memory");
    } else {
      asm volatile("s_waitcnt vmcnt(0)" ::: "memory");
    }
    __builtin_amdgcn_s_barrier();
    __builtin_amdgcn_sched_barrier(0);
    const u16* ab = sh + cb * 4096;
    const u16* bb = sh + 12288 + cb * 4096;
    bf16x8 a[4], b[4];
#pragma unroll
    for (int i = 0; i < 4; i++) a[i] = *(const bf16x8*)&ab[offa[i]];
#pragma unroll
    for (int j = 0; j < 4; j++) b[j] = *(const bf16x8*)&bb[offb[j]];
#pragma unroll
    for (int i = 0; i < 4; i++)
#pragma unroll
      for (int j = 0; j < 4; j++)
        acc[i][j] = mfma16(a[i], b[j], acc[i][j]);
    __builtin_amdgcn_sched_barrier(0);
    __builtin_amdgcn_s_barrier();
    __builtin_amdgcn_sched_barrier(0);
  }

  int cr = (lane >> 4) * 4, cc = lane & 15;
#pragma unroll
  for (int j = 0; j < 4; j++) {
    int col = c0w + j * 16 + cc;
    float bv = bias[bn + col];
#pragma unroll
    for (int i = 0; i < 4; i++)
#pragma unroll
      for (int r = 0; r < 4; r++) {
        int row = r0w + i * 16 + cr + r;
        int chunk = (col >> 3) ^ (row & 15);
        sh[row * 128 + chunk * 8 + (col & 7)] =
            f2bf(epi_post<MODE>(acc[i][j][r] + bv));
      }
  }
  __syncthreads();
  {
    int row = tid >> 1, half = tid & 1;
    u16* gro = Cb + (size_t)(bm + row) * Ndim + bn + half * 64;
#pragma unroll
    for (int c = 0; c < 8; c++) {
      int lc = half * 8 + c;
      int pc = lc ^ (row & 15);
      bf16x8 v = *(const bf16x8*)&sh[row * 128 + pc * 8];
      *(bf16x8*)(gro + c * 8) = v;
    }
  }
}

// ---------------- local windowed + global-key attention ----------
// grid (NC*4, B*H), block 128 (2 waves, 64 q-rows). Barrier-free main
// loop: V read as B-fragments directly from transposed global V (vt),
// K register double-buffered; plds is per-wave (lgkmcnt only).
__global__ __launch_bounds__(128) void attn_local(const u16* __restrict__ qb,
                                                  const u16* __restrict__ kb_,
                                                  const u16* __restrict__ vt,
                                                  const float* __restrict__ mask,
                                                  u16* __restrict__ ao) {
  int bid = blockIdx.x + blockIdx.y * gridDim.x;
  bid = xcd_swz(bid, 1536);
  int cx = bid & 63, bh = bid >> 6;
  int c = cx >> 2, sub = cx & 3;
  int b = bh / H_, h = bh % H_;
  int tid = threadIdx.x;
  int w = tid >> 6, lane = tid & 63;
  int lr = lane & 15, lg = lane >> 4;

  __shared__ u16 plds[2][32][72];
  __shared__ unsigned char vflag[576];

  int base_off = sub * 64;
  int kwin0 = c * W_ - W_;
  for (int i = tid; i < 576; i += 128) {
    int kp = kwin0 + base_off + i;
    vflag[i] = (kp >= 0 && kp < S_ && mask[b * S_ + kp] == 0.0f) ? 1 : 0;
  }
  __syncthreads();

  size_t hoff = (size_t)b * S_ * D_ + h * DH_;
  const u16* vth = vt + ((size_t)(b * D_ + h * DH_) << 12);
  int qrow0 = c * W_ + base_off + w * 32;
  bf16x8 aq[2][2];
#pragma unroll
  for (int fi = 0; fi < 2; fi++)
#pragma unroll
    for (int ks = 0; ks < 2; ks++)
      aq[fi][ks] = *(const bf16x8*)(qb + hoff + (size_t)(qrow0 + fi * 16 + lr) * D_ + ks * 32 + lg * 8);

  int K0 = kwin0 + base_off;
  int kb_lo = (K0 < 0) ? (1 + ((-K0) >> 6)) : 1;
  int kb_hi = 9;
  { int hi = 1 + ((S_ - 64 - K0) >> 6); if (hi < 9) kb_hi = hi; }
  int niter = 1 + (kb_hi - kb_lo + 1);

  float ls[2][4];
  f32x4 o[2][4] = {};
#pragma unroll
  for (int fi = 0; fi < 2; fi++)
#pragma unroll
    for (int r = 0; r < 4; r++) ls[fi][r] = 0.f;

  bf16x8 ck0[4], ck1[4], nk0[4], nk1[4];
#pragma unroll
  for (int nj = 0; nj < 4; nj++) {
    const u16* ks8 = kb_ + hoff + (size_t)(nj * 16 + lr) * D_ + lg * 8;
    ck0[nj] = *(const bf16x8*)(ks8);
    ck1[nj] = *(const bf16x8*)(ks8 + 32);
  }

  for (int it = 0; it < niter; it++) {
    int kb = (it == 0) ? 0 : (kb_lo + it - 1);
    int kstart = (it == 0) ? 0 : (K0 + (kb - 1) * 64);

    // QK with resident K registers
    f32x4 sc[2][4];
#pragma unroll
    for (int fi = 0; fi < 2; fi++)
#pragma unroll
      for (int nj = 0; nj < 4; nj++) {
        f32x4 t = {};
        t = mfma16(aq[fi][0], ck0[nj], t);
        t = mfma16(aq[fi][1], ck1[nj], t);
        sc[fi][nj] = t;
      }

    // V fragments for this iteration (latency covered by softmax below)
    bf16x8 vf[4][2];
#pragma unroll
    for (int dj = 0; dj < 4; dj++)
#pragma unroll
      for (int ks = 0; ks < 2; ks++)
        vf[dj][ks] = *(const bf16x8*)&vth[((size_t)(dj * 16 + lr) << 12) + kstart + ks * 32 + lg * 8];

    // prefetch next K
    if (it + 1 < niter) {
      int ks2 = K0 + (kb_lo + it - 1) * 64;
#pragma unroll
      for (int nj = 0; nj < 4; nj++) {
        const u16* ks8 = kb_ + hoff + (size_t)(ks2 + nj * 16 + lr) * D_ + lg * 8;
        nk0[nj] = *(const bf16x8*)(ks8);
        nk1[nj] = *(const bf16x8*)(ks8 + 32);
      }
    }

    if (kb >= 2 && kb <= 8) {
#pragma unroll
      for (int nj = 0; nj < 4; nj++) {
        bool kv = vflag[(kb - 1) * 64 + nj * 16 + lr] != 0;
#pragma unroll
        for (int fi = 0; fi < 2; fi++)
#pragma unroll
          for (int r = 0; r < 4; r++)
            sc[fi][nj][r] = kv ? sc[fi][nj][r] : NEGV;
      }
    } else if (kb > 0) {
#pragma unroll
      for (int nj = 0; nj < 4; nj++) {
        int fidx = (kb - 1) * 64 + nj * 16 + lr;
        int koff = base_off + fidx;
        bool kv = vflag[fidx] != 0;
#pragma unroll
        for (int fi = 0; fi < 2; fi++)
#pragma unroll
          for (int r = 0; r < 4; r++) {
            int wq = base_off + w * 32 + fi * 16 + lg * 4 + r;
            if (!(kv && koff >= wq && koff <= wq + 2 * W_)) sc[fi][nj][r] = NEGV;
          }
      }
    }

    // fixed-max softmax accumulation
#pragma unroll
    for (int fi = 0; fi < 2; fi++)
#pragma unroll
      for (int r = 0; r < 4; r++) {
        float ps = 0.f;
#pragma unroll
        for (int nj = 0; nj < 4; nj++) {
          float p = __expf(sc[fi][nj][r]);
          sc[fi][nj][r] = p;
          ps += p;
        }
#pragma unroll
        for (int d = 1; d < 16; d <<= 1) ps += __shfl_xor(ps, d);
        ls[fi][r] += ps;
      }

    // P relayout through per-wave LDS (no cross-wave sync needed)
#pragma unroll
    for (int fi = 0; fi < 2; fi++)
#pragma unroll
      for (int nj = 0; nj < 4; nj++)
#pragma unroll
        for (int r = 0; r < 4; r++)
          plds[w][fi * 16 + lg * 4 + r][nj * 16 + lr] = f2bf(sc[fi][nj][r]);
    asm volatile("s_waitcnt lgkmcnt(0)" ::: "memory");
    __builtin_amdgcn_sched_barrier(0);

    bf16x8 ap[2][2];
#pragma unroll
    for (int fi = 0; fi < 2; fi++)
#pragma unroll
      for (int ks = 0; ks < 2; ks++)
        ap[fi][ks] = *(const bf16x8*)&plds[w][fi * 16 + lr][ks * 32 + lg * 8];
#pragma unroll
    for (int dj = 0; dj < 4; dj++)
#pragma unroll
      for (int ks = 0; ks < 2; ks++) {
        o[0][dj] = mfma16(ap[0][ks], vf[dj][ks], o[0][dj]);
        o[1][dj] = mfma16(ap[1][ks], vf[dj][ks], o[1][dj]);
      }

    if (it + 1 < niter) {
#pragma unroll
      for (int j = 0; j < 4; j++) {
        ck0[j] = nk0[j]; ck1[j] = nk1[j];
      }
    }
  }

#pragma unroll
  for (int fi = 0; fi < 2; fi++)
#pragma unroll
    for (int dj = 0; dj < 4; dj++)
#pragma unroll
      for (int r = 0; r < 4; r++) {
        int row = qrow0 + fi * 16 + lg * 4 + r;
        float v = o[fi][dj][r] / ls[fi][r];
        ao[hoff + (size_t)row * D_ + dj * 16 + lr] = f2bf(v);
      }
}

// ---------------- global attention, split-K partials -------------
// Barrier-free: V fragments direct from transposed global VG.
__global__ __launch_bounds__(128) void attn_gsplit(const u16* __restrict__ qg,
                                                   const u16* __restrict__ kg,
                                                   const u16* __restrict__ vgt,
                                                   float* __restrict__ opart,
                                                   float* __restrict__ lpart) {
  int sp = blockIdx.x, bh = blockIdx.y;
  int b = bh / H_, h = bh % H_;
  int tid = threadIdx.x, w = tid >> 6, lane = tid & 63;
  int lr = lane & 15, lg = lane >> 4;
  __shared__ u16 plds[2][32][72];
  size_t hoff = (size_t)b * S_ * D_ + h * DH_;
  const u16* vth = vgt + ((size_t)(b * D_ + h * DH_) << 12);
  int qrow0 = w * 32;
  bf16x8 aq[2][2];
#pragma unroll
  for (int fi = 0; fi < 2; fi++)
#pragma unroll
    for (int ks = 0; ks < 2; ks++)
      aq[fi][ks] = *(const bf16x8*)(qg + hoff + (size_t)(qrow0 + fi * 16 + lr) * D_ + ks * 32 + lg * 8);
  float ls[2][4];
  f32x4 o[2][4] = {};
#pragma unroll
  for (int fi = 0; fi < 2; fi++)
#pragma unroll
    for (int r = 0; r < 4; r++) ls[fi][r] = 0.f;

  for (int kb = 0; kb < 4; kb++) {
    int kstart = sp * 256 + kb * 64;

    bf16x8 bk0[4], bk1[4];
#pragma unroll
    for (int nj = 0; nj < 4; nj++) {
      const u16* ks8 = kg + hoff + (size_t)(kstart + nj * 16 + lr) * D_ + lg * 8;
      bk0[nj] = *(const bf16x8*)(ks8);
      bk1[nj] = *(const bf16x8*)(ks8 + 32);
    }
    bf16x8 vf[4][2];
#pragma unroll
    for (int dj = 0; dj < 4; dj++)
#pragma unroll
      for (int ks = 0; ks < 2; ks++)
        vf[dj][ks] = *(const bf16x8*)&vth[((size_t)(dj * 16 + lr) << 12) + kstart + ks * 32 + lg * 8];

    f32x4 sc[2][4];
#pragma unroll
    for (int fi = 0; fi < 2; fi++)
#pragma unroll
      for (int nj = 0; nj < 4; nj++) {
        f32x4 t = {};
        t = mfma16(aq[fi][0], bk0[nj], t);
        t = mfma16(aq[fi][1], bk1[nj], t);
        sc[fi][nj] = t;
      }
#pragma unroll
    for (int fi = 0; fi < 2; fi++)
#pragma unroll
      for (int r = 0; r < 4; r++) {
        float ps = 0.f;
#pragma unroll
        for (int nj = 0; nj < 4; nj++) {
          float p = __expf(sc[fi][nj][r]);
          sc[fi][nj][r] = p;
          ps += p;
        }
#pragma unroll
        for (int d = 1; d < 16; d <<= 1) ps += __shfl_xor(ps, d);
        ls[fi][r] += ps;
      }
#pragma unroll
    for (int fi = 0; fi < 2; fi++)
#pragma unroll
      for (int nj = 0; nj < 4; nj++)
#pragma unroll
        for (int r = 0; r < 4; r++)
          plds[w][fi * 16 + lg * 4 + r][nj * 16 + lr] = f2bf(sc[fi][nj][r]);
    asm volatile("s_waitcnt lgkmcnt(0)" ::: "memory");
    __builtin_amdgcn_sched_barrier(0);
    bf16x8 ap[2][2];
#pragma unroll
    for (int fi = 0; fi < 2; fi++)
#pragma unroll
      for (int ks = 0; ks < 2; ks++)
        ap[fi][ks] = *(const bf16x8*)&plds[w][fi * 16 + lr][ks * 32 + lg * 8];
#pragma unroll
    for (int dj = 0; dj < 4; dj++)
#pragma unroll
      for (int ks = 0; ks < 2; ks++) {
        o[0][dj] = mfma16(ap[0][ks], vf[dj][ks], o[0][dj]);
        o[1][dj] = mfma16(ap[1][ks], vf[dj][ks], o[1][dj]);
      }
  }

  size_t pbase = (size_t)(bh * NSPLIT + sp) * 64;
#pragma unroll
  for (int fi = 0; fi < 2; fi++)
#pragma unroll
    for (int r = 0; r < 4; r++) {
      int row = qrow0 + fi * 16 + lg * 4 + r;
      if (lr == 0) lpart[pbase + row] = ls[fi][r];
#pragma unroll
      for (int dj = 0; dj < 4; dj++)
        opart[(pbase + row) * 64 + dj * 16 + lr] = o[fi][dj][r];
    }
}

// ---------------- combine split-K partials (plain sums) ----------
__global__ __launch_bounds__(256) void attn_gcombine(const float* __restrict__ opart,
                                                     const float* __restrict__ lpart,
                                                     u16* __restrict__ ao) {
  int bh = blockIdx.x;
  int b = bh / H_, h = bh % H_;
  int t = threadIdx.x;
  __shared__ float lt[64];
  if (t < 64) {
    float lsum = 0.f;
#pragma unroll
    for (int sp = 0; sp < NSPLIT; sp++)
      lsum += lpart[(size_t)(bh * NSPLIT + sp) * 64 + t];
    lt[t] = lsum;
  }
  __syncthreads();
  int row = t >> 2, c0 = (t & 3) * 16;
  float acc[16] = {};
  for (int sp = 0; sp < NSPLIT; sp++) {
    const float* op = opart + ((size_t)(bh * NSPLIT + sp) * 64 + row) * 64 + c0;
#pragma unroll
    for (int j = 0; j < 16; j++) acc[j] += op[j];
  }
  float inv = 1.f / lt[row];
  size_t hoff = (size_t)b * S_ * D_ + h * DH_;
#pragma unroll
  for (int j = 0; j < 16; j++)
    ao[hoff + (size_t)row * D_ + c0 + j] = f2bf(acc[j] * inv);
}

// ---------------- residual + LayerNorm (bf16 in/out) -------------
__global__ __launch_bounds__(192) void ln_b(const u16* __restrict__ x,
                                            const u16* __restrict__ res,
                                            const float* __restrict__ gg,
                                            const float* __restrict__ bb,
                                            u16* __restrict__ outb,
                                            float* __restrict__ outf) {
  int row = blockIdx.x, t = threadIdx.x;
  const u16* xr = x + (size_t)row * D_;
  const u16* rr = res + (size_t)row * D_;
  u16x4 xv = *(const u16x4*)&xr[t * 4];
  u16x4 rv = *(const u16x4*)&rr[t * 4];
  float v[4];
#pragma unroll
  for (int e = 0; e < 4; e++) v[e] = b2f(xv[e]) + b2f(rv[e]);
  __shared__ float sha[3], shb[3];
  float s = v[0] + v[1] + v[2] + v[3];
#pragma unroll
  for (int d = 1; d < 64; d <<= 1) s += __shfl_xor(s, d);
  if ((t & 63) == 0) sha[t >> 6] = s;
  __syncthreads();
  float mu = (sha[0] + sha[1] + sha[2]) * (1.f / 768.f);
  float dd[4], s2 = 0.f;
#pragma unroll
  for (int e = 0; e < 4; e++) { dd[e] = v[e] - mu; s2 += dd[e] * dd[e]; }
#pragma unroll
  for (int d = 1; d < 64; d <<= 1) s2 += __shfl_xor(s2, d);
  if ((t & 63) == 0) shb[t >> 6] = s2;
  __syncthreads();
  float var = (shb[0] + shb[1] + shb[2]) * (1.f / 768.f);
  float rs = rsqrtf(var + 1e-5f);
  float4 gv = *(const float4*)&gg[t * 4];
  float4 bv = *(const float4*)&bb[t * 4];
  float y0 = dd[0] * rs * gv.x + bv.x;
  float y1 = dd[1] * rs * gv.y + bv.y;
  float y2 = dd[2] * rs * gv.z + bv.z;
  float y3 = dd[3] * rs * gv.w + bv.w;
  u16x4 ov;
  ov[0] = f2bf(y0); ov[1] = f2bf(y1); ov[2] = f2bf(y2); ov[3] = f2bf(y3);
  *(u16x4*)&outb[(size_t)row * D_ + t * 4] = ov;
  if (outf) {
    float4 of = {y0, y1, y2, y3};
    *(float4*)&outf[(size_t)row * D_ + t * 4] = of;
  }
}

// =================================================================
extern "C" void kernel_launch(void* const* d_in, const int* in_sizes, int n_in,
                              void* d_out, int out_size, void* d_ws, size_t ws_size,
                              hipStream_t stream) {
  (void)in_sizes; (void)n_in; (void)out_size; (void)ws_size;
  const float* hidden = (const float*)d_in[0];
  const float* mask   = (const float*)d_in[1];
  const float* Wq  = (const float*)d_in[4];   const float* bq  = (const float*)d_in[5];
  const float* Wk  = (const float*)d_in[6];   const float* bk  = (const float*)d_in[7];
  const float* Wv  = (const float*)d_in[8];   const float* bv  = (const float*)d_in[9];
  const float* Wqg = (const float*)d_in[10];  const float* bqg = (const float*)d_in[11];
  const float* Wkg = (const float*)d_in[12];  const float* bkg = (const float*)d_in[13];
  const float* Wvg = (const float*)d_in[14];  const float* bvg = (const float*)d_in[15];
  const float* Wo  = (const float*)d_in[16];  const float* bo  = (const float*)d_in[17];
  const float* Wi  = (const float*)d_in[18];  const float* bi  = (const float*)d_in[19];
  const float* Wo2 = (const float*)d_in[20];  const float* bo2 = (const float*)d_in[21];
  const float* ln1g = (const float*)d_in[22]; const float* ln1b = (const float*)d_in[23];
  const float* ln2g = (const float*)d_in[24]; const float* ln2b = (const float*)d_in[25];

  char* ws = (char*)d_ws;
  size_t off = 0;
  auto alloc = [&](size_t bytes) -> void* {
    void* p = ws + off;
    off += (bytes + 255) & ~(size_t)255;
    return p;
  };
  const size_t DD = (size_t)D_ * D_;
  const size_t DF = (size_t)D_ * FF_;
  u16* Wt = (u16*)alloc((7 * L_ * DD + 2 * L_ * DF) * 2);
  u16* wo_t  = Wt + 6 * L_ * DD;
  u16* wi_t  = Wt + 7 * L_ * DD;
  u16* wo2_t = Wt + 7 * L_ * DD + L_ * DF;

  u16* X0 = (u16*)alloc((size_t)M_ * D_ * 2);
  u16* X1 = (u16*)alloc((size_t)M_ * D_ * 2);
  u16* tb = (u16*)alloc((size_t)M_ * D_ * 2);
  u16* B_bf = (u16*)alloc((size_t)M_ * FF_ * 2);
  u16* qbf  = (u16*)alloc((size_t)M_ * D_ * 2 * 6);
  u16* kbf  = qbf + 1 * (size_t)M_ * D_;
  u16* qgbf = qbf + 3 * (size_t)M_ * D_;
  u16* kgbf = qbf + 4 * (size_t)M_ * D_;
  u16* vtb  = (u16*)alloc((size_t)M_ * D_ * 2 * 2);   // V^T and VG^T
  u16* vgt  = vtb + (size_t)M_ * D_;
  u16* aobf = (u16*)alloc((size_t)M_ * D_ * 2);
  float* opart = (float*)alloc((size_t)B_ * H_ * NSPLIT * 64 * 64 * 4);
  float* lpart = (float*)alloc((size_t)B_ * H_ * NSPLIT * 64 * 4);

  dim3 tb32(32, 8);
  Ptr7 wp;
  wp.p[0] = Wq; wp.p[1] = Wk; wp.p[2] = Wv; wp.p[3] = Wqg;
  wp.p[4] = Wkg; wp.p[5] = Wvg; wp.p[6] = Wo;
  wtrans7<<<dim3(24, 24, 14), tb32, 0, stream>>>(wp, Wt);
  wtrans<<<dim3(96, 24, 2), tb32, 0, stream>>>(Wi,  wi_t,  D_, FF_);
  wtrans<<<dim3(24, 96, 2), tb32, 0, stream>>>(Wo2, wo2_t, FF_, D_);

  conv_b<<<(M_ * D_ / 4 + 255) / 256, 256, 0, stream>>>(hidden, X0, M_ * D_ / 4);

  for (int l = 0; l < L_; l++) {
    size_t wdd = (size_t)l * DD;
    size_t wdf = (size_t)l * DF;
    dim3 g64(6, 64);

    Bias6 bp;
    bp.p[0] = bq  + l * D_;
    bp.p[1] = bk  + l * D_;
    bp.p[2] = bv  + l * D_;
    bp.p[3] = bkg + l * D_;
    bp.p[4] = bvg + l * D_;
    bp.p[5] = bqg + l * D_;
    gemm_wide<1, 5><<<dim3(18, 64), 512, 0, stream>>>(X0, Wt, bp, qbf, vtb, D_, D_, l);

    attn_local<<<dim3((S_ / W_) * 4, B_ * H_), 128, 0, stream>>>(qbf, kbf, vtb, mask, aobf);
    attn_gsplit<<<dim3(NSPLIT, B_ * H_), 128, 0, stream>>>(qgbf, kgbf, vgt, opart, lpart);
    attn_gcombine<<<B_ * H_, 256, 0, stream>>>(opart, lpart, aobf);

    gemm_pipe<1><<<g64, 256, 0, stream>>>(aobf, wo_t + wdd, bo + l * D_, tb, D_, D_, 1);
    ln_b<<<M_, 192, 0, stream>>>(tb, X0, ln1g + l * D_, ln1b + l * D_, X1, nullptr);

    Bias6 bpi; bpi.p[0] = bi + l * FF_;
    gemm_wide<3, 1><<<dim3(12, 64), 512, 0, stream>>>(X1, wi_t + wdf, bpi, B_bf, nullptr, D_, FF_, 0);
    gemm_pipe<1><<<g64, 256, 0, stream>>>(B_bf, wo2_t + wdf, bo2 + l * D_, tb, D_, FF_, 1);

    ln_b<<<M_, 192, 0, stream>>>(tb, X1, ln2g + l * D_, ln2b + l * D_, X0,
                                 (l == L_ - 1) ? (float*)d_out : nullptr);
  }
}

// Round 15
// 637.413 us; speedup vs baseline: 1.1618x; 1.0150x over previous
//
#include <hip/hip_runtime.h>

#define B_ 2
#define S_ 4096
#define D_ 768
#define H_ 12
#define DH_ 64
#define W_ 256
#define G_ 64
#define FF_ 3072
#define L_ 2
#define M_ (B_*S_)
#define NEGV -1e9f
#define NSPLIT 16

typedef short bf16x8 __attribute__((ext_vector_type(8)));
typedef float f32x4 __attribute__((ext_vector_type(4)));
typedef unsigned short u16;
typedef unsigned short u16x4 __attribute__((ext_vector_type(4)));

__device__ __forceinline__ u16 f2bf(float f) {
  union { float f; unsigned u; } a; a.f = f;
  unsigned r = a.u + 0x7FFFu + ((a.u >> 16) & 1u);
  return (u16)(r >> 16);
}
__device__ __forceinline__ float b2f(u16 u) {
  union { unsigned u; float f; } a; a.u = ((unsigned)u) << 16;
  return a.f;
}

__device__ __forceinline__ f32x4 mfma16(bf16x8 a, bf16x8 b, f32x4 c) {
  return __builtin_amdgcn_mfma_f32_16x16x32_bf16(a, b, c, 0, 0, 0);
}

__device__ __forceinline__ void gload16(const u16* g, u16* l) {
  __builtin_amdgcn_global_load_lds((const __attribute__((address_space(1))) void*)g,
                                   (__attribute__((address_space(3))) void*)l, 16, 0, 0);
}

__device__ __forceinline__ int xcd_swz(int bid, int nwg) {
  if ((nwg & 7) == 0) {
    int cpx = nwg >> 3;
    bid = (bid & 7) * cpx + (bid >> 3);
  }
  return bid;
}

// ---------------- batched weight transpose (7 DxD slabs) ---------
struct Ptr7 { const float* p[7]; };
__global__ __launch_bounds__(256) void wtrans7(Ptr7 in, u16* __restrict__ out) {
  __shared__ float tile[32][33];
  int z = blockIdx.z;
  int slab = z >> 1, l = z & 1;
  const float* src = in.p[slab] + (size_t)l * D_ * D_;
  u16* dst = out + (size_t)z * D_ * D_;
  int k0 = blockIdx.y * 32, n0 = blockIdx.x * 32;
  int tx = threadIdx.x, ty = threadIdx.y;
#pragma unroll
  for (int i = 0; i < 4; i++)
    tile[ty + i*8][tx] = src[(size_t)(k0 + ty + i*8) * D_ + n0 + tx];
  __syncthreads();
#pragma unroll
  for (int i = 0; i < 4; i++)
    dst[(size_t)(n0 + ty + i*8) * D_ + k0 + tx] = f2bf(tile[tx][ty + i*8]);
}

__global__ __launch_bounds__(256) void wtrans(const float* __restrict__ in,
                                              u16* __restrict__ out, int K, int N) {
  __shared__ float tile[32][33];
  size_t base = (size_t)blockIdx.z * K * N;
  int k0 = blockIdx.y * 32, n0 = blockIdx.x * 32;
  int tx = threadIdx.x, ty = threadIdx.y;
#pragma unroll
  for (int i = 0; i < 4; i++)
    tile[ty + i*8][tx] = in[base + (size_t)(k0 + ty + i*8) * N + n0 + tx];
  __syncthreads();
#pragma unroll
  for (int i = 0; i < 4; i++)
    out[base + (size_t)(n0 + ty + i*8) * K + k0 + tx] = f2bf(tile[tx][ty + i*8]);
}

// ---------------- f32 -> bf16 convert ----------------------------
__global__ __launch_bounds__(256) void conv_b(const float* __restrict__ in,
                                              u16* __restrict__ outb, int n4) {
  int i = blockIdx.x * 256 + threadIdx.x;
  if (i >= n4) return;
  float4 v = ((const float4*)in)[i];
  u16x4 o;
  o[0] = f2bf(v.x); o[1] = f2bf(v.y); o[2] = f2bf(v.z); o[3] = f2bf(v.w);
  ((u16x4*)outb)[i] = o;
}

template <int MODE>
__device__ __forceinline__ float epi_post(float v) {
  if (MODE == 2) return v * 0.125f;
  if (MODE == 3) {
    float y = 0.79788456f * (v + 0.044715f * v * v * v);
    float e = __expf(fminf(2.f * y, 20.f));
    return v * e / (e + 1.f);
  }
  return v;
}

struct Bias6 { const float* p[6]; };

// ============ 128x256 GEMM: 8 waves, BK=32, 2-ring LDS (48 KB) ====
// 3 blocks/CU (24 waves).  NW=5: batched q/k/v/kg/vg + folded qg; v (widx2)
// and vg (widx4) emitted TRANSPOSED via an LDS-bounce epilogue (coalesced
// bf16x8 stores along s).
template <int MODE, int NW>
__global__ __launch_bounds__(512, 4) void gemm_wide(const u16* __restrict__ A,
                                                    const u16* __restrict__ Wbase,
                                                    Bias6 bp,
                                                    u16* __restrict__ OutBase,
                                                    u16* __restrict__ VtB,
                                                    int Kdim, int Nstride, int l) {
  __shared__ u16 sh[24576];   // 2 x (A 4096 + B 8192) u16 = 48 KB
  int gx = gridDim.x;
  int bid = blockIdx.x + blockIdx.y * gx;
  bid = xcd_swz(bid, gx * gridDim.y);
  int bxx = bid % gx, by = bid / gx;
  int bm = by * 128;
  int widx, bn;
  const u16* Bt; u16* Cb; const float* bias;
  bool qscale = false;
  if (NW == 5) {
    widx = bxx / 3;
    bn = (bxx % 3) * 256;
    int slab;
    if (widx == 5) {
      if (by != 0 && by != 32) return;
      slab = 3; qscale = true;
    } else {
      slab = widx + (widx >= 3 ? 1 : 0);
      qscale = (widx == 0);
    }
    Bt = Wbase + ((size_t)slab * L_ + l) * (size_t)D_ * D_;
    Cb = OutBase + (size_t)slab * M_ * D_;
    bias = bp.p[widx];
  } else {
    widx = 0;
    bn = bxx * 256;
    Bt = Wbase; Cb = OutBase; bias = bp.p[0];
  }
  int tid = threadIdx.x;
  int lane = tid & 63, wid = tid >> 6;
  int wr = wid >> 2, wc = wid & 3;
  int lr = lane & 15, lg = lane >> 4;

  int fA = tid;
  int lA_ = fA >> 3, uA = (fA & 7) ^ (lA_ & 7);
  int rowA = lA_ * 2 + (uA >> 2), c8A = uA & 3;
  const u16* srcA = A + (size_t)(bm + rowA) * Kdim + c8A * 8;
  int fB0 = tid, fB1 = tid + 512;
  int lB0 = fB0 >> 3, uB0 = (fB0 & 7) ^ (lB0 & 7);
  int rB0 = lB0 * 2 + (uB0 >> 2), c8B0 = uB0 & 3;
  int lB1 = fB1 >> 3, uB1 = (fB1 & 7) ^ (lB1 & 7);
  int rB1 = lB1 * 2 + (uB1 >> 2), c8B1 = uB1 & 3;
  const u16* srcB0 = Bt + (size_t)(bn + rB0) * Kdim + c8B0 * 8;
  const u16* srcB1 = Bt + (size_t)(bn + rB1) * Kdim + c8B1 * 8;

  auto stage = [&](int kt, int buf) {
    int k1 = kt << 5;
    gload16(srcA + k1, &sh[buf * 4096 + fA * 8]);
    gload16(srcB0 + k1, &sh[8192 + buf * 8192 + fB0 * 8]);
    gload16(srcB1 + k1, &sh[8192 + buf * 8192 + fB1 * 8]);
  };

  int offa[4], offb[4];
#pragma unroll
  for (int i = 0; i < 4; i++) {
    int ra = wr * 64 + i * 16 + lr;
    int la = ra >> 1, sa = (((ra & 1) << 2) | lg) ^ (la & 7);
    offa[i] = la * 64 + sa * 8;
    int rb = wc * 64 + i * 16 + lr;
    int lb = rb >> 1, sb = (((rb & 1) << 2) | lg) ^ (lb & 7);
    offb[i] = lb * 64 + sb * 8;
  }

  int nt = Kdim >> 5;
  f32x4 acc[4][4] = {};

  stage(0, 0);

  for (int t = 0; t < nt; t++) {
    int cb = t & 1;
    if (t + 1 < nt) {
      stage(t + 1, cb ^ 1);
      asm volatile("s_waitcnt vmcnt(3)" ::: "memory");
    } else {
      asm volatile("s_waitcnt vmcnt(0)" ::: "memory");
    }
    __builtin_amdgcn_s_barrier();
    __builtin_amdgcn_sched_barrier(0);
    const u16* ab = sh + cb * 4096;
    const u16* bb = sh + 8192 + cb * 8192;
    bf16x8 a[4], b[4];
#pragma unroll
    for (int i = 0; i < 4; i++) a[i] = *(const bf16x8*)&ab[offa[i]];
#pragma unroll
    for (int j = 0; j < 4; j++) b[j] = *(const bf16x8*)&bb[offb[j]];
    __builtin_amdgcn_s_setprio(1);
#pragma unroll
    for (int i = 0; i < 4; i++)
#pragma unroll
      for (int j = 0; j < 4; j++)
        acc[i][j] = mfma16(a[i], b[j], acc[i][j]);
    __builtin_amdgcn_s_setprio(0);
    __builtin_amdgcn_sched_barrier(0);
    __builtin_amdgcn_s_barrier();
    __builtin_amdgcn_sched_barrier(0);
  }

  int r0 = bm + wr * 64, c0 = bn + wc * 64;
  int cr = (lane >> 4) * 4, cc = lane & 15;

  if (NW == 5 && (widx == 2 || widx == 4)) {
    // transposed V/VG epilogue via LDS bounce: two 128-col passes.
    // LDS layout per pass: sh[colp*128 + (s ^ ((colp&15)<<3))]
    u16* Vt = VtB + (widx == 4 ? (size_t)M_ * D_ : 0);
    int bb2 = bm >> 12, ssb = bm & 4095;
    __syncthreads();
#pragma unroll
    for (int p = 0; p < 2; p++) {
      if (p) __syncthreads();
      if ((wc >> 1) == p) {
#pragma unroll
        for (int j = 0; j < 4; j++) {
          int coll = wc * 64 + j * 16 + cc;      // [0,256)
          int colp = coll & 127;                 // within pass
          float bv = bias[bn + coll];
#pragma unroll
          for (int i = 0; i < 4; i++)
#pragma unroll
            for (int r = 0; r < 4; r++) {
              int s = wr * 64 + i * 16 + cr + r;
              sh[colp * 128 + (s ^ ((colp & 15) << 3))] = f2bf(acc[i][j][r] + bv);
            }
        }
      }
      __syncthreads();
#pragma unroll
      for (int k = 0; k < 4; k++) {
        int g = tid + k * 512;
        int colp = g >> 4, sc2 = g & 15;
        bf16x8 v = *(const bf16x8*)&sh[colp * 128 + ((sc2 * 8) ^ ((colp & 15) << 3))];
        int colg = bn + p * 128 + colp;
        *(bf16x8*)&Vt[((size_t)(bb2 * D_ + colg) << 12) + ssb + sc2 * 8] = v;
      }
    }
    return;
  }

  float sc = qscale ? 0.125f : 1.0f;
#pragma unroll
  for (int j = 0; j < 4; j++) {
    int col = c0 + j * 16 + cc;
    float bv = bias[col];
#pragma unroll
    for (int i = 0; i < 4; i++)
#pragma unroll
      for (int r = 0; r < 4; r++) {
        size_t off = (size_t)(r0 + i * 16 + cr + r) * Nstride + col;
        Cb[off] = f2bf(epi_post<MODE>((acc[i][j][r] + bv) * sc));
      }
  }
}

// ============ 128x128 GEMM: 3-deep pipeline + LDS-bounce epilogue =
template <int MODE>
__global__ __launch_bounds__(256) void gemm_pipe(const u16* __restrict__ A,
                                                 const u16* __restrict__ Bt,
                                                 const float* __restrict__ bias,
                                                 u16* __restrict__ Cb,
                                                 int Ndim, int Kdim, int rowTileStride) {
  __shared__ u16 sh[24576];
  int gx = gridDim.x;
  int bid = blockIdx.x + blockIdx.y * gx;
  bid = xcd_swz(bid, gx * gridDim.y);
  int bm = (bid / gx) * rowTileStride * 128;
  int bn = (bid % gx) * 128;
  int tid = threadIdx.x;
  int lane = tid & 63, w = tid >> 6;
  int r0w = (w >> 1) * 64, c0w = (w & 1) * 64;
  int lr = lane & 15, lg = lane >> 4;

  int f0 = tid, l0 = f0 >> 3, s0 = (f0 & 7) ^ (l0 & 7);
  int row0 = (l0 << 1) | (s0 >> 2), c0s = (s0 & 3) * 8;
  int f1 = tid + 256, l1 = f1 >> 3, s1 = (f1 & 7) ^ (l1 & 7);
  int row1 = (l1 << 1) | (s1 >> 2), c1s = (s1 & 3) * 8;
  const u16* A0 = A + (size_t)(bm + row0) * Kdim + c0s;
  const u16* A1 = A + (size_t)(bm + row1) * Kdim + c1s;
  const u16* B0 = Bt + (size_t)(bn + row0) * Kdim + c0s;
  const u16* B1 = Bt + (size_t)(bn + row1) * Kdim + c1s;

  int offa[4], offb[4];
#pragma unroll
  for (int i = 0; i < 4; i++) {
    int ra = r0w + i * 16 + lr;
    int la = ra >> 1, sa = ((ra & 1) << 2) | lg;
    offa[i] = la * 64 + (sa ^ (la & 7)) * 8;
    int rb = c0w + i * 16 + lr;
    int lb = rb >> 1, sb = ((rb & 1) << 2) | lg;
    offb[i] = lb * 64 + (sb ^ (lb & 7)) * 8;
  }

  auto stage = [&](int kt, int buf) {
    int k1 = kt << 5;
    u16* ab = sh + buf * 4096;
    u16* bb = sh + 12288 + buf * 4096;
    gload16(A0 + k1, &ab[tid * 8]);
    gload16(A1 + k1, &ab[tid * 8 + 2048]);
    gload16(B0 + k1, &bb[tid * 8]);
    gload16(B1 + k1, &bb[tid * 8 + 2048]);
  };

  int nt = Kdim >> 5;
  f32x4 acc[4][4] = {};

  stage(0, 0);
  if (nt > 1) stage(1, 1);

  for (int t = 0; t < nt; t++) {
    int cb = t % 3;
    if (t + 2 < nt) {
      stage(t + 2, (t + 2) % 3);
      asm volatile("s_waitcnt vmcnt(8)" ::: "memory");
    } else if (t + 1 < nt) {
      asm volatile("s_waitcnt vmcnt(4)" ::: "memory");
    } else {
      asm volatile("s_waitcnt vmcnt(0)" ::: "memory");
    }
    __builtin_amdgcn_s_barrier();
    __builtin_amdgcn_sched_barrier(0);
    const u16* ab = sh + cb * 4096;
    const u16* bb = sh + 12288 + cb * 4096;
    bf16x8 a[4], b[4];
#pragma unroll
    for (int i = 0; i < 4; i++) a[i] = *(const bf16x8*)&ab[offa[i]];
#pragma unroll
    for (int j = 0; j < 4; j++) b[j] = *(const bf16x8*)&bb[offb[j]];
#pragma unroll
    for (int i = 0; i < 4; i++)
#pragma unroll
      for (int j = 0; j < 4; j++)
        acc[i][j] = mfma16(a[i], b[j], acc[i][j]);
    __builtin_amdgcn_sched_barrier(0);
    __builtin_amdgcn_s_barrier();
    __builtin_amdgcn_sched_barrier(0);
  }

  int cr = (lane >> 4) * 4, cc = lane & 15;
#pragma unroll
  for (int j = 0; j < 4; j++) {
    int col = c0w + j * 16 + cc;
    float bv = bias[bn + col];
#pragma unroll
    for (int i = 0; i < 4; i++)
#pragma unroll
      for (int r = 0; r < 4; r++) {
        int row = r0w + i * 16 + cr + r;
        int chunk = (col >> 3) ^ (row & 15);
        sh[row * 128 + chunk * 8 + (col & 7)] =
            f2bf(epi_post<MODE>(acc[i][j][r] + bv));
      }
  }
  __syncthreads();
  {
    int row = tid >> 1, half = tid & 1;
    u16* gro = Cb + (size_t)(bm + row) * Ndim + bn + half * 64;
#pragma unroll
    for (int c = 0; c < 8; c++) {
      int lc = half * 8 + c;
      int pc = lc ^ (row & 15);
      bf16x8 v = *(const bf16x8*)&sh[row * 128 + pc * 8];
      *(bf16x8*)(gro + c * 8) = v;
    }
  }
}

// ---------------- local windowed + global-key attention ----------
__global__ __launch_bounds__(128) void attn_local(const u16* __restrict__ qb,
                                                  const u16* __restrict__ kb_,
                                                  const u16* __restrict__ vt,
                                                  const float* __restrict__ mask,
                                                  u16* __restrict__ ao) {
  int bid = blockIdx.x + blockIdx.y * gridDim.x;
  bid = xcd_swz(bid, 1536);
  int cx = bid & 63, bh = bid >> 6;
  int c = cx >> 2, sub = cx & 3;
  int b = bh / H_, h = bh % H_;
  int tid = threadIdx.x;
  int w = tid >> 6, lane = tid & 63;
  int lr = lane & 15, lg = lane >> 4;

  __shared__ u16 plds[2][32][72];
  __shared__ unsigned char vflag[576];

  int base_off = sub * 64;
  int kwin0 = c * W_ - W_;
  for (int i = tid; i < 576; i += 128) {
    int kp = kwin0 + base_off + i;
    vflag[i] = (kp >= 0 && kp < S_ && mask[b * S_ + kp] == 0.0f) ? 1 : 0;
  }
  __syncthreads();

  size_t hoff = (size_t)b * S_ * D_ + h * DH_;
  const u16* vth = vt + ((size_t)(b * D_ + h * DH_) << 12);
  int qrow0 = c * W_ + base_off + w * 32;
  bf16x8 aq[2][2];
#pragma unroll
  for (int fi = 0; fi < 2; fi++)
#pragma unroll
    for (int ks = 0; ks < 2; ks++)
      aq[fi][ks] = *(const bf16x8*)(qb + hoff + (size_t)(qrow0 + fi * 16 + lr) * D_ + ks * 32 + lg * 8);

  int K0 = kwin0 + base_off;
  int kb_lo = (K0 < 0) ? (1 + ((-K0) >> 6)) : 1;
  int kb_hi = 9;
  { int hi = 1 + ((S_ - 64 - K0) >> 6); if (hi < 9) kb_hi = hi; }
  int niter = 1 + (kb_hi - kb_lo + 1);

  float ls[2][4];
  f32x4 o[2][4] = {};
#pragma unroll
  for (int fi = 0; fi < 2; fi++)
#pragma unroll
    for (int r = 0; r < 4; r++) ls[fi][r] = 0.f;

  bf16x8 ck0[4], ck1[4], nk0[4], nk1[4];
#pragma unroll
  for (int nj = 0; nj < 4; nj++) {
    const u16* ks8 = kb_ + hoff + (size_t)(nj * 16 + lr) * D_ + lg * 8;
    ck0[nj] = *(const bf16x8*)(ks8);
    ck1[nj] = *(const bf16x8*)(ks8 + 32);
  }

  for (int it = 0; it < niter; it++) {
    int kb = (it == 0) ? 0 : (kb_lo + it - 1);
    int kstart = (it == 0) ? 0 : (K0 + (kb - 1) * 64);

    f32x4 sc[2][4];
#pragma unroll
    for (int fi = 0; fi < 2; fi++)
#pragma unroll
      for (int nj = 0; nj < 4; nj++) {
        f32x4 t = {};
        t = mfma16(aq[fi][0], ck0[nj], t);
        t = mfma16(aq[fi][1], ck1[nj], t);
        sc[fi][nj] = t;
      }

    bf16x8 vf[4][2];
#pragma unroll
    for (int dj = 0; dj < 4; dj++)
#pragma unroll
      for (int ks = 0; ks < 2; ks++)
        vf[dj][ks] = *(const bf16x8*)&vth[((size_t)(dj * 16 + lr) << 12) + kstart + ks * 32 + lg * 8];

    if (it + 1 < niter) {
      int ks2 = K0 + (kb_lo + it - 1) * 64;
#pragma unroll
      for (int nj = 0; nj < 4; nj++) {
        const u16* ks8 = kb_ + hoff + (size_t)(ks2 + nj * 16 + lr) * D_ + lg * 8;
        nk0[nj] = *(const bf16x8*)(ks8);
        nk1[nj] = *(const bf16x8*)(ks8 + 32);
      }
    }

    if (kb >= 2 && kb <= 8) {
#pragma unroll
      for (int nj = 0; nj < 4; nj++) {
        bool kv = vflag[(kb - 1) * 64 + nj * 16 + lr] != 0;
#pragma unroll
        for (int fi = 0; fi < 2; fi++)
#pragma unroll
          for (int r = 0; r < 4; r++)
            sc[fi][nj][r] = kv ? sc[fi][nj][r] : NEGV;
      }
    } else if (kb > 0) {
#pragma unroll
      for (int nj = 0; nj < 4; nj++) {
        int fidx = (kb - 1) * 64 + nj * 16 + lr;
        int koff = base_off + fidx;
        bool kv = vflag[fidx] != 0;
#pragma unroll
        for (int fi = 0; fi < 2; fi++)
#pragma unroll
          for (int r = 0; r < 4; r++) {
            int wq = base_off + w * 32 + fi * 16 + lg * 4 + r;
            if (!(kv && koff >= wq && koff <= wq + 2 * W_)) sc[fi][nj][r] = NEGV;
          }
      }
    }

#pragma unroll
    for (int fi = 0; fi < 2; fi++)
#pragma unroll
      for (int r = 0; r < 4; r++) {
        float ps = 0.f;
#pragma unroll
        for (int nj = 0; nj < 4; nj++) {
          float p = __expf(sc[fi][nj][r]);
          sc[fi][nj][r] = p;
          ps += p;
        }
#pragma unroll
        for (int d = 1; d < 16; d <<= 1) ps += __shfl_xor(ps, d);
        ls[fi][r] += ps;
      }

#pragma unroll
    for (int fi = 0; fi < 2; fi++)
#pragma unroll
      for (int nj = 0; nj < 4; nj++)
#pragma unroll
        for (int r = 0; r < 4; r++)
          plds[w][fi * 16 + lg * 4 + r][nj * 16 + lr] = f2bf(sc[fi][nj][r]);
    asm volatile("s_waitcnt lgkmcnt(0)" ::: "memory");
    __builtin_amdgcn_sched_barrier(0);

    bf16x8 ap[2][2];
#pragma unroll
    for (int fi = 0; fi < 2; fi++)
#pragma unroll
      for (int ks = 0; ks < 2; ks++)
        ap[fi][ks] = *(const bf16x8*)&plds[w][fi * 16 + lr][ks * 32 + lg * 8];
#pragma unroll
    for (int dj = 0; dj < 4; dj++)
#pragma unroll
      for (int ks = 0; ks < 2; ks++) {
        o[0][dj] = mfma16(ap[0][ks], vf[dj][ks], o[0][dj]);
        o[1][dj] = mfma16(ap[1][ks], vf[dj][ks], o[1][dj]);
      }

    if (it + 1 < niter) {
#pragma unroll
      for (int j = 0; j < 4; j++) {
        ck0[j] = nk0[j]; ck1[j] = nk1[j];
      }
    }
  }

#pragma unroll
  for (int fi = 0; fi < 2; fi++)
#pragma unroll
    for (int dj = 0; dj < 4; dj++)
#pragma unroll
      for (int r = 0; r < 4; r++) {
        int row = qrow0 + fi * 16 + lg * 4 + r;
        float v = o[fi][dj][r] / ls[fi][r];
        ao[hoff + (size_t)row * D_ + dj * 16 + lr] = f2bf(v);
      }
}

// ---------------- global attention, split-K partials -------------
__global__ __launch_bounds__(128) void attn_gsplit(const u16* __restrict__ qg,
                                                   const u16* __restrict__ kg,
                                                   const u16* __restrict__ vgt,
                                                   float* __restrict__ opart,
                                                   float* __restrict__ lpart) {
  int sp = blockIdx.x, bh = blockIdx.y;
  int b = bh / H_, h = bh % H_;
  int tid = threadIdx.x, w = tid >> 6, lane = tid & 63;
  int lr = lane & 15, lg = lane >> 4;
  __shared__ u16 plds[2][32][72];
  size_t hoff = (size_t)b * S_ * D_ + h * DH_;
  const u16* vth = vgt + ((size_t)(b * D_ + h * DH_) << 12);
  int qrow0 = w * 32;
  bf16x8 aq[2][2];
#pragma unroll
  for (int fi = 0; fi < 2; fi++)
#pragma unroll
    for (int ks = 0; ks < 2; ks++)
      aq[fi][ks] = *(const bf16x8*)(qg + hoff + (size_t)(qrow0 + fi * 16 + lr) * D_ + ks * 32 + lg * 8);
  float ls[2][4];
  f32x4 o[2][4] = {};
#pragma unroll
  for (int fi = 0; fi < 2; fi++)
#pragma unroll
    for (int r = 0; r < 4; r++) ls[fi][r] = 0.f;

  for (int kb = 0; kb < 4; kb++) {
    int kstart = sp * 256 + kb * 64;

    bf16x8 bk0[4], bk1[4];
#pragma unroll
    for (int nj = 0; nj < 4; nj++) {
      const u16* ks8 = kg + hoff + (size_t)(kstart + nj * 16 + lr) * D_ + lg * 8;
      bk0[nj] = *(const bf16x8*)(ks8);
      bk1[nj] = *(const bf16x8*)(ks8 + 32);
    }
    bf16x8 vf[4][2];
#pragma unroll
    for (int dj = 0; dj < 4; dj++)
#pragma unroll
      for (int ks = 0; ks < 2; ks++)
        vf[dj][ks] = *(const bf16x8*)&vth[((size_t)(dj * 16 + lr) << 12) + kstart + ks * 32 + lg * 8];

    f32x4 sc[2][4];
#pragma unroll
    for (int fi = 0; fi < 2; fi++)
#pragma unroll
      for (int nj = 0; nj < 4; nj++) {
        f32x4 t = {};
        t = mfma16(aq[fi][0], bk0[nj], t);
        t = mfma16(aq[fi][1], bk1[nj], t);
        sc[fi][nj] = t;
      }
#pragma unroll
    for (int fi = 0; fi < 2; fi++)
#pragma unroll
      for (int r = 0; r < 4; r++) {
        float ps = 0.f;
#pragma unroll
        for (int nj = 0; nj < 4; nj++) {
          float p = __expf(sc[fi][nj][r]);
          sc[fi][nj][r] = p;
          ps += p;
        }
#pragma unroll
        for (int d = 1; d < 16; d <<= 1) ps += __shfl_xor(ps, d);
        ls[fi][r] += ps;
      }
#pragma unroll
    for (int fi = 0; fi < 2; fi++)
#pragma unroll
      for (int nj = 0; nj < 4; nj++)
#pragma unroll
        for (int r = 0; r < 4; r++)
          plds[w][fi * 16 + lg * 4 + r][nj * 16 + lr] = f2bf(sc[fi][nj][r]);
    asm volatile("s_waitcnt lgkmcnt(0)" ::: "memory");
    __builtin_amdgcn_sched_barrier(0);
    bf16x8 ap[2][2];
#pragma unroll
    for (int fi = 0; fi < 2; fi++)
#pragma unroll
      for (int ks = 0; ks < 2; ks++)
        ap[fi][ks] = *(const bf16x8*)&plds[w][fi * 16 + lr][ks * 32 + lg * 8];
#pragma unroll
    for (int dj = 0; dj < 4; dj++)
#pragma unroll
      for (int ks = 0; ks < 2; ks++) {
        o[0][dj] = mfma16(ap[0][ks], vf[dj][ks], o[0][dj]);
        o[1][dj] = mfma16(ap[1][ks], vf[dj][ks], o[1][dj]);
      }
  }

  size_t pbase = (size_t)(bh * NSPLIT + sp) * 64;
#pragma unroll
  for (int fi = 0; fi < 2; fi++)
#pragma unroll
    for (int r = 0; r < 4; r++) {
      int row = qrow0 + fi * 16 + lg * 4 + r;
      if (lr == 0) lpart[pbase + row] = ls[fi][r];
#pragma unroll
      for (int dj = 0; dj < 4; dj++)
        opart[(pbase + row) * 64 + dj * 16 + lr] = o[fi][dj][r];
    }
}

// ---------------- combine split-K partials (plain sums) ----------
__global__ __launch_bounds__(256) void attn_gcombine(const float* __restrict__ opart,
                                                     const float* __restrict__ lpart,
                                                     u16* __restrict__ ao) {
  int bh = blockIdx.x;
  int b = bh / H_, h = bh % H_;
  int t = threadIdx.x;
  __shared__ float lt[64];
  if (t < 64) {
    float lsum = 0.f;
#pragma unroll
    for (int sp = 0; sp < NSPLIT; sp++)
      lsum += lpart[(size_t)(bh * NSPLIT + sp) * 64 + t];
    lt[t] = lsum;
  }
  __syncthreads();
  int row = t >> 2, c0 = (t & 3) * 16;
  float acc[16] = {};
  for (int sp = 0; sp < NSPLIT; sp++) {
    const float* op = opart + ((size_t)(bh * NSPLIT + sp) * 64 + row) * 64 + c0;
#pragma unroll
    for (int j = 0; j < 16; j++) acc[j] += op[j];
  }
  float inv = 1.f / lt[row];
  size_t hoff = (size_t)b * S_ * D_ + h * DH_;
#pragma unroll
  for (int j = 0; j < 16; j++)
    ao[hoff + (size_t)row * D_ + c0 + j] = f2bf(acc[j] * inv);
}

// ---------------- residual + LayerNorm (bf16 in/out) -------------
__global__ __launch_bounds__(192) void ln_b(const u16* __restrict__ x,
                                            const u16* __restrict__ res,
                                            const float* __restrict__ gg,
                                            const float* __restrict__ bb,
                                            u16* __restrict__ outb,
                                            float* __restrict__ outf) {
  int row = blockIdx.x, t = threadIdx.x;
  const u16* xr = x + (size_t)row * D_;
  const u16* rr = res + (size_t)row * D_;
  u16x4 xv = *(const u16x4*)&xr[t * 4];
  u16x4 rv = *(const u16x4*)&rr[t * 4];
  float v[4];
#pragma unroll
  for (int e = 0; e < 4; e++) v[e] = b2f(xv[e]) + b2f(rv[e]);
  __shared__ float sha[3], shb[3];
  float s = v[0] + v[1] + v[2] + v[3];
#pragma unroll
  for (int d = 1; d < 64; d <<= 1) s += __shfl_xor(s, d);
  if ((t & 63) == 0) sha[t >> 6] = s;
  __syncthreads();
  float mu = (sha[0] + sha[1] + sha[2]) * (1.f / 768.f);
  float dd[4], s2 = 0.f;
#pragma unroll
  for (int e = 0; e < 4; e++) { dd[e] = v[e] - mu; s2 += dd[e] * dd[e]; }
#pragma unroll
  for (int d = 1; d < 64; d <<= 1) s2 += __shfl_xor(s2, d);
  if ((t & 63) == 0) shb[t >> 6] = s2;
  __syncthreads();
  float var = (shb[0] + shb[1] + shb[2]) * (1.f / 768.f);
  float rs = rsqrtf(var + 1e-5f);
  float4 gv = *(const float4*)&gg[t * 4];
  float4 bv = *(const float4*)&bb[t * 4];
  float y0 = dd[0] * rs * gv.x + bv.x;
  float y1 = dd[1] * rs * gv.y + bv.y;
  float y2 = dd[2] * rs * gv.z + bv.z;
  float y3 = dd[3] * rs * gv.w + bv.w;
  u16x4 ov;
  ov[0] = f2bf(y0); ov[1] = f2bf(y1); ov[2] = f2bf(y2); ov[3] = f2bf(y3);
  *(u16x4*)&outb[(size_t)row * D_ + t * 4] = ov;
  if (outf) {
    float4 of = {y0, y1, y2, y3};
    *(float4*)&outf[(size_t)row * D_ + t * 4] = of;
  }
}

// =================================================================
extern "C" void kernel_launch(void* const* d_in, const int* in_sizes, int n_in,
                              void* d_out, int out_size, void* d_ws, size_t ws_size,
                              hipStream_t stream) {
  (void)in_sizes; (void)n_in; (void)out_size; (void)ws_size;
  const float* hidden = (const float*)d_in[0];
  const float* mask   = (const float*)d_in[1];
  const float* Wq  = (const float*)d_in[4];   const float* bq  = (const float*)d_in[5];
  const float* Wk  = (const float*)d_in[6];   const float* bk  = (const float*)d_in[7];
  const float* Wv  = (const float*)d_in[8];   const float* bv  = (const float*)d_in[9];
  const float* Wqg = (const float*)d_in[10];  const float* bqg = (const float*)d_in[11];
  const float* Wkg = (const float*)d_in[12];  const float* bkg = (const float*)d_in[13];
  const float* Wvg = (const float*)d_in[14];  const float* bvg = (const float*)d_in[15];
  const float* Wo  = (const float*)d_in[16];  const float* bo  = (const float*)d_in[17];
  const float* Wi  = (const float*)d_in[18];  const float* bi  = (const float*)d_in[19];
  const float* Wo2 = (const float*)d_in[20];  const float* bo2 = (const float*)d_in[21];
  const float* ln1g = (const float*)d_in[22]; const float* ln1b = (const float*)d_in[23];
  const float* ln2g = (const float*)d_in[24]; const float* ln2b = (const float*)d_in[25];

  char* ws = (char*)d_ws;
  size_t off = 0;
  auto alloc = [&](size_t bytes) -> void* {
    void* p = ws + off;
    off += (bytes + 255) & ~(size_t)255;
    return p;
  };
  const size_t DD = (size_t)D_ * D_;
  const size_t DF = (size_t)D_ * FF_;
  u16* Wt = (u16*)alloc((7 * L_ * DD + 2 * L_ * DF) * 2);
  u16* wo_t  = Wt + 6 * L_ * DD;
  u16* wi_t  = Wt + 7 * L_ * DD;
  u16* wo2_t = Wt + 7 * L_ * DD + L_ * DF;

  u16* X0 = (u16*)alloc((size_t)M_ * D_ * 2);
  u16* X1 = (u16*)alloc((size_t)M_ * D_ * 2);
  u16* tb = (u16*)alloc((size_t)M_ * D_ * 2);
  u16* B_bf = (u16*)alloc((size_t)M_ * FF_ * 2);
  u16* qbf  = (u16*)alloc((size_t)M_ * D_ * 2 * 6);
  u16* kbf  = qbf + 1 * (size_t)M_ * D_;
  u16* qgbf = qbf + 3 * (size_t)M_ * D_;
  u16* kgbf = qbf + 4 * (size_t)M_ * D_;
  u16* vtb  = (u16*)alloc((size_t)M_ * D_ * 2 * 2);   // V^T and VG^T
  u16* vgt  = vtb + (size_t)M_ * D_;
  u16* aobf = (u16*)alloc((size_t)M_ * D_ * 2);
  float* opart = (float*)alloc((size_t)B_ * H_ * NSPLIT * 64 * 64 * 4);
  float* lpart = (float*)alloc((size_t)B_ * H_ * NSPLIT * 64 * 4);

  dim3 tb32(32, 8);
  Ptr7 wp;
  wp.p[0] = Wq; wp.p[1] = Wk; wp.p[2] = Wv; wp.p[3] = Wqg;
  wp.p[4] = Wkg; wp.p[5] = Wvg; wp.p[6] = Wo;
  wtrans7<<<dim3(24, 24, 14), tb32, 0, stream>>>(wp, Wt);
  wtrans<<<dim3(96, 24, 2), tb32, 0, stream>>>(Wi,  wi_t,  D_, FF_);
  wtrans<<<dim3(24, 96, 2), tb32, 0, stream>>>(Wo2, wo2_t, FF_, D_);

  conv_b<<<(M_ * D_ / 4 + 255) / 256, 256, 0, stream>>>(hidden, X0, M_ * D_ / 4);

  for (int l = 0; l < L_; l++) {
    size_t wdd = (size_t)l * DD;
    size_t wdf = (size_t)l * DF;
    dim3 g64(6, 64);

    Bias6 bp;
    bp.p[0] = bq  + l * D_;
    bp.p[1] = bk  + l * D_;
    bp.p[2] = bv  + l * D_;
    bp.p[3] = bkg + l * D_;
    bp.p[4] = bvg + l * D_;
    bp.p[5] = bqg + l * D_;
    gemm_wide<1, 5><<<dim3(18, 64), 512, 0, stream>>>(X0, Wt, bp, qbf, vtb, D_, D_, l);

    attn_local<<<dim3((S_ / W_) * 4, B_ * H_), 128, 0, stream>>>(qbf, kbf, vtb, mask, aobf);
    attn_gsplit<<<dim3(NSPLIT, B_ * H_), 128, 0, stream>>>(qgbf, kgbf, vgt, opart, lpart);
    attn_gcombine<<<B_ * H_, 256, 0, stream>>>(opart, lpart, aobf);

    gemm_pipe<1><<<g64, 256, 0, stream>>>(aobf, wo_t + wdd, bo + l * D_, tb, D_, D_, 1);
    ln_b<<<M_, 192, 0, stream>>>(tb, X0, ln1g + l * D_, ln1b + l * D_, X1, nullptr);

    Bias6 bpi; bpi.p[0] = bi + l * FF_;
    gemm_wide<3, 1><<<dim3(12, 64), 512, 0, stream>>>(X1, wi_t + wdf, bpi, B_bf, nullptr, D_, FF_, 0);
    gemm_pipe<1><<<g64, 256, 0, stream>>>(B_bf, wo2_t + wdf, bo2 + l * D_, tb, D_, FF_, 1);

    ln_b<<<M_, 192, 0, stream>>>(tb, X1, ln2g + l * D_, ln2b + l * D_, X0,
                                 (l == L_ - 1) ? (float*)d_out : nullptr);
  }
}